// Round 6
// baseline (443.802 us; speedup 1.0000x reference)
//
#include <hip/hip_runtime.h>
#include <hip/hip_bf16.h>
#include <math.h>

#define NA 16384
#define NE 65536
#define AD 29

__device__ __forceinline__ float sigmoidf_(float x) { return 1.0f / (1.0f + expf(-x)); }

// ============ init h: pad atom features 29 -> 64 ============
__global__ void k_init_h(const float* __restrict__ af, float* __restrict__ h) {
  int idx = blockIdx.x * 256 + threadIdx.x;
  if (idx >= NA * 64) return;
  int a = idx >> 6, d = idx & 63;
  h[idx] = (d < AD) ? af[a * AD + d] : 0.0f;
}

// ============ Kr relayout (once per call): Kr4[(k9*16+j4)*64 + i] = K[k9][i][4j4..+3]
// (k9==8 is the bias matrix). Lane i then reads its float4 coalesced.
__global__ void k_prep_Kr(const float* __restrict__ kern, const float* __restrict__ kbias,
                          float* __restrict__ Kr) {
  int f = blockIdx.x * 256 + threadIdx.x;    // 9*16*64*4 = 36864 floats
  if (f >= 36864) return;
  int t = f & 3, i = (f >> 2) & 63, j4 = (f >> 8) & 15, k9 = f >> 12;
  int col = j4 * 4 + t;
  Kr[f] = (k9 < 8) ? kern[k9 * 4096 + i * 64 + col] : kbias[i * 64 + col];
}

// ============ edge bucketing by src (once per call; counting sort) ============
__global__ void k_count(const int* __restrict__ pairs, int* __restrict__ count) {
  int e = blockIdx.x * 256 + threadIdx.x;
  if (e >= NE) return;
  atomicAdd(&count[pairs[2 * e]], 1);
}
__global__ void k_scan1(const int* __restrict__ count, int* __restrict__ bsum) {
  __shared__ int red[256];
  int b = blockIdx.x, t = threadIdx.x;
  red[t] = count[b * 256 + t];
  __syncthreads();
  for (int s = 128; s > 0; s >>= 1) { if (t < s) red[t] += red[t + s]; __syncthreads(); }
  if (t == 0) bsum[b] = red[0];
}
__global__ void k_scan2(const int* __restrict__ count, const int* __restrict__ bsum,
                        int* __restrict__ start, int* __restrict__ cursor) {
  __shared__ int sc[256];
  __shared__ int basev;
  int b = blockIdx.x, t = threadIdx.x;
  if (t == 0) { int s = 0; for (int i = 0; i < b; ++i) s += bsum[i]; basev = s; }
  int v = count[b * 256 + t];
  sc[t] = v;
  __syncthreads();
  for (int off = 1; off < 256; off <<= 1) {
    int add = (t >= off) ? sc[t - off] : 0;
    __syncthreads();
    sc[t] += add;
    __syncthreads();
  }
  int excl = sc[t] - v + basev;
  start[b * 256 + t] = excl;
  cursor[b * 256 + t] = excl;
}
__global__ void k_place(const int* __restrict__ pairs, int* __restrict__ cursor,
                        int* __restrict__ elist) {
  int e = blockIdx.x * 256 + threadIdx.x;
  if (e >= NE) return;
  int pos = atomicAdd(&cursor[pairs[2 * e]], 1);
  elist[pos] = e;
}

// ============ fused message step: agg[a] = sum_{k,j} K[k][i][j] * T[a][k][j]
// where T[a][k][j] = sum_{e: src=a} bf[e][k]*h[dst_e][j]  (k=8: bf=1 -> bias).
// Phase A: 8 independent per-atom gather chains in flight (hides L2 latency),
// T accumulated in registers (lane = j), spilled to LDS.
// Phase B: lane = i; Kr streamed coalesced from L2, T broadcast from LDS,
// 8 atoms amortize each Kr load. No atomics; agg fully overwritten.
#define MW 4
#define MA 8
__global__ __launch_bounds__(256, 2) void k_msg(
    const float* __restrict__ bf, const int* __restrict__ pairs,
    const float* __restrict__ h, const int* __restrict__ start,
    const int* __restrict__ count, const int* __restrict__ elist,
    const float* __restrict__ Kr, float* __restrict__ agg) {
  __shared__ __align__(16) float T_s[MW][MA][576];   // 73,728 B
  const int tid = threadIdx.x, lane = tid & 63, wv = tid >> 6;
  const int abase = blockIdx.x * (MW * MA) + wv * MA;

  int s_[MA], c_[MA];
#pragma unroll
  for (int a = 0; a < MA; ++a) { s_[a] = start[abase + a]; c_[a] = count[abase + a]; }
  float t[MA][9];
#pragma unroll
  for (int a = 0; a < MA; ++a)
#pragma unroll
    for (int k = 0; k < 9; ++k) t[a][k] = 0.f;
  int maxc = 0;
#pragma unroll
  for (int a = 0; a < MA; ++a) maxc = max(maxc, c_[a]);

  for (int r = 0; r < maxc; ++r) {
#pragma unroll
    for (int a = 0; a < MA; ++a) {
      if (r < c_[a]) {                       // wave-uniform branch
        int e = elist[s_[a] + r];
        int dst = pairs[2 * e + 1];
        float hv = h[dst * 64 + lane];
        float bq = (lane < 8) ? bf[e * 8 + lane] : 0.f;
#pragma unroll
        for (int k = 0; k < 8; ++k) t[a][k] = fmaf(__shfl(bq, k, 64), hv, t[a][k]);
        t[a][8] += hv;
      }
    }
  }
#pragma unroll
  for (int a = 0; a < MA; ++a)
#pragma unroll
    for (int k = 0; k < 9; ++k) T_s[wv][a][k * 64 + lane] = t[a][k];
  __syncthreads();

  float acc[MA];
#pragma unroll
  for (int a = 0; a < MA; ++a) acc[a] = 0.f;
  const float4* Kr4 = reinterpret_cast<const float4*>(Kr);
  const float4* Ts4 = reinterpret_cast<const float4*>(&T_s[wv][0][0]);
#pragma unroll 2
  for (int kj = 0; kj < 144; ++kj) {
    float4 Kv = Kr4[kj * 64 + lane];
#pragma unroll
    for (int a = 0; a < MA; ++a) {
      float4 Tv = Ts4[a * 144 + kj];         // broadcast read
      acc[a] = fmaf(Kv.x, Tv.x, acc[a]);
      acc[a] = fmaf(Kv.y, Tv.y, acc[a]);
      acc[a] = fmaf(Kv.z, Tv.z, acc[a]);
      acc[a] = fmaf(Kv.w, Tv.w, acc[a]);
    }
  }
#pragma unroll
  for (int a = 0; a < MA; ++a) agg[(abase + a) * 64 + lane] = acc[a];
}

// ============ GRU cell (per atom) ============
#define GABLK 4
__global__ __launch_bounds__(512, 1) void k_gru(
    const float* __restrict__ agg, const float* __restrict__ wih,
    const float* __restrict__ whh, const float* __restrict__ bih,
    const float* __restrict__ bhh, float* __restrict__ h) {
  __shared__ __align__(16) float wih_s[192 * 64];
  __shared__ __align__(16) float whh_s[192 * 64];
  __shared__ __align__(16) float act_s[8][2][GABLK][64];
  const int tid = threadIdx.x, lane = tid & 63, wv = tid >> 6;

  for (int idx = tid; idx < 192 * 64; idx += 512) {
    int r = idx >> 6, d = idx & 63;
    int pos = (r << 6) + ((((d >> 2) ^ (r & 7)) << 2) | (d & 3));
    wih_s[pos] = wih[idx];
    whh_s[pos] = whh[idx];
  }
  __syncthreads();

  const float4* wi4 = reinterpret_cast<const float4*>(wih_s);
  const float4* wh4 = reinterpret_cast<const float4*>(whh_s);
  const float bir = bih[lane], biz = bih[64 + lane], bin_ = bih[128 + lane];
  const float bhr = bhh[lane], bhz = bhh[64 + lane], bhn = bhh[128 + lane];
  const int swz = lane & 7;
  const int gw = blockIdx.x * 8 + wv;
  const int stride = gridDim.x * 8 * GABLK;

  for (int ag = gw * GABLK; ag < NA; ag += stride) {
#pragma unroll
    for (int e = 0; e < GABLK; ++e) {
      act_s[wv][0][e][lane] = agg[(ag + e) * 64 + lane];
      act_s[wv][1][e][lane] = h[(ag + e) * 64 + lane];
    }
    __syncthreads();
    const float4* a4 = reinterpret_cast<const float4*>(&act_s[wv][0][0][0]);
    const float4* h4 = reinterpret_cast<const float4*>(&act_s[wv][1][0][0]);
    float air[GABLK] = {0,0,0,0}, aiz[GABLK] = {0,0,0,0}, ain[GABLK] = {0,0,0,0};
    float ahr[GABLK] = {0,0,0,0}, ahz[GABLK] = {0,0,0,0}, ahn[GABLK] = {0,0,0,0};
#pragma unroll 2
    for (int d4 = 0; d4 < 16; ++d4) {
      int sl = d4 ^ swz;
      float4 wir = wi4[(lane << 4) + sl];
      float4 wiz = wi4[((lane + 64) << 4) + sl];
      float4 win = wi4[((lane + 128) << 4) + sl];
      float4 whr = wh4[(lane << 4) + sl];
      float4 whz = wh4[((lane + 64) << 4) + sl];
      float4 whn = wh4[((lane + 128) << 4) + sl];
#pragma unroll
      for (int e = 0; e < GABLK; ++e) {
        float4 av = a4[e * 16 + d4];
        float4 hv = h4[e * 16 + d4];
        air[e] += wir.x*av.x + wir.y*av.y + wir.z*av.z + wir.w*av.w;
        aiz[e] += wiz.x*av.x + wiz.y*av.y + wiz.z*av.z + wiz.w*av.w;
        ain[e] += win.x*av.x + win.y*av.y + win.z*av.z + win.w*av.w;
        ahr[e] += whr.x*hv.x + whr.y*hv.y + whr.z*hv.z + whr.w*hv.w;
        ahz[e] += whz.x*hv.x + whz.y*hv.y + whz.z*hv.z + whz.w*hv.w;
        ahn[e] += whn.x*hv.x + whn.y*hv.y + whn.z*hv.z + whn.w*hv.w;
      }
    }
#pragma unroll
    for (int e = 0; e < GABLK; ++e) {
      float r = sigmoidf_((air[e] + bir) + (ahr[e] + bhr));
      float z = sigmoidf_((aiz[e] + biz) + (ahz[e] + bhz));
      float nn = tanhf((ain[e] + bin_) + r * (ahn[e] + bhn));
      float hold = act_s[wv][1][e][lane];
      h[(ag + e) * 64 + lane] = (1.0f - z) * nn + z * hold;
    }
    __syncthreads();
  }
}

// ============ qkv projection + valid mask ============
#define QABLK 4
__global__ __launch_bounds__(256, 1) void k_qkv(
    const float* __restrict__ h, const float* __restrict__ w,
    const float* __restrict__ b, float* __restrict__ qkv,
    int* __restrict__ valid) {
  __shared__ __align__(16) float w_s[192 * 64];
  __shared__ __align__(16) float x_s[4][QABLK][64];
  const int tid = threadIdx.x, lane = tid & 63, wv = tid >> 6;
  for (int idx = tid; idx < 192 * 64; idx += 256) {
    int r = idx >> 6, d = idx & 63;
    w_s[(r << 6) + ((((d >> 2) ^ (r & 7)) << 2) | (d & 3))] = w[idx];
  }
  __syncthreads();
  const float4* w4 = reinterpret_cast<const float4*>(w_s);
  const float bq = b[lane], bk = b[64 + lane], bv_ = b[128 + lane];
  const int swz = lane & 7;
  const int gw = blockIdx.x * 4 + wv;
  const int stride = gridDim.x * 4 * QABLK;
  for (int ag = gw * QABLK; ag < NA; ag += stride) {
#pragma unroll
    for (int e = 0; e < QABLK; ++e) x_s[wv][e][lane] = h[(ag + e) * 64 + lane];
    __syncthreads();
    const float4* x4 = reinterpret_cast<const float4*>(&x_s[wv][0][0]);
    float aq[QABLK] = {0,0,0,0}, ak[QABLK] = {0,0,0,0}, av_[QABLK] = {0,0,0,0};
    int nz[QABLK] = {0,0,0,0};
#pragma unroll 4
    for (int d4 = 0; d4 < 16; ++d4) {
      int sl = d4 ^ swz;
      float4 wq = w4[(lane << 4) + sl];
      float4 wk = w4[((lane + 64) << 4) + sl];
      float4 wvv = w4[((lane + 128) << 4) + sl];
#pragma unroll
      for (int e = 0; e < QABLK; ++e) {
        float4 xv = x4[e * 16 + d4];
        aq[e] += wq.x*xv.x + wq.y*xv.y + wq.z*xv.z + wq.w*xv.w;
        ak[e] += wk.x*xv.x + wk.y*xv.y + wk.z*xv.z + wk.w*xv.w;
        av_[e] += wvv.x*xv.x + wvv.y*xv.y + wvv.z*xv.z + wvv.w*xv.w;
        nz[e] |= (int)(xv.x != 0.f) | (int)(xv.y != 0.f) | (int)(xv.z != 0.f) | (int)(xv.w != 0.f);
      }
    }
#pragma unroll
    for (int e = 0; e < QABLK; ++e) {
      qkv[(ag + e) * 192 + lane] = aq[e] + bq;
      qkv[(ag + e) * 192 + 64 + lane] = ak[e] + bk;
      qkv[(ag + e) * 192 + 128 + lane] = av_[e] + bv_;
      if (lane == 0) valid[ag + e] = nz[e];
    }
    __syncthreads();
  }
}

// ============ attention: one wave per (molecule, head), online softmax ============
__global__ void k_attn(const float* __restrict__ qkv, const int* __restrict__ valid,
                       float* __restrict__ ao) {
  const int b = blockIdx.x >> 3, hh = blockIdx.x & 7;
  __shared__ float k_s[64][8];
  __shared__ float v_s[64][8];
  __shared__ int vd_s[64];
  const int lane = threadIdx.x;
  const int rowbase = (b * 64 + lane) * 192;
#pragma unroll
  for (int j = 0; j < 8; ++j) {
    k_s[lane][j] = qkv[rowbase + 64 + hh * 8 + j];
    v_s[lane][j] = qkv[rowbase + 128 + hh * 8 + j];
  }
  vd_s[lane] = valid[b * 64 + lane];
  __syncthreads();
  float q[8];
#pragma unroll
  for (int j = 0; j < 8; ++j) q[j] = qkv[rowbase + hh * 8 + j];
  float m = -3.0e38f, l = 0.f, o[8] = {0,0,0,0,0,0,0,0};
  for (int t = 0; t < 64; ++t) {
    float s = 0.f;
#pragma unroll
    for (int j = 0; j < 8; ++j) s += q[j] * k_s[t][j];
    s *= 0.35355339059327373f;
    s = vd_s[t] ? s : -1.0e9f;
    float mn = fmaxf(m, s);
    float c = expf(m - mn);
    float p = expf(s - mn);
    l = l * c + p;
#pragma unroll
    for (int j = 0; j < 8; ++j) o[j] = o[j] * c + p * v_s[t][j];
    m = mn;
  }
  const float inv = 1.0f / l;
  const int obase = (b * 64 + lane) * 64 + hh * 8;
#pragma unroll
  for (int j = 0; j < 8; ++j) ao[obase + j] = o[j] * inv;
}

// ============ out_proj + residual + LN1 ============
#define OABLK 4
__global__ __launch_bounds__(256, 1) void k_out_ln1(
    const float* __restrict__ x, const float* __restrict__ ao,
    const float* __restrict__ w, const float* __restrict__ bias,
    const float* __restrict__ g, const float* __restrict__ bb,
    float* __restrict__ y1) {
  __shared__ __align__(16) float w_s[64 * 64];
  __shared__ __align__(16) float a_s[4][OABLK][64];
  const int tid = threadIdx.x, lane = tid & 63, wv = tid >> 6;
  for (int idx = tid; idx < 64 * 64; idx += 256) {
    int r = idx >> 6, d = idx & 63;
    w_s[(r << 6) + ((((d >> 2) ^ (r & 7)) << 2) | (d & 3))] = w[idx];
  }
  __syncthreads();
  const float4* w4 = reinterpret_cast<const float4*>(w_s);
  const float bo = bias[lane], gg = g[lane], bbb = bb[lane];
  const int swz = lane & 7;
  const int gw = blockIdx.x * 4 + wv;
  const int stride = gridDim.x * 4 * OABLK;
  for (int ag = gw * OABLK; ag < NA; ag += stride) {
#pragma unroll
    for (int e = 0; e < OABLK; ++e) a_s[wv][e][lane] = ao[(ag + e) * 64 + lane];
    __syncthreads();
    const float4* a4 = reinterpret_cast<const float4*>(&a_s[wv][0][0]);
    float acc[OABLK] = {0,0,0,0};
#pragma unroll 4
    for (int d4 = 0; d4 < 16; ++d4) {
      int sl = d4 ^ swz;
      float4 wr = w4[(lane << 4) + sl];
#pragma unroll
      for (int e = 0; e < OABLK; ++e) {
        float4 av = a4[e * 16 + d4];
        acc[e] += wr.x*av.x + wr.y*av.y + wr.z*av.z + wr.w*av.w;
      }
    }
#pragma unroll
    for (int e = 0; e < OABLK; ++e) {
      float val = acc[e] + bo + x[(ag + e) * 64 + lane];
      float s1 = val, s2 = val * val;
#pragma unroll
      for (int mm = 1; mm < 64; mm <<= 1) {
        s1 += __shfl_xor(s1, mm, 64);
        s2 += __shfl_xor(s2, mm, 64);
      }
      float mu = s1 * 0.015625f;
      float var = s2 * 0.015625f - mu * mu;
      y1[(ag + e) * 64 + lane] = (val - mu) * rsqrtf(var + 1e-5f) * gg + bbb;
    }
    __syncthreads();
  }
}

// ============ FFN (512 hidden) + residual + LN2 ============
#define FW 4
#define FABLK 8
__global__ __launch_bounds__(256, 2) void k_ffn(
    const float* __restrict__ y1, const float* __restrict__ w1,
    const float* __restrict__ b1, const float* __restrict__ w2,
    const float* __restrict__ b2, const float* __restrict__ g,
    const float* __restrict__ bb, float* __restrict__ y2) {
  __shared__ __align__(16) float hbuf[FW][FABLK][512];   // 64 KB
  __shared__ __align__(16) float y1_s[FW][FABLK][64];    // 8 KB
  const int tid = threadIdx.x, lane = tid & 63, wv = tid >> 6;
  const float4* w1_4 = reinterpret_cast<const float4*>(w1);
  const float4* b1_4 = reinterpret_cast<const float4*>(b1);
  const float b2v = b2[lane], gg = g[lane], bbb = bb[lane];
  const int gw = blockIdx.x * FW + wv;
  const int stride = gridDim.x * FW * FABLK;
  for (int ag = gw * FABLK; ag < NA; ag += stride) {
#pragma unroll
    for (int e = 0; e < FABLK; ++e) y1_s[wv][e][lane] = y1[(ag + e) * 64 + lane];
    __syncthreads();
    float4 hv0[FABLK], hv1[FABLK];
    const float4 bq0 = b1_4[lane], bq1 = b1_4[64 + lane];
#pragma unroll
    for (int e = 0; e < FABLK; ++e) { hv0[e] = bq0; hv1[e] = bq1; }
#pragma unroll 4
    for (int d = 0; d < 64; ++d) {
      float4 w0 = w1_4[d * 128 + lane];
      float4 w1v = w1_4[d * 128 + 64 + lane];
#pragma unroll
      for (int e = 0; e < FABLK; ++e) {
        float yv = y1_s[wv][e][d];
        hv0[e].x = fmaf(yv, w0.x, hv0[e].x);
        hv0[e].y = fmaf(yv, w0.y, hv0[e].y);
        hv0[e].z = fmaf(yv, w0.z, hv0[e].z);
        hv0[e].w = fmaf(yv, w0.w, hv0[e].w);
        hv1[e].x = fmaf(yv, w1v.x, hv1[e].x);
        hv1[e].y = fmaf(yv, w1v.y, hv1[e].y);
        hv1[e].z = fmaf(yv, w1v.z, hv1[e].z);
        hv1[e].w = fmaf(yv, w1v.w, hv1[e].w);
      }
    }
    float4* hb4w = reinterpret_cast<float4*>(&hbuf[wv][0][0]);
#pragma unroll
    for (int e = 0; e < FABLK; ++e) {
      float4 r0 = hv0[e], r1 = hv1[e];
      r0.x = fmaxf(r0.x, 0.f); r0.y = fmaxf(r0.y, 0.f);
      r0.z = fmaxf(r0.z, 0.f); r0.w = fmaxf(r0.w, 0.f);
      r1.x = fmaxf(r1.x, 0.f); r1.y = fmaxf(r1.y, 0.f);
      r1.z = fmaxf(r1.z, 0.f); r1.w = fmaxf(r1.w, 0.f);
      hb4w[e * 128 + lane] = r0;
      hb4w[e * 128 + 64 + lane] = r1;
    }
    __syncthreads();
    float acc[FABLK] = {0,0,0,0,0,0,0,0};
    const float4* hb4 = reinterpret_cast<const float4*>(&hbuf[wv][0][0]);
#pragma unroll 4
    for (int c4 = 0; c4 < 128; ++c4) {
      float w2v0 = w2[(c4 * 4 + 0) * 64 + lane];
      float w2v1 = w2[(c4 * 4 + 1) * 64 + lane];
      float w2v2 = w2[(c4 * 4 + 2) * 64 + lane];
      float w2v3 = w2[(c4 * 4 + 3) * 64 + lane];
#pragma unroll
      for (int e = 0; e < FABLK; ++e) {
        float4 hq = hb4[e * 128 + c4];
        acc[e] = fmaf(hq.x, w2v0, acc[e]);
        acc[e] = fmaf(hq.y, w2v1, acc[e]);
        acc[e] = fmaf(hq.z, w2v2, acc[e]);
        acc[e] = fmaf(hq.w, w2v3, acc[e]);
      }
    }
#pragma unroll
    for (int e = 0; e < FABLK; ++e) {
      float val = y1_s[wv][e][lane] + acc[e] + b2v;
      float s1 = val, s2 = val * val;
#pragma unroll
      for (int mm = 1; mm < 64; mm <<= 1) {
        s1 += __shfl_xor(s1, mm, 64);
        s2 += __shfl_xor(s2, mm, 64);
      }
      float mu = s1 * 0.015625f;
      float var = s2 * 0.015625f - mu * mu;
      y2[(ag + e) * 64 + lane] = (val - mu) * rsqrtf(var + 1e-5f) * gg + bbb;
    }
    __syncthreads();
  }
}

// ============ mean-pool over tokens ============
__global__ void k_pool(const float* __restrict__ y2, float* __restrict__ pooled) {
  const int b = blockIdx.x, lane = threadIdx.x;
  float s = 0.f;
  for (int t = 0; t < 64; ++t) s += y2[(b * 64 + t) * 64 + lane];
  pooled[b * 64 + lane] = s * 0.015625f;
}

// ============ readout head ============
__global__ __launch_bounds__(256) void k_head(
    const float* __restrict__ pooled, const float* __restrict__ d1w,
    const float* __restrict__ d1b, const float* __restrict__ d2w,
    const float* __restrict__ d2b, float* __restrict__ out) {
  const int b = blockIdx.x;
  __shared__ float p_s[64];
  __shared__ float red_s[4];
  const int tid = threadIdx.x;
  if (tid < 64) p_s[tid] = pooled[b * 64 + tid];
  __syncthreads();
  float acc = 0.f;
#pragma unroll
  for (int rep = 0; rep < 2; ++rep) {
    int c = rep * 256 + tid;
    float hvv = d1b[c];
    for (int d = 0; d < 64; ++d) hvv += p_s[d] * d1w[d * 512 + c];
    acc += fmaxf(hvv, 0.f) * d2w[c];
  }
#pragma unroll
  for (int mm = 1; mm < 64; mm <<= 1) acc += __shfl_xor(acc, mm, 64);
  if ((tid & 63) == 0) red_s[tid >> 6] = acc;
  __syncthreads();
  if (tid == 0) {
    float t = red_s[0] + red_s[1] + red_s[2] + red_s[3] + d2b[0];
    out[b] = 1.0f / (1.0f + expf(-t));
  }
}

extern "C" void kernel_launch(void* const* d_in, const int* in_sizes, int n_in,
                              void* d_out, int out_size, void* d_ws, size_t ws_size,
                              hipStream_t stream) {
  (void)in_sizes; (void)n_in; (void)out_size; (void)ws_size;
  const float* af   = (const float*)d_in[0];
  const float* bfeat= (const float*)d_in[1];
  const int*   pairs= (const int*)d_in[2];
  // d_in[3] = molecule_indicator (identity layout; unused)
  const float* kern = (const float*)d_in[4];
  const float* kbias= (const float*)d_in[5];
  const float* wih  = (const float*)d_in[6];
  const float* whh  = (const float*)d_in[7];
  const float* bih  = (const float*)d_in[8];
  const float* bhh  = (const float*)d_in[9];
  const float* ipw  = (const float*)d_in[10];
  const float* ipb  = (const float*)d_in[11];
  const float* opw  = (const float*)d_in[12];
  const float* opb  = (const float*)d_in[13];
  const float* fw1  = (const float*)d_in[14];
  const float* fb1  = (const float*)d_in[15];
  const float* fw2  = (const float*)d_in[16];
  const float* fb2  = (const float*)d_in[17];
  const float* l1g  = (const float*)d_in[18];
  const float* l1b  = (const float*)d_in[19];
  const float* l2g  = (const float*)d_in[20];
  const float* l2b  = (const float*)d_in[21];
  const float* d1w  = (const float*)d_in[22];
  const float* d1b  = (const float*)d_in[23];
  const float* d2w  = (const float*)d_in[24];
  const float* d2b  = (const float*)d_in[25];
  float* out = (float*)d_out;

  // workspace layout (floats)
  float* ws = (float*)d_ws;
  float* h      = ws;
  float* agg    = h + (size_t)NA * 64;
  float* qkv    = agg + (size_t)NA * 64;
  float* ao     = qkv + (size_t)NA * 192;
  float* y1     = ao + (size_t)NA * 64;
  float* y2     = y1 + (size_t)NA * 64;
  float* pooled = y2 + (size_t)NA * 64;
  int*   valid  = (int*)(pooled + 256 * 64);

  // MP-loop scratch aliased into the qkv region (dead until after the loop):
  // Kr (36864 f) | count | start | cursor (NA ints each) | elist (NE ints) | bsum (64)
  float* Kr     = qkv;
  int*   count  = (int*)(qkv + 36864);
  int*   start  = count + NA;
  int*   cursor = start + NA;
  int*   elist  = cursor + NA;
  int*   bsum   = elist + NE;

  k_init_h<<<NA * 64 / 256, 256, 0, stream>>>(af, h);
  k_prep_Kr<<<144, 256, 0, stream>>>(kern, kbias, Kr);
  hipMemsetAsync(count, 0, (size_t)NA * sizeof(int), stream);
  k_count<<<NE / 256, 256, 0, stream>>>(pairs, count);
  k_scan1<<<64, 256, 0, stream>>>(count, bsum);
  k_scan2<<<64, 256, 0, stream>>>(count, bsum, start, cursor);
  k_place<<<NE / 256, 256, 0, stream>>>(pairs, cursor, elist);

  for (int s = 0; s < 4; ++s) {
    k_msg<<<NA / (MW * MA * 1), 256, 0, stream>>>(bfeat, pairs, h, start, count, elist, Kr, agg);
    k_gru<<<256, 512, 0, stream>>>(agg, wih, whh, bih, bhh, h);
  }
  k_qkv<<<512, 256, 0, stream>>>(h, ipw, ipb, qkv, valid);
  k_attn<<<2048, 64, 0, stream>>>(qkv, valid, ao);
  k_out_ln1<<<512, 256, 0, stream>>>(h, ao, opw, opb, l1g, l1b, y1);
  k_ffn<<<512, 256, 0, stream>>>(y1, fw1, fb1, fw2, fb2, l2g, l2b, y2);
  k_pool<<<256, 64, 0, stream>>>(y2, pooled);
  k_head<<<256, 256, 0, stream>>>(pooled, d1w, d1b, d2w, d2b, out);
}

// Round 7
// 407.703 us; speedup vs baseline: 1.0885x; 1.0885x over previous
//
#include <hip/hip_runtime.h>
#include <hip/hip_bf16.h>
#include <math.h>

#define NA 16384
#define NE 65536
#define AD 29

__device__ __forceinline__ float sigmoidf_(float x) { return 1.0f / (1.0f + expf(-x)); }

// ============ init h: pad atom features 29 -> 64 ============
__global__ void k_init_h(const float* __restrict__ af, float* __restrict__ h) {
  int idx = blockIdx.x * 256 + threadIdx.x;
  if (idx >= NA * 64) return;
  int a = idx >> 6, d = idx & 63;
  h[idx] = (d < AD) ? af[a * AD + d] : 0.0f;
}

// ============ Kr relayout (once per call): Kr4[(k9*16+j4)*64 + i] = K[k9][i][4j4..+3]
// (k9==8 is the bias matrix). Lane i then reads its float4 coalesced.
__global__ void k_prep_Kr(const float* __restrict__ kern, const float* __restrict__ kbias,
                          float* __restrict__ Kr) {
  int f = blockIdx.x * 256 + threadIdx.x;    // 9*16*64*4 = 36864 floats
  if (f >= 36864) return;
  int t = f & 3, i = (f >> 2) & 63, j4 = (f >> 8) & 15, k9 = f >> 12;
  int col = j4 * 4 + t;
  Kr[f] = (k9 < 8) ? kern[k9 * 4096 + i * 64 + col] : kbias[i * 64 + col];
}

// ============ edge bucketing by src (once per call; counting sort) ============
__global__ void k_count(const int* __restrict__ pairs, int* __restrict__ count) {
  int e = blockIdx.x * 256 + threadIdx.x;
  if (e >= NE) return;
  atomicAdd(&count[pairs[2 * e]], 1);
}
__global__ void k_scan1(const int* __restrict__ count, int* __restrict__ bsum) {
  __shared__ int red[256];
  int b = blockIdx.x, t = threadIdx.x;
  red[t] = count[b * 256 + t];
  __syncthreads();
  for (int s = 128; s > 0; s >>= 1) { if (t < s) red[t] += red[t + s]; __syncthreads(); }
  if (t == 0) bsum[b] = red[0];
}
__global__ void k_scan2(const int* __restrict__ count, const int* __restrict__ bsum,
                        int* __restrict__ start, int* __restrict__ cursor) {
  __shared__ int sc[256];
  __shared__ int basev;
  int b = blockIdx.x, t = threadIdx.x;
  if (t == 0) { int s = 0; for (int i = 0; i < b; ++i) s += bsum[i]; basev = s; }
  int v = count[b * 256 + t];
  sc[t] = v;
  __syncthreads();
  for (int off = 1; off < 256; off <<= 1) {
    int add = (t >= off) ? sc[t - off] : 0;
    __syncthreads();
    sc[t] += add;
    __syncthreads();
  }
  int excl = sc[t] - v + basev;
  start[b * 256 + t] = excl;
  cursor[b * 256 + t] = excl;
  if (b * 256 + t == NA - 1) start[NA] = excl + v;   // sentinel = NE
}
__global__ void k_place(const int* __restrict__ pairs, int* __restrict__ cursor,
                        int* __restrict__ elist) {
  int e = blockIdx.x * 256 + threadIdx.x;
  if (e >= NE) return;
  int pos = atomicAdd(&cursor[pairs[2 * e]], 1);
  elist[pos] = e;
}
// sorted edge payloads: sdst[pos] = dst of elist[pos]; sbf[pos*8+k] = bf[elist[pos]][k]
__global__ void k_reorder(const float* __restrict__ bf, const int* __restrict__ pairs,
                          const int* __restrict__ elist, int* __restrict__ sdst,
                          float* __restrict__ sbf) {
  int idx = blockIdx.x * 256 + threadIdx.x;    // NE*8 threads
  if (idx >= NE * 8) return;
  int pos = idx >> 3, k = idx & 7;
  int e = elist[pos];
  sbf[idx] = bf[e * 8 + k];
  if (k == 0) sdst[pos] = pairs[2 * e + 1];
}

// ============ fused message step ============
// agg[a][i] = sum_{k,j} K[k][i][j] * T[a][k][j],
// T[a][k][j] = sum_{e: src=a} bf[e][k]*h[dst_e][j]  (k=8 slab: bias, bf=1).
// Phase A: wave owns 8 atoms = one contiguous sorted-edge range; edges
// processed in batches of 8 with static-indexed register arrays so 8 h-gathers
// are in flight at once (round-6 version chased elist->pairs->h serially).
// Run boundaries flushed to LDS with plain writes (one flush per atom; no
// atomics anywhere). Phase B: lane = output i; Kr streamed coalesced, T
// broadcast from LDS, 8 atoms amortize each Kr load.
#define MW 4
#define MAW 8
__global__ __launch_bounds__(256, 2) void k_msg(
    const float* __restrict__ h, const int* __restrict__ start,
    const int* __restrict__ sdst, const float* __restrict__ sbf,
    const float* __restrict__ Kr, float* __restrict__ agg) {
  __shared__ __align__(16) float T_s[MW * MAW][576];   // 73,728 B
  const int tid = threadIdx.x, lane = tid & 63, wv = tid >> 6;
  const int awave = blockIdx.x * (MW * MAW) + wv * MAW;

  // zero T (block-strided; covers zero-edge atoms)
  float4* tz = reinterpret_cast<float4*>(&T_s[0][0]);
  for (int i = tid; i < MW * MAW * 144; i += 256) tz[i] = make_float4(0.f, 0.f, 0.f, 0.f);

  // the wave's 9 run boundaries live in lanes 0..8 (start[NA] sentinel = NE)
  const int bb = (lane <= MAW) ? start[awave + lane] : 0;
  const int rs = __shfl(bb, 0, 64);
  const int re = __shfl(bb, MAW, 64);
  __syncthreads();

  float t[9];
#pragma unroll
  for (int k = 0; k < 9; ++k) t[k] = 0.f;
  int cura = 0;
  int nextb = __shfl(bb, 1, 64);

  for (int base = rs; base < re; base += 8) {
    const int nb = re - base;                    // active lanes this batch: min(8,nb)
    int d[8]; float bq[8], hv[8];
#pragma unroll
    for (int i = 0; i < 8; ++i) d[i] = (i < nb) ? sdst[base + i] : 0;
#pragma unroll
    for (int i = 0; i < 8; ++i)
      bq[i] = (i < nb && lane < 8) ? sbf[(base + i) * 8 + lane] : 0.f;
#pragma unroll
    for (int i = 0; i < 8; ++i) hv[i] = (i < nb) ? h[d[i] * 64 + lane] : 0.f;
#pragma unroll
    for (int i = 0; i < 8; ++i) {
      if (i < nb) {
        const int pos = base + i;
        while (pos >= nextb) {                   // crossed atom boundary: flush run
#pragma unroll
          for (int k = 0; k < 9; ++k) { T_s[wv * MAW + cura][k * 64 + lane] = t[k]; t[k] = 0.f; }
          ++cura;
          nextb = __shfl(bb, cura + 1, 64);
        }
#pragma unroll
        for (int k = 0; k < 8; ++k) t[k] = fmaf(__shfl(bq[i], k, 64), hv[i], t[k]);
        t[8] += hv[i];
      }
    }
  }
  if (re > rs) {                                 // flush last run
#pragma unroll
    for (int k = 0; k < 9; ++k) T_s[wv * MAW + cura][k * 64 + lane] = t[k];
  }
  __syncthreads();

  // Phase B: matvec per atom
  float acc[MAW];
#pragma unroll
  for (int a = 0; a < MAW; ++a) acc[a] = 0.f;
  const float4* Kr4 = reinterpret_cast<const float4*>(Kr);
  const float4* Ts4 = reinterpret_cast<const float4*>(&T_s[wv * MAW][0]);
#pragma unroll 2
  for (int kj = 0; kj < 144; ++kj) {
    float4 Kv = Kr4[kj * 64 + lane];
#pragma unroll
    for (int a = 0; a < MAW; ++a) {
      float4 Tv = Ts4[a * 144 + kj];             // broadcast read
      acc[a] = fmaf(Kv.x, Tv.x, acc[a]);
      acc[a] = fmaf(Kv.y, Tv.y, acc[a]);
      acc[a] = fmaf(Kv.z, Tv.z, acc[a]);
      acc[a] = fmaf(Kv.w, Tv.w, acc[a]);
    }
  }
#pragma unroll
  for (int a = 0; a < MAW; ++a) agg[(awave + a) * 64 + lane] = acc[a];
}

// ============ GRU cell (per atom) ============
#define GABLK 4
__global__ __launch_bounds__(512, 1) void k_gru(
    const float* __restrict__ agg, const float* __restrict__ wih,
    const float* __restrict__ whh, const float* __restrict__ bih,
    const float* __restrict__ bhh, float* __restrict__ h) {
  __shared__ __align__(16) float wih_s[192 * 64];
  __shared__ __align__(16) float whh_s[192 * 64];
  __shared__ __align__(16) float act_s[8][2][GABLK][64];
  const int tid = threadIdx.x, lane = tid & 63, wv = tid >> 6;

  for (int idx = tid; idx < 192 * 64; idx += 512) {
    int r = idx >> 6, d = idx & 63;
    int pos = (r << 6) + ((((d >> 2) ^ (r & 7)) << 2) | (d & 3));
    wih_s[pos] = wih[idx];
    whh_s[pos] = whh[idx];
  }
  __syncthreads();

  const float4* wi4 = reinterpret_cast<const float4*>(wih_s);
  const float4* wh4 = reinterpret_cast<const float4*>(whh_s);
  const float bir = bih[lane], biz = bih[64 + lane], bin_ = bih[128 + lane];
  const float bhr = bhh[lane], bhz = bhh[64 + lane], bhn = bhh[128 + lane];
  const int swz = lane & 7;
  const int gw = blockIdx.x * 8 + wv;
  const int stride = gridDim.x * 8 * GABLK;

  for (int ag = gw * GABLK; ag < NA; ag += stride) {
#pragma unroll
    for (int e = 0; e < GABLK; ++e) {
      act_s[wv][0][e][lane] = agg[(ag + e) * 64 + lane];
      act_s[wv][1][e][lane] = h[(ag + e) * 64 + lane];
    }
    __syncthreads();
    const float4* a4 = reinterpret_cast<const float4*>(&act_s[wv][0][0][0]);
    const float4* h4 = reinterpret_cast<const float4*>(&act_s[wv][1][0][0]);
    float air[GABLK] = {0,0,0,0}, aiz[GABLK] = {0,0,0,0}, ain[GABLK] = {0,0,0,0};
    float ahr[GABLK] = {0,0,0,0}, ahz[GABLK] = {0,0,0,0}, ahn[GABLK] = {0,0,0,0};
#pragma unroll 2
    for (int d4 = 0; d4 < 16; ++d4) {
      int sl = d4 ^ swz;
      float4 wir = wi4[(lane << 4) + sl];
      float4 wiz = wi4[((lane + 64) << 4) + sl];
      float4 win = wi4[((lane + 128) << 4) + sl];
      float4 whr = wh4[(lane << 4) + sl];
      float4 whz = wh4[((lane + 64) << 4) + sl];
      float4 whn = wh4[((lane + 128) << 4) + sl];
#pragma unroll
      for (int e = 0; e < GABLK; ++e) {
        float4 av = a4[e * 16 + d4];
        float4 hv = h4[e * 16 + d4];
        air[e] += wir.x*av.x + wir.y*av.y + wir.z*av.z + wir.w*av.w;
        aiz[e] += wiz.x*av.x + wiz.y*av.y + wiz.z*av.z + wiz.w*av.w;
        ain[e] += win.x*av.x + win.y*av.y + win.z*av.z + win.w*av.w;
        ahr[e] += whr.x*hv.x + whr.y*hv.y + whr.z*hv.z + whr.w*hv.w;
        ahz[e] += whz.x*hv.x + whz.y*hv.y + whz.z*hv.z + whz.w*hv.w;
        ahn[e] += whn.x*hv.x + whn.y*hv.y + whn.z*hv.z + whn.w*hv.w;
      }
    }
#pragma unroll
    for (int e = 0; e < GABLK; ++e) {
      float r = sigmoidf_((air[e] + bir) + (ahr[e] + bhr));
      float z = sigmoidf_((aiz[e] + biz) + (ahz[e] + bhz));
      float nn = tanhf((ain[e] + bin_) + r * (ahn[e] + bhn));
      float hold = act_s[wv][1][e][lane];
      h[(ag + e) * 64 + lane] = (1.0f - z) * nn + z * hold;
    }
    __syncthreads();
  }
}

// ============ qkv projection + valid mask ============
#define QABLK 4
__global__ __launch_bounds__(256, 1) void k_qkv(
    const float* __restrict__ h, const float* __restrict__ w,
    const float* __restrict__ b, float* __restrict__ qkv,
    int* __restrict__ valid) {
  __shared__ __align__(16) float w_s[192 * 64];
  __shared__ __align__(16) float x_s[4][QABLK][64];
  const int tid = threadIdx.x, lane = tid & 63, wv = tid >> 6;
  for (int idx = tid; idx < 192 * 64; idx += 256) {
    int r = idx >> 6, d = idx & 63;
    w_s[(r << 6) + ((((d >> 2) ^ (r & 7)) << 2) | (d & 3))] = w[idx];
  }
  __syncthreads();
  const float4* w4 = reinterpret_cast<const float4*>(w_s);
  const float bq = b[lane], bk = b[64 + lane], bv_ = b[128 + lane];
  const int swz = lane & 7;
  const int gw = blockIdx.x * 4 + wv;
  const int stride = gridDim.x * 4 * QABLK;
  for (int ag = gw * QABLK; ag < NA; ag += stride) {
#pragma unroll
    for (int e = 0; e < QABLK; ++e) x_s[wv][e][lane] = h[(ag + e) * 64 + lane];
    __syncthreads();
    const float4* x4 = reinterpret_cast<const float4*>(&x_s[wv][0][0]);
    float aq[QABLK] = {0,0,0,0}, ak[QABLK] = {0,0,0,0}, av_[QABLK] = {0,0,0,0};
    int nz[QABLK] = {0,0,0,0};
#pragma unroll 4
    for (int d4 = 0; d4 < 16; ++d4) {
      int sl = d4 ^ swz;
      float4 wq = w4[(lane << 4) + sl];
      float4 wk = w4[((lane + 64) << 4) + sl];
      float4 wvv = w4[((lane + 128) << 4) + sl];
#pragma unroll
      for (int e = 0; e < QABLK; ++e) {
        float4 xv = x4[e * 16 + d4];
        aq[e] += wq.x*xv.x + wq.y*xv.y + wq.z*xv.z + wq.w*xv.w;
        ak[e] += wk.x*xv.x + wk.y*xv.y + wk.z*xv.z + wk.w*xv.w;
        av_[e] += wvv.x*xv.x + wvv.y*xv.y + wvv.z*xv.z + wvv.w*xv.w;
        nz[e] |= (int)(xv.x != 0.f) | (int)(xv.y != 0.f) | (int)(xv.z != 0.f) | (int)(xv.w != 0.f);
      }
    }
#pragma unroll
    for (int e = 0; e < QABLK; ++e) {
      qkv[(ag + e) * 192 + lane] = aq[e] + bq;
      qkv[(ag + e) * 192 + 64 + lane] = ak[e] + bk;
      qkv[(ag + e) * 192 + 128 + lane] = av_[e] + bv_;
      if (lane == 0) valid[ag + e] = nz[e];
    }
    __syncthreads();
  }
}

// ============ attention: one wave per (molecule, head), online softmax ============
__global__ void k_attn(const float* __restrict__ qkv, const int* __restrict__ valid,
                       float* __restrict__ ao) {
  const int b = blockIdx.x >> 3, hh = blockIdx.x & 7;
  __shared__ float k_s[64][8];
  __shared__ float v_s[64][8];
  __shared__ int vd_s[64];
  const int lane = threadIdx.x;
  const int rowbase = (b * 64 + lane) * 192;
#pragma unroll
  for (int j = 0; j < 8; ++j) {
    k_s[lane][j] = qkv[rowbase + 64 + hh * 8 + j];
    v_s[lane][j] = qkv[rowbase + 128 + hh * 8 + j];
  }
  vd_s[lane] = valid[b * 64 + lane];
  __syncthreads();
  float q[8];
#pragma unroll
  for (int j = 0; j < 8; ++j) q[j] = qkv[rowbase + hh * 8 + j];
  float m = -3.0e38f, l = 0.f, o[8] = {0,0,0,0,0,0,0,0};
  for (int t = 0; t < 64; ++t) {
    float s = 0.f;
#pragma unroll
    for (int j = 0; j < 8; ++j) s += q[j] * k_s[t][j];
    s *= 0.35355339059327373f;
    s = vd_s[t] ? s : -1.0e9f;
    float mn = fmaxf(m, s);
    float c = expf(m - mn);
    float p = expf(s - mn);
    l = l * c + p;
#pragma unroll
    for (int j = 0; j < 8; ++j) o[j] = o[j] * c + p * v_s[t][j];
    m = mn;
  }
  const float inv = 1.0f / l;
  const int obase = (b * 64 + lane) * 64 + hh * 8;
#pragma unroll
  for (int j = 0; j < 8; ++j) ao[obase + j] = o[j] * inv;
}

// ============ out_proj + residual + LN1 ============
#define OABLK 4
__global__ __launch_bounds__(256, 1) void k_out_ln1(
    const float* __restrict__ x, const float* __restrict__ ao,
    const float* __restrict__ w, const float* __restrict__ bias,
    const float* __restrict__ g, const float* __restrict__ bb,
    float* __restrict__ y1) {
  __shared__ __align__(16) float w_s[64 * 64];
  __shared__ __align__(16) float a_s[4][OABLK][64];
  const int tid = threadIdx.x, lane = tid & 63, wv = tid >> 6;
  for (int idx = tid; idx < 64 * 64; idx += 256) {
    int r = idx >> 6, d = idx & 63;
    w_s[(r << 6) + ((((d >> 2) ^ (r & 7)) << 2) | (d & 3))] = w[idx];
  }
  __syncthreads();
  const float4* w4 = reinterpret_cast<const float4*>(w_s);
  const float bo = bias[lane], gg = g[lane], bbb = bb[lane];
  const int swz = lane & 7;
  const int gw = blockIdx.x * 4 + wv;
  const int stride = gridDim.x * 4 * OABLK;
  for (int ag = gw * OABLK; ag < NA; ag += stride) {
#pragma unroll
    for (int e = 0; e < OABLK; ++e) a_s[wv][e][lane] = ao[(ag + e) * 64 + lane];
    __syncthreads();
    const float4* a4 = reinterpret_cast<const float4*>(&a_s[wv][0][0]);
    float acc[OABLK] = {0,0,0,0};
#pragma unroll 4
    for (int d4 = 0; d4 < 16; ++d4) {
      int sl = d4 ^ swz;
      float4 wr = w4[(lane << 4) + sl];
#pragma unroll
      for (int e = 0; e < OABLK; ++e) {
        float4 av = a4[e * 16 + d4];
        acc[e] += wr.x*av.x + wr.y*av.y + wr.z*av.z + wr.w*av.w;
      }
    }
#pragma unroll
    for (int e = 0; e < OABLK; ++e) {
      float val = acc[e] + bo + x[(ag + e) * 64 + lane];
      float s1 = val, s2 = val * val;
#pragma unroll
      for (int mm = 1; mm < 64; mm <<= 1) {
        s1 += __shfl_xor(s1, mm, 64);
        s2 += __shfl_xor(s2, mm, 64);
      }
      float mu = s1 * 0.015625f;
      float var = s2 * 0.015625f - mu * mu;
      y1[(ag + e) * 64 + lane] = (val - mu) * rsqrtf(var + 1e-5f) * gg + bbb;
    }
    __syncthreads();
  }
}

// ============ FFN (512 hidden) + residual + LN2 ============
#define FW 4
#define FABLK 8
__global__ __launch_bounds__(256, 2) void k_ffn(
    const float* __restrict__ y1, const float* __restrict__ w1,
    const float* __restrict__ b1, const float* __restrict__ w2,
    const float* __restrict__ b2, const float* __restrict__ g,
    const float* __restrict__ bb, float* __restrict__ y2) {
  __shared__ __align__(16) float hbuf[FW][FABLK][512];   // 64 KB
  __shared__ __align__(16) float y1_s[FW][FABLK][64];    // 8 KB
  const int tid = threadIdx.x, lane = tid & 63, wv = tid >> 6;
  const float4* w1_4 = reinterpret_cast<const float4*>(w1);
  const float4* b1_4 = reinterpret_cast<const float4*>(b1);
  const float b2v = b2[lane], gg = g[lane], bbb = bb[lane];
  const int gw = blockIdx.x * FW + wv;
  const int stride = gridDim.x * FW * FABLK;
  for (int ag = gw * FABLK; ag < NA; ag += stride) {
#pragma unroll
    for (int e = 0; e < FABLK; ++e) y1_s[wv][e][lane] = y1[(ag + e) * 64 + lane];
    __syncthreads();
    float4 hv0[FABLK], hv1[FABLK];
    const float4 bq0 = b1_4[lane], bq1 = b1_4[64 + lane];
#pragma unroll
    for (int e = 0; e < FABLK; ++e) { hv0[e] = bq0; hv1[e] = bq1; }
#pragma unroll 4
    for (int d = 0; d < 64; ++d) {
      float4 w0 = w1_4[d * 128 + lane];
      float4 w1v = w1_4[d * 128 + 64 + lane];
#pragma unroll
      for (int e = 0; e < FABLK; ++e) {
        float yv = y1_s[wv][e][d];
        hv0[e].x = fmaf(yv, w0.x, hv0[e].x);
        hv0[e].y = fmaf(yv, w0.y, hv0[e].y);
        hv0[e].z = fmaf(yv, w0.z, hv0[e].z);
        hv0[e].w = fmaf(yv, w0.w, hv0[e].w);
        hv1[e].x = fmaf(yv, w1v.x, hv1[e].x);
        hv1[e].y = fmaf(yv, w1v.y, hv1[e].y);
        hv1[e].z = fmaf(yv, w1v.z, hv1[e].z);
        hv1[e].w = fmaf(yv, w1v.w, hv1[e].w);
      }
    }
    float4* hb4w = reinterpret_cast<float4*>(&hbuf[wv][0][0]);
#pragma unroll
    for (int e = 0; e < FABLK; ++e) {
      float4 r0 = hv0[e], r1 = hv1[e];
      r0.x = fmaxf(r0.x, 0.f); r0.y = fmaxf(r0.y, 0.f);
      r0.z = fmaxf(r0.z, 0.f); r0.w = fmaxf(r0.w, 0.f);
      r1.x = fmaxf(r1.x, 0.f); r1.y = fmaxf(r1.y, 0.f);
      r1.z = fmaxf(r1.z, 0.f); r1.w = fmaxf(r1.w, 0.f);
      hb4w[e * 128 + lane] = r0;
      hb4w[e * 128 + 64 + lane] = r1;
    }
    __syncthreads();
    float acc[FABLK] = {0,0,0,0,0,0,0,0};
    const float4* hb4 = reinterpret_cast<const float4*>(&hbuf[wv][0][0]);
#pragma unroll 4
    for (int c4 = 0; c4 < 128; ++c4) {
      float w2v0 = w2[(c4 * 4 + 0) * 64 + lane];
      float w2v1 = w2[(c4 * 4 + 1) * 64 + lane];
      float w2v2 = w2[(c4 * 4 + 2) * 64 + lane];
      float w2v3 = w2[(c4 * 4 + 3) * 64 + lane];
#pragma unroll
      for (int e = 0; e < FABLK; ++e) {
        float4 hq = hb4[e * 128 + c4];
        acc[e] = fmaf(hq.x, w2v0, acc[e]);
        acc[e] = fmaf(hq.y, w2v1, acc[e]);
        acc[e] = fmaf(hq.z, w2v2, acc[e]);
        acc[e] = fmaf(hq.w, w2v3, acc[e]);
      }
    }
#pragma unroll
    for (int e = 0; e < FABLK; ++e) {
      float val = y1_s[wv][e][lane] + acc[e] + b2v;
      float s1 = val, s2 = val * val;
#pragma unroll
      for (int mm = 1; mm < 64; mm <<= 1) {
        s1 += __shfl_xor(s1, mm, 64);
        s2 += __shfl_xor(s2, mm, 64);
      }
      float mu = s1 * 0.015625f;
      float var = s2 * 0.015625f - mu * mu;
      y2[(ag + e) * 64 + lane] = (val - mu) * rsqrtf(var + 1e-5f) * gg + bbb;
    }
    __syncthreads();
  }
}

// ============ mean-pool over tokens ============
__global__ void k_pool(const float* __restrict__ y2, float* __restrict__ pooled) {
  const int b = blockIdx.x, lane = threadIdx.x;
  float s = 0.f;
  for (int t = 0; t < 64; ++t) s += y2[(b * 64 + t) * 64 + lane];
  pooled[b * 64 + lane] = s * 0.015625f;
}

// ============ readout head ============
__global__ __launch_bounds__(256) void k_head(
    const float* __restrict__ pooled, const float* __restrict__ d1w,
    const float* __restrict__ d1b, const float* __restrict__ d2w,
    const float* __restrict__ d2b, float* __restrict__ out) {
  const int b = blockIdx.x;
  __shared__ float p_s[64];
  __shared__ float red_s[4];
  const int tid = threadIdx.x;
  if (tid < 64) p_s[tid] = pooled[b * 64 + tid];
  __syncthreads();
  float acc = 0.f;
#pragma unroll
  for (int rep = 0; rep < 2; ++rep) {
    int c = rep * 256 + tid;
    float hvv = d1b[c];
    for (int d = 0; d < 64; ++d) hvv += p_s[d] * d1w[d * 512 + c];
    acc += fmaxf(hvv, 0.f) * d2w[c];
  }
#pragma unroll
  for (int mm = 1; mm < 64; mm <<= 1) acc += __shfl_xor(acc, mm, 64);
  if ((tid & 63) == 0) red_s[tid >> 6] = acc;
  __syncthreads();
  if (tid == 0) {
    float t = red_s[0] + red_s[1] + red_s[2] + red_s[3] + d2b[0];
    out[b] = 1.0f / (1.0f + expf(-t));
  }
}

extern "C" void kernel_launch(void* const* d_in, const int* in_sizes, int n_in,
                              void* d_out, int out_size, void* d_ws, size_t ws_size,
                              hipStream_t stream) {
  (void)in_sizes; (void)n_in; (void)out_size; (void)ws_size;
  const float* af   = (const float*)d_in[0];
  const float* bfeat= (const float*)d_in[1];
  const int*   pairs= (const int*)d_in[2];
  // d_in[3] = molecule_indicator (identity layout; unused)
  const float* kern = (const float*)d_in[4];
  const float* kbias= (const float*)d_in[5];
  const float* wih  = (const float*)d_in[6];
  const float* whh  = (const float*)d_in[7];
  const float* bih  = (const float*)d_in[8];
  const float* bhh  = (const float*)d_in[9];
  const float* ipw  = (const float*)d_in[10];
  const float* ipb  = (const float*)d_in[11];
  const float* opw  = (const float*)d_in[12];
  const float* opb  = (const float*)d_in[13];
  const float* fw1  = (const float*)d_in[14];
  const float* fb1  = (const float*)d_in[15];
  const float* fw2  = (const float*)d_in[16];
  const float* fb2  = (const float*)d_in[17];
  const float* l1g  = (const float*)d_in[18];
  const float* l1b  = (const float*)d_in[19];
  const float* l2g  = (const float*)d_in[20];
  const float* l2b  = (const float*)d_in[21];
  const float* d1w  = (const float*)d_in[22];
  const float* d1b  = (const float*)d_in[23];
  const float* d2w  = (const float*)d_in[24];
  const float* d2b  = (const float*)d_in[25];
  float* out = (float*)d_out;

  // workspace layout (floats)
  float* ws = (float*)d_ws;
  float* h      = ws;
  float* agg    = h + (size_t)NA * 64;
  float* qkv    = agg + (size_t)NA * 64;
  float* ao     = qkv + (size_t)NA * 192;
  float* y1     = ao + (size_t)NA * 64;
  float* y2     = y1 + (size_t)NA * 64;
  float* pooled = y2 + (size_t)NA * 64;
  int*   valid  = (int*)(pooled + 256 * 64);

  // MP-loop scratch aliased into the qkv region (dead until after the loop):
  // Kr | count(NA) | start(NA+1) | cursor(NA) | elist(NE) | bsum(256) | sdst(NE) | sbf(8*NE)
  float* Kr     = qkv;
  int*   count  = (int*)(qkv + 36864);
  int*   start  = count + NA;
  int*   cursor = start + NA + 1;
  int*   elist  = cursor + NA;
  int*   bsum   = elist + NE;
  int*   sdst   = bsum + 256;
  float* sbf    = (float*)(sdst + NE);

  k_init_h<<<NA * 64 / 256, 256, 0, stream>>>(af, h);
  k_prep_Kr<<<144, 256, 0, stream>>>(kern, kbias, Kr);
  hipMemsetAsync(count, 0, (size_t)NA * sizeof(int), stream);
  k_count<<<NE / 256, 256, 0, stream>>>(pairs, count);
  k_scan1<<<64, 256, 0, stream>>>(count, bsum);
  k_scan2<<<64, 256, 0, stream>>>(count, bsum, start, cursor);
  k_place<<<NE / 256, 256, 0, stream>>>(pairs, cursor, elist);
  k_reorder<<<NE * 8 / 256, 256, 0, stream>>>(bfeat, pairs, elist, sdst, sbf);

  for (int s = 0; s < 4; ++s) {
    k_msg<<<NA / (MW * MAW), 256, 0, stream>>>(h, start, sdst, sbf, Kr, agg);
    k_gru<<<256, 512, 0, stream>>>(agg, wih, whh, bih, bhh, h);
  }
  k_qkv<<<512, 256, 0, stream>>>(h, ipw, ipb, qkv, valid);
  k_attn<<<2048, 64, 0, stream>>>(qkv, valid, ao);
  k_out_ln1<<<512, 256, 0, stream>>>(h, ao, opw, opb, l1g, l1b, y1);
  k_ffn<<<512, 256, 0, stream>>>(y1, fw1, fb1, fw2, fb2, l2g, l2b, y2);
  k_pool<<<256, 64, 0, stream>>>(y2, pooled);
  k_head<<<256, 256, 0, stream>>>(pooled, d1w, d1b, d2w, d2b, out);
}

// Round 8
// 405.423 us; speedup vs baseline: 1.0947x; 1.0056x over previous
//
#include <hip/hip_runtime.h>
#include <hip/hip_bf16.h>
#include <math.h>

#define NA 16384
#define NE 65536
#define AD 29

__device__ __forceinline__ float sigmoidf_(float x) { return 1.0f / (1.0f + expf(-x)); }

// ============ init h: pad atom features 29 -> 64 ============
__global__ void k_init_h(const float* __restrict__ af, float* __restrict__ h) {
  int idx = blockIdx.x * 256 + threadIdx.x;
  if (idx >= NA * 64) return;
  int a = idx >> 6, d = idx & 63;
  h[idx] = (d < AD) ? af[a * AD + d] : 0.0f;
}

// ============ Kr relayout (once per call): Kr4[(k9*16+j4)*64 + i] = K[k9][i][4j4..+3]
__global__ void k_prep_Kr(const float* __restrict__ kern, const float* __restrict__ kbias,
                          float* __restrict__ Kr) {
  int f = blockIdx.x * 256 + threadIdx.x;    // 9*16*64*4 = 36864 floats
  if (f >= 36864) return;
  int t = f & 3, i = (f >> 2) & 63, j4 = (f >> 8) & 15, k9 = f >> 12;
  int col = j4 * 4 + t;
  Kr[f] = (k9 < 8) ? kern[k9 * 4096 + i * 64 + col] : kbias[i * 64 + col];
}

// ============ GRU weight transpose (once per call): wT[j*192+r] = w[r*64+j]
__global__ void k_prep_wT(const float* __restrict__ wih, const float* __restrict__ whh,
                          float* __restrict__ wihT, float* __restrict__ whhT) {
  int idx = blockIdx.x * 256 + threadIdx.x;
  if (idx >= 192 * 64) return;
  int r = idx >> 6, j = idx & 63;
  wihT[j * 192 + r] = wih[idx];
  whhT[j * 192 + r] = whh[idx];
}

// ============ edge bucketing by src (once per call; counting sort) ============
__global__ void k_count(const int* __restrict__ pairs, int* __restrict__ count) {
  int e = blockIdx.x * 256 + threadIdx.x;
  if (e >= NE) return;
  atomicAdd(&count[pairs[2 * e]], 1);
}
__global__ void k_scan1(const int* __restrict__ count, int* __restrict__ bsum) {
  __shared__ int red[256];
  int b = blockIdx.x, t = threadIdx.x;
  red[t] = count[b * 256 + t];
  __syncthreads();
  for (int s = 128; s > 0; s >>= 1) { if (t < s) red[t] += red[t + s]; __syncthreads(); }
  if (t == 0) bsum[b] = red[0];
}
__global__ void k_scan2(const int* __restrict__ count, const int* __restrict__ bsum,
                        int* __restrict__ start, int* __restrict__ cursor) {
  __shared__ int sc[256];
  __shared__ int basev;
  int b = blockIdx.x, t = threadIdx.x;
  if (t == 0) { int s = 0; for (int i = 0; i < b; ++i) s += bsum[i]; basev = s; }
  int v = count[b * 256 + t];
  sc[t] = v;
  __syncthreads();
  for (int off = 1; off < 256; off <<= 1) {
    int add = (t >= off) ? sc[t - off] : 0;
    __syncthreads();
    sc[t] += add;
    __syncthreads();
  }
  int excl = sc[t] - v + basev;
  start[b * 256 + t] = excl;
  cursor[b * 256 + t] = excl;
  if (b * 256 + t == NA - 1) start[NA] = excl + v;   // sentinel = NE
}
__global__ void k_place(const int* __restrict__ pairs, int* __restrict__ cursor,
                        int* __restrict__ elist) {
  int e = blockIdx.x * 256 + threadIdx.x;
  if (e >= NE) return;
  int pos = atomicAdd(&cursor[pairs[2 * e]], 1);
  elist[pos] = e;
}
__global__ void k_reorder(const float* __restrict__ bf, const int* __restrict__ pairs,
                          const int* __restrict__ elist, int* __restrict__ sdst,
                          float* __restrict__ sbf) {
  int idx = blockIdx.x * 256 + threadIdx.x;    // NE*8 threads
  if (idx >= NE * 8) return;
  int pos = idx >> 3, k = idx & 7;
  int e = elist[pos];
  sbf[idx] = bf[e * 8 + k];
  if (k == 0) sdst[pos] = pairs[2 * e + 1];
}

// ============ fused message + GRU step ============
// Phase A: gather T[a][k][j] = sum_{e:src=a} bf[e][k]*h_in[dst_e][j] (k=8: bias)
//          into registers (lane=j), 8-edge batches (8 h-gathers in flight),
//          flushed per-atom to LDS. Sorted-edge payloads, no atomics.
// Phase B: agg[a][i=lane] = sum_{kj} Kr[kj][i] . T[a][kj]; Kr streamed
//          coalesced from L2 with unroll-4 pipeline; T broadcast from LDS.
// Phase C: GRU applied in-register (agg never touches memory): per j, 6
//          coalesced wT loads amortized over 8 atoms; agg/h broadcast by shfl.
// h ping-pong (h_in read-only, h_out own-atoms only) keeps blocks race-free.
#define MW 4
#define MAW 8
__global__ __launch_bounds__(256, 2) void k_msg(
    const float* __restrict__ h_in, const int* __restrict__ start,
    const int* __restrict__ sdst, const float* __restrict__ sbf,
    const float* __restrict__ Kr, const float* __restrict__ wihT,
    const float* __restrict__ whhT, const float* __restrict__ bih,
    const float* __restrict__ bhh, float* __restrict__ h_out) {
  __shared__ __align__(16) float T_s[MW * MAW][576];   // 73,728 B
  const int tid = threadIdx.x, lane = tid & 63, wv = tid >> 6;
  const int awave = blockIdx.x * (MW * MAW) + wv * MAW;

  // zero T (block-strided; covers zero-edge atoms)
  float4* tz = reinterpret_cast<float4*>(&T_s[0][0]);
  for (int i = tid; i < MW * MAW * 144; i += 256) tz[i] = make_float4(0.f, 0.f, 0.f, 0.f);

  // wave's 9 run boundaries in lanes 0..8 (start[NA] sentinel = NE)
  const int bb = (lane <= MAW) ? start[awave + lane] : 0;
  const int rs = __shfl(bb, 0, 64);
  const int re = __shfl(bb, MAW, 64);
  __syncthreads();                               // zeroing done before flushes

  float t[9];
#pragma unroll
  for (int k = 0; k < 9; ++k) t[k] = 0.f;
  int cura = 0;
  int nextb = __shfl(bb, 1, 64);

  for (int base = rs; base < re; base += 8) {
    const int nb = re - base;                    // active edges this batch: min(8,nb)
    const float bqall = sbf[base * 8 + lane];    // 8 edges x 8 k, coalesced
    int dc[8]; float hv[8];
#pragma unroll
    for (int i = 0; i < 8; ++i) dc[i] = (i < nb) ? sdst[base + i] : 0;
#pragma unroll
    for (int i = 0; i < 8; ++i) hv[i] = (i < nb) ? h_in[dc[i] * 64 + lane] : 0.f;
#pragma unroll
    for (int i = 0; i < 8; ++i) {
      if (i < nb) {
        const int pos = base + i;
        while (pos >= nextb) {                   // crossed atom boundary: flush run
#pragma unroll
          for (int k = 0; k < 9; ++k) { T_s[wv * MAW + cura][k * 64 + lane] = t[k]; t[k] = 0.f; }
          ++cura;
          nextb = __shfl(bb, cura + 1, 64);
        }
#pragma unroll
        for (int k = 0; k < 8; ++k) t[k] = fmaf(__shfl(bqall, i * 8 + k, 64), hv[i], t[k]);
        t[8] += hv[i];
      }
    }
  }
  if (re > rs) {                                 // flush last run
#pragma unroll
    for (int k = 0; k < 9; ++k) T_s[wv * MAW + cura][k * 64 + lane] = t[k];
  }
  __syncthreads();

  // ---- Phase B: matvec per atom (acc[a] = agg[awave+a][lane]) ----
  float acc[MAW];
#pragma unroll
  for (int a = 0; a < MAW; ++a) acc[a] = 0.f;
  const float4* Kr4 = reinterpret_cast<const float4*>(Kr);
  const float4* Ts4 = reinterpret_cast<const float4*>(&T_s[wv * MAW][0]);
#pragma unroll 4
  for (int kj = 0; kj < 144; ++kj) {
    float4 Kv = Kr4[kj * 64 + lane];
#pragma unroll
    for (int a = 0; a < MAW; ++a) {
      float4 Tv = Ts4[a * 144 + kj];             // broadcast read
      acc[a] = fmaf(Kv.x, Tv.x, acc[a]);
      acc[a] = fmaf(Kv.y, Tv.y, acc[a]);
      acc[a] = fmaf(Kv.z, Tv.z, acc[a]);
      acc[a] = fmaf(Kv.w, Tv.w, acc[a]);
    }
  }

  // ---- Phase C: fused GRU (lane = output i) ----
  float hreg[MAW];
#pragma unroll
  for (int a = 0; a < MAW; ++a) hreg[a] = h_in[(awave + a) * 64 + lane];
  float air[MAW], aiz[MAW], ain[MAW], ahr[MAW], ahz[MAW], ahn[MAW];
#pragma unroll
  for (int a = 0; a < MAW; ++a) { air[a]=0.f; aiz[a]=0.f; ain[a]=0.f; ahr[a]=0.f; ahz[a]=0.f; ahn[a]=0.f; }
#pragma unroll 2
  for (int j = 0; j < 64; ++j) {
    const float wi0 = wihT[j * 192 + lane];
    const float wi1 = wihT[j * 192 + 64 + lane];
    const float wi2 = wihT[j * 192 + 128 + lane];
    const float wh0 = whhT[j * 192 + lane];
    const float wh1 = whhT[j * 192 + 64 + lane];
    const float wh2 = whhT[j * 192 + 128 + lane];
#pragma unroll
    for (int a = 0; a < MAW; ++a) {
      const float ag = __shfl(acc[a], j, 64);
      const float hj = __shfl(hreg[a], j, 64);
      air[a] = fmaf(wi0, ag, air[a]);
      aiz[a] = fmaf(wi1, ag, aiz[a]);
      ain[a] = fmaf(wi2, ag, ain[a]);
      ahr[a] = fmaf(wh0, hj, ahr[a]);
      ahz[a] = fmaf(wh1, hj, ahz[a]);
      ahn[a] = fmaf(wh2, hj, ahn[a]);
    }
  }
  const float bir = bih[lane], biz = bih[64 + lane], bin_ = bih[128 + lane];
  const float bhr = bhh[lane], bhz = bhh[64 + lane], bhn = bhh[128 + lane];
#pragma unroll
  for (int a = 0; a < MAW; ++a) {
    float r = sigmoidf_((air[a] + bir) + (ahr[a] + bhr));
    float z = sigmoidf_((aiz[a] + biz) + (ahz[a] + bhz));
    float nn = tanhf((ain[a] + bin_) + r * (ahn[a] + bhn));
    h_out[(awave + a) * 64 + lane] = (1.0f - z) * nn + z * hreg[a];
  }
}

// ============ qkv projection + valid mask ============
#define QABLK 4
__global__ __launch_bounds__(256, 1) void k_qkv(
    const float* __restrict__ h, const float* __restrict__ w,
    const float* __restrict__ b, float* __restrict__ qkv,
    int* __restrict__ valid) {
  __shared__ __align__(16) float w_s[192 * 64];
  __shared__ __align__(16) float x_s[4][QABLK][64];
  const int tid = threadIdx.x, lane = tid & 63, wv = tid >> 6;
  for (int idx = tid; idx < 192 * 64; idx += 256) {
    int r = idx >> 6, d = idx & 63;
    w_s[(r << 6) + ((((d >> 2) ^ (r & 7)) << 2) | (d & 3))] = w[idx];
  }
  __syncthreads();
  const float4* w4 = reinterpret_cast<const float4*>(w_s);
  const float bq = b[lane], bk = b[64 + lane], bv_ = b[128 + lane];
  const int swz = lane & 7;
  const int gw = blockIdx.x * 4 + wv;
  const int stride = gridDim.x * 4 * QABLK;
  for (int ag = gw * QABLK; ag < NA; ag += stride) {
#pragma unroll
    for (int e = 0; e < QABLK; ++e) x_s[wv][e][lane] = h[(ag + e) * 64 + lane];
    __syncthreads();
    const float4* x4 = reinterpret_cast<const float4*>(&x_s[wv][0][0]);
    float aq[QABLK] = {0,0,0,0}, ak[QABLK] = {0,0,0,0}, av_[QABLK] = {0,0,0,0};
    int nz[QABLK] = {0,0,0,0};
#pragma unroll 4
    for (int d4 = 0; d4 < 16; ++d4) {
      int sl = d4 ^ swz;
      float4 wq = w4[(lane << 4) + sl];
      float4 wk = w4[((lane + 64) << 4) + sl];
      float4 wvv = w4[((lane + 128) << 4) + sl];
#pragma unroll
      for (int e = 0; e < QABLK; ++e) {
        float4 xv = x4[e * 16 + d4];
        aq[e] += wq.x*xv.x + wq.y*xv.y + wq.z*xv.z + wq.w*xv.w;
        ak[e] += wk.x*xv.x + wk.y*xv.y + wk.z*xv.z + wk.w*xv.w;
        av_[e] += wvv.x*xv.x + wvv.y*xv.y + wvv.z*xv.z + wvv.w*xv.w;
        nz[e] |= (int)(xv.x != 0.f) | (int)(xv.y != 0.f) | (int)(xv.z != 0.f) | (int)(xv.w != 0.f);
      }
    }
#pragma unroll
    for (int e = 0; e < QABLK; ++e) {
      qkv[(ag + e) * 192 + lane] = aq[e] + bq;
      qkv[(ag + e) * 192 + 64 + lane] = ak[e] + bk;
      qkv[(ag + e) * 192 + 128 + lane] = av_[e] + bv_;
      if (lane == 0) valid[ag + e] = nz[e];
    }
    __syncthreads();
  }
}

// ============ attention: one wave per (molecule, head), online softmax ============
__global__ void k_attn(const float* __restrict__ qkv, const int* __restrict__ valid,
                       float* __restrict__ ao) {
  const int b = blockIdx.x >> 3, hh = blockIdx.x & 7;
  __shared__ float k_s[64][8];
  __shared__ float v_s[64][8];
  __shared__ int vd_s[64];
  const int lane = threadIdx.x;
  const int rowbase = (b * 64 + lane) * 192;
#pragma unroll
  for (int j = 0; j < 8; ++j) {
    k_s[lane][j] = qkv[rowbase + 64 + hh * 8 + j];
    v_s[lane][j] = qkv[rowbase + 128 + hh * 8 + j];
  }
  vd_s[lane] = valid[b * 64 + lane];
  __syncthreads();
  float q[8];
#pragma unroll
  for (int j = 0; j < 8; ++j) q[j] = qkv[rowbase + hh * 8 + j];
  float m = -3.0e38f, l = 0.f, o[8] = {0,0,0,0,0,0,0,0};
  for (int t = 0; t < 64; ++t) {
    float s = 0.f;
#pragma unroll
    for (int j = 0; j < 8; ++j) s += q[j] * k_s[t][j];
    s *= 0.35355339059327373f;
    s = vd_s[t] ? s : -1.0e9f;
    float mn = fmaxf(m, s);
    float c = expf(m - mn);
    float p = expf(s - mn);
    l = l * c + p;
#pragma unroll
    for (int j = 0; j < 8; ++j) o[j] = o[j] * c + p * v_s[t][j];
    m = mn;
  }
  const float inv = 1.0f / l;
  const int obase = (b * 64 + lane) * 64 + hh * 8;
#pragma unroll
  for (int j = 0; j < 8; ++j) ao[obase + j] = o[j] * inv;
}

// ============ out_proj + residual + LN1 ============
#define OABLK 4
__global__ __launch_bounds__(256, 1) void k_out_ln1(
    const float* __restrict__ x, const float* __restrict__ ao,
    const float* __restrict__ w, const float* __restrict__ bias,
    const float* __restrict__ g, const float* __restrict__ bb,
    float* __restrict__ y1) {
  __shared__ __align__(16) float w_s[64 * 64];
  __shared__ __align__(16) float a_s[4][OABLK][64];
  const int tid = threadIdx.x, lane = tid & 63, wv = tid >> 6;
  for (int idx = tid; idx < 64 * 64; idx += 256) {
    int r = idx >> 6, d = idx & 63;
    w_s[(r << 6) + ((((d >> 2) ^ (r & 7)) << 2) | (d & 3))] = w[idx];
  }
  __syncthreads();
  const float4* w4 = reinterpret_cast<const float4*>(w_s);
  const float bo = bias[lane], gg = g[lane], bbb = bb[lane];
  const int swz = lane & 7;
  const int gw = blockIdx.x * 4 + wv;
  const int stride = gridDim.x * 4 * OABLK;
  for (int ag = gw * OABLK; ag < NA; ag += stride) {
#pragma unroll
    for (int e = 0; e < OABLK; ++e) a_s[wv][e][lane] = ao[(ag + e) * 64 + lane];
    __syncthreads();
    const float4* a4 = reinterpret_cast<const float4*>(&a_s[wv][0][0]);
    float acc[OABLK] = {0,0,0,0};
#pragma unroll 4
    for (int d4 = 0; d4 < 16; ++d4) {
      int sl = d4 ^ swz;
      float4 wr = w4[(lane << 4) + sl];
#pragma unroll
      for (int e = 0; e < OABLK; ++e) {
        float4 av = a4[e * 16 + d4];
        acc[e] += wr.x*av.x + wr.y*av.y + wr.z*av.z + wr.w*av.w;
      }
    }
#pragma unroll
    for (int e = 0; e < OABLK; ++e) {
      float val = acc[e] + bo + x[(ag + e) * 64 + lane];
      float s1 = val, s2 = val * val;
#pragma unroll
      for (int mm = 1; mm < 64; mm <<= 1) {
        s1 += __shfl_xor(s1, mm, 64);
        s2 += __shfl_xor(s2, mm, 64);
      }
      float mu = s1 * 0.015625f;
      float var = s2 * 0.015625f - mu * mu;
      y1[(ag + e) * 64 + lane] = (val - mu) * rsqrtf(var + 1e-5f) * gg + bbb;
    }
    __syncthreads();
  }
}

// ============ FFN (512 hidden) + residual + LN2 ============
#define FW 4
#define FABLK 8
__global__ __launch_bounds__(256, 2) void k_ffn(
    const float* __restrict__ y1, const float* __restrict__ w1,
    const float* __restrict__ b1, const float* __restrict__ w2,
    const float* __restrict__ b2, const float* __restrict__ g,
    const float* __restrict__ bb, float* __restrict__ y2) {
  __shared__ __align__(16) float hbuf[FW][FABLK][512];   // 64 KB
  __shared__ __align__(16) float y1_s[FW][FABLK][64];    // 8 KB
  const int tid = threadIdx.x, lane = tid & 63, wv = tid >> 6;
  const float4* w1_4 = reinterpret_cast<const float4*>(w1);
  const float4* b1_4 = reinterpret_cast<const float4*>(b1);
  const float b2v = b2[lane], gg = g[lane], bbb = bb[lane];
  const int gw = blockIdx.x * FW + wv;
  const int stride = gridDim.x * FW * FABLK;
  for (int ag = gw * FABLK; ag < NA; ag += stride) {
#pragma unroll
    for (int e = 0; e < FABLK; ++e) y1_s[wv][e][lane] = y1[(ag + e) * 64 + lane];
    __syncthreads();
    float4 hv0[FABLK], hv1[FABLK];
    const float4 bq0 = b1_4[lane], bq1 = b1_4[64 + lane];
#pragma unroll
    for (int e = 0; e < FABLK; ++e) { hv0[e] = bq0; hv1[e] = bq1; }
#pragma unroll 4
    for (int d = 0; d < 64; ++d) {
      float4 w0 = w1_4[d * 128 + lane];
      float4 w1v = w1_4[d * 128 + 64 + lane];
#pragma unroll
      for (int e = 0; e < FABLK; ++e) {
        float yv = y1_s[wv][e][d];
        hv0[e].x = fmaf(yv, w0.x, hv0[e].x);
        hv0[e].y = fmaf(yv, w0.y, hv0[e].y);
        hv0[e].z = fmaf(yv, w0.z, hv0[e].z);
        hv0[e].w = fmaf(yv, w0.w, hv0[e].w);
        hv1[e].x = fmaf(yv, w1v.x, hv1[e].x);
        hv1[e].y = fmaf(yv, w1v.y, hv1[e].y);
        hv1[e].z = fmaf(yv, w1v.z, hv1[e].z);
        hv1[e].w = fmaf(yv, w1v.w, hv1[e].w);
      }
    }
    float4* hb4w = reinterpret_cast<float4*>(&hbuf[wv][0][0]);
#pragma unroll
    for (int e = 0; e < FABLK; ++e) {
      float4 r0 = hv0[e], r1 = hv1[e];
      r0.x = fmaxf(r0.x, 0.f); r0.y = fmaxf(r0.y, 0.f);
      r0.z = fmaxf(r0.z, 0.f); r0.w = fmaxf(r0.w, 0.f);
      r1.x = fmaxf(r1.x, 0.f); r1.y = fmaxf(r1.y, 0.f);
      r1.z = fmaxf(r1.z, 0.f); r1.w = fmaxf(r1.w, 0.f);
      hb4w[e * 128 + lane] = r0;
      hb4w[e * 128 + 64 + lane] = r1;
    }
    __syncthreads();
    float acc[FABLK] = {0,0,0,0,0,0,0,0};
    const float4* hb4 = reinterpret_cast<const float4*>(&hbuf[wv][0][0]);
#pragma unroll 4
    for (int c4 = 0; c4 < 128; ++c4) {
      float w2v0 = w2[(c4 * 4 + 0) * 64 + lane];
      float w2v1 = w2[(c4 * 4 + 1) * 64 + lane];
      float w2v2 = w2[(c4 * 4 + 2) * 64 + lane];
      float w2v3 = w2[(c4 * 4 + 3) * 64 + lane];
#pragma unroll
      for (int e = 0; e < FABLK; ++e) {
        float4 hq = hb4[e * 128 + c4];
        acc[e] = fmaf(hq.x, w2v0, acc[e]);
        acc[e] = fmaf(hq.y, w2v1, acc[e]);
        acc[e] = fmaf(hq.z, w2v2, acc[e]);
        acc[e] = fmaf(hq.w, w2v3, acc[e]);
      }
    }
#pragma unroll
    for (int e = 0; e < FABLK; ++e) {
      float val = y1_s[wv][e][lane] + acc[e] + b2v;
      float s1 = val, s2 = val * val;
#pragma unroll
      for (int mm = 1; mm < 64; mm <<= 1) {
        s1 += __shfl_xor(s1, mm, 64);
        s2 += __shfl_xor(s2, mm, 64);
      }
      float mu = s1 * 0.015625f;
      float var = s2 * 0.015625f - mu * mu;
      y2[(ag + e) * 64 + lane] = (val - mu) * rsqrtf(var + 1e-5f) * gg + bbb;
    }
    __syncthreads();
  }
}

// ============ mean-pool over tokens ============
__global__ void k_pool(const float* __restrict__ y2, float* __restrict__ pooled) {
  const int b = blockIdx.x, lane = threadIdx.x;
  float s = 0.f;
  for (int t = 0; t < 64; ++t) s += y2[(b * 64 + t) * 64 + lane];
  pooled[b * 64 + lane] = s * 0.015625f;
}

// ============ readout head ============
__global__ __launch_bounds__(256) void k_head(
    const float* __restrict__ pooled, const float* __restrict__ d1w,
    const float* __restrict__ d1b, const float* __restrict__ d2w,
    const float* __restrict__ d2b, float* __restrict__ out) {
  const int b = blockIdx.x;
  __shared__ float p_s[64];
  __shared__ float red_s[4];
  const int tid = threadIdx.x;
  if (tid < 64) p_s[tid] = pooled[b * 64 + tid];
  __syncthreads();
  float acc = 0.f;
#pragma unroll
  for (int rep = 0; rep < 2; ++rep) {
    int c = rep * 256 + tid;
    float hvv = d1b[c];
    for (int d = 0; d < 64; ++d) hvv += p_s[d] * d1w[d * 512 + c];
    acc += fmaxf(hvv, 0.f) * d2w[c];
  }
#pragma unroll
  for (int mm = 1; mm < 64; mm <<= 1) acc += __shfl_xor(acc, mm, 64);
  if ((tid & 63) == 0) red_s[tid >> 6] = acc;
  __syncthreads();
  if (tid == 0) {
    float t = red_s[0] + red_s[1] + red_s[2] + red_s[3] + d2b[0];
    out[b] = 1.0f / (1.0f + expf(-t));
  }
}

extern "C" void kernel_launch(void* const* d_in, const int* in_sizes, int n_in,
                              void* d_out, int out_size, void* d_ws, size_t ws_size,
                              hipStream_t stream) {
  (void)in_sizes; (void)n_in; (void)out_size; (void)ws_size;
  const float* af   = (const float*)d_in[0];
  const float* bfeat= (const float*)d_in[1];
  const int*   pairs= (const int*)d_in[2];
  // d_in[3] = molecule_indicator (identity layout; unused)
  const float* kern = (const float*)d_in[4];
  const float* kbias= (const float*)d_in[5];
  const float* wih  = (const float*)d_in[6];
  const float* whh  = (const float*)d_in[7];
  const float* bih  = (const float*)d_in[8];
  const float* bhh  = (const float*)d_in[9];
  const float* ipw  = (const float*)d_in[10];
  const float* ipb  = (const float*)d_in[11];
  const float* opw  = (const float*)d_in[12];
  const float* opb  = (const float*)d_in[13];
  const float* fw1  = (const float*)d_in[14];
  const float* fb1  = (const float*)d_in[15];
  const float* fw2  = (const float*)d_in[16];
  const float* fb2  = (const float*)d_in[17];
  const float* l1g  = (const float*)d_in[18];
  const float* l1b  = (const float*)d_in[19];
  const float* l2g  = (const float*)d_in[20];
  const float* l2b  = (const float*)d_in[21];
  const float* d1w  = (const float*)d_in[22];
  const float* d1b  = (const float*)d_in[23];
  const float* d2w  = (const float*)d_in[24];
  const float* d2b  = (const float*)d_in[25];
  float* out = (float*)d_out;

  // workspace layout (floats)
  float* ws = (float*)d_ws;
  float* h      = ws;                    // ping buffer (final h after 4 steps)
  float* h2     = h + (size_t)NA * 64;   // pong buffer (was agg; agg is register-only now)
  float* qkv    = h2 + (size_t)NA * 64;
  float* ao     = qkv + (size_t)NA * 192;
  float* y1     = ao + (size_t)NA * 64;
  float* y2     = y1 + (size_t)NA * 64;
  float* pooled = y2 + (size_t)NA * 64;
  int*   valid  = (int*)(pooled + 256 * 64);

  // MP-loop scratch aliased into the qkv region (dead until after the loop):
  float* Kr     = qkv;                         // 36864 f
  int*   count  = (int*)(qkv + 36864);         // NA
  int*   start  = count + NA;                  // NA+1
  int*   cursor = start + NA + 1;              // NA
  int*   elist  = cursor + NA;                 // NE
  int*   bsum   = elist + NE;                  // 256
  int*   sdst   = bsum + 256;                  // NE + 8 pad
  float* sbf    = (float*)(sdst + NE + 8);     // NE*8 + 64 pad
  float* wihT   = sbf + (size_t)NE * 8 + 64;   // 12288
  float* whhT   = wihT + 12288;                // 12288

  k_init_h<<<NA * 64 / 256, 256, 0, stream>>>(af, h);
  k_prep_Kr<<<144, 256, 0, stream>>>(kern, kbias, Kr);
  k_prep_wT<<<48, 256, 0, stream>>>(wih, whh, wihT, whhT);
  hipMemsetAsync(count, 0, (size_t)NA * sizeof(int), stream);
  k_count<<<NE / 256, 256, 0, stream>>>(pairs, count);
  k_scan1<<<64, 256, 0, stream>>>(count, bsum);
  k_scan2<<<64, 256, 0, stream>>>(count, bsum, start, cursor);
  k_place<<<NE / 256, 256, 0, stream>>>(pairs, cursor, elist);
  k_reorder<<<NE * 8 / 256, 256, 0, stream>>>(bfeat, pairs, elist, sdst, sbf);

  float* hin = h;
  float* hout = h2;
  for (int s = 0; s < 4; ++s) {
    k_msg<<<NA / (MW * MAW), 256, 0, stream>>>(hin, start, sdst, sbf, Kr,
                                               wihT, whhT, bih, bhh, hout);
    float* tmp = hin; hin = hout; hout = tmp;
  }
  // 4 swaps -> final h is back in 'h'

  k_qkv<<<512, 256, 0, stream>>>(h, ipw, ipb, qkv, valid);
  k_attn<<<2048, 64, 0, stream>>>(qkv, valid, ao);
  k_out_ln1<<<512, 256, 0, stream>>>(h, ao, opw, opb, l1g, l1b, y1);
  k_ffn<<<512, 256, 0, stream>>>(y1, fw1, fb1, fw2, fb2, l2g, l2b, y2);
  k_pool<<<256, 64, 0, stream>>>(y2, pooled);
  k_head<<<256, 256, 0, stream>>>(pooled, d1w, d1b, d2w, d2b, out);
}

// Round 9
// 390.842 us; speedup vs baseline: 1.1355x; 1.0373x over previous
//
#include <hip/hip_runtime.h>
#include <hip/hip_bf16.h>
#include <math.h>

#define NA 16384
#define NE 65536
#define AD 29

__device__ __forceinline__ float sigmoidf_(float x) { return 1.0f / (1.0f + expf(-x)); }

// ============ init h: pad atom features 29 -> 64 ============
__global__ void k_init_h(const float* __restrict__ af, float* __restrict__ h) {
  int idx = blockIdx.x * 256 + threadIdx.x;
  if (idx >= NA * 64) return;
  int a = idx >> 6, d = idx & 63;
  h[idx] = (d < AD) ? af[a * AD + d] : 0.0f;
}

// ============ Kr relayout (once per call): Kr4[(k9*16+j4)*64 + i] = K[k9][i][4j4..+3]
__global__ void k_prep_Kr(const float* __restrict__ kern, const float* __restrict__ kbias,
                          float* __restrict__ Kr) {
  int f = blockIdx.x * 256 + threadIdx.x;    // 9*16*64*4 = 36864 floats
  if (f >= 36864) return;
  int t = f & 3, i = (f >> 2) & 63, j4 = (f >> 8) & 15, k9 = f >> 12;
  int col = j4 * 4 + t;
  Kr[f] = (k9 < 8) ? kern[k9 * 4096 + i * 64 + col] : kbias[i * 64 + col];
}

// ============ GRU weight relayout (once): wT4[j4*192 + r] = {w[r][4j4..+3]}
// lane r reads float4 coalesced per j4-chunk.
__global__ void k_prep_wT(const float* __restrict__ wih, const float* __restrict__ whh,
                          float* __restrict__ wiT, float* __restrict__ whT) {
  int idx = blockIdx.x * 256 + threadIdx.x;    // 12288 floats each
  if (idx >= 12288) return;
  int j4 = idx / 768, rem = idx % 768, r = rem >> 2, t = rem & 3;
  int src = r * 64 + j4 * 4 + t;
  wiT[idx] = wih[src];
  whT[idx] = whh[src];
}

// ============ edge bucketing by src (once per call; counting sort) ============
__global__ void k_count(const int* __restrict__ pairs, int* __restrict__ count) {
  int e = blockIdx.x * 256 + threadIdx.x;
  if (e >= NE) return;
  atomicAdd(&count[pairs[2 * e]], 1);
}
__global__ void k_scan1(const int* __restrict__ count, int* __restrict__ bsum) {
  __shared__ int red[256];
  int b = blockIdx.x, t = threadIdx.x;
  red[t] = count[b * 256 + t];
  __syncthreads();
  for (int s = 128; s > 0; s >>= 1) { if (t < s) red[t] += red[t + s]; __syncthreads(); }
  if (t == 0) bsum[b] = red[0];
}
__global__ void k_scan2(const int* __restrict__ count, const int* __restrict__ bsum,
                        int* __restrict__ start, int* __restrict__ cursor) {
  __shared__ int sc[256];
  __shared__ int basev;
  int b = blockIdx.x, t = threadIdx.x;
  if (t == 0) { int s = 0; for (int i = 0; i < b; ++i) s += bsum[i]; basev = s; }
  int v = count[b * 256 + t];
  sc[t] = v;
  __syncthreads();
  for (int off = 1; off < 256; off <<= 1) {
    int add = (t >= off) ? sc[t - off] : 0;
    __syncthreads();
    sc[t] += add;
    __syncthreads();
  }
  int excl = sc[t] - v + basev;
  start[b * 256 + t] = excl;
  cursor[b * 256 + t] = excl;
  if (b * 256 + t == NA - 1) start[NA] = excl + v;   // sentinel = NE
}
__global__ void k_place(const int* __restrict__ pairs, int* __restrict__ cursor,
                        int* __restrict__ elist) {
  int e = blockIdx.x * 256 + threadIdx.x;
  if (e >= NE) return;
  int pos = atomicAdd(&cursor[pairs[2 * e]], 1);
  elist[pos] = e;
}
__global__ void k_reorder(const float* __restrict__ bf, const int* __restrict__ pairs,
                          const int* __restrict__ elist, int* __restrict__ sdst,
                          float* __restrict__ sbf) {
  int idx = blockIdx.x * 256 + threadIdx.x;    // NE*8 threads
  if (idx >= NE * 8) return;
  int pos = idx >> 3, k = idx & 7;
  int e = elist[pos];
  sbf[idx] = bf[e * 8 + k];
  if (k == 0) sdst[pos] = pairs[2 * e + 1];
}

// ============ fused message + GRU step (wave-private LDS; zero __syncthreads) ====
// Phase A: per atom, gather T[k][j] = sum_{e:src=a} bf[e][k]*h_in[dst_e][j]
//          (k=8: bias), 8-edge batches with 8 h-gathers in flight, flush to
//          the wave's T_s region. No boundary while-chain (round-8 lesson).
// Phase B: acc[a][i=lane] = sum_{kj} Kr[kj][i] . T[a][kj]; Kr coalesced L2
//          stream, T float4 LDS broadcasts, 8 atoms amortize each Kr load.
// Phase C: GRU matvec, round-7 k_gru style: acc/h staged into the (dead)
//          T_s region, read back as float4 broadcasts; weights read as
//          coalesced float4 from the [j4][192] wT layout. (Round-8's shfl
//          version issued 1024 ds_bpermutes per wave -> LDS-pipe bound.)
#define MW 4
#define MAW 8
__global__ __launch_bounds__(256, 2) void k_msg(
    const float* __restrict__ h_in, const int* __restrict__ start,
    const int* __restrict__ sdst, const float* __restrict__ sbf,
    const float* __restrict__ Kr, const float* __restrict__ wiT,
    const float* __restrict__ whT, const float* __restrict__ bih,
    const float* __restrict__ bhh, float* __restrict__ h_out) {
  __shared__ __align__(16) float T_s[MW * MAW][576];   // 73,728 B
  const int tid = threadIdx.x, lane = tid & 63, wv = tid >> 6;
  const int awave = blockIdx.x * (MW * MAW) + wv * MAW;

  const int bb = (lane <= MAW) ? start[awave + lane] : 0;

  // ---- Phase A: per-atom gather ----
  for (int a = 0; a < MAW; ++a) {
    const int s0 = __shfl(bb, a, 64);
    const int s1 = __shfl(bb, a + 1, 64);
    float t[9] = {0.f, 0.f, 0.f, 0.f, 0.f, 0.f, 0.f, 0.f, 0.f};
    for (int base = s0; base < s1; base += 8) {
      const int nb = s1 - base;                  // active: min(8, nb)
      const float bqall = sbf[base * 8 + lane];  // 8 edges x 8 k, coalesced
      int dc[8]; float hv[8];
#pragma unroll
      for (int i = 0; i < 8; ++i) dc[i] = (i < nb) ? sdst[base + i] : 0;
#pragma unroll
      for (int i = 0; i < 8; ++i) hv[i] = (i < nb) ? h_in[dc[i] * 64 + lane] : 0.f;
#pragma unroll
      for (int i = 0; i < 8; ++i) {
        if (i < nb) {
#pragma unroll
          for (int k = 0; k < 8; ++k) t[k] = fmaf(__shfl(bqall, i * 8 + k, 64), hv[i], t[k]);
          t[8] += hv[i];
        }
      }
    }
#pragma unroll
    for (int k = 0; k < 9; ++k) T_s[wv * MAW + a][k * 64 + lane] = t[k];
  }

  // ---- Phase B: matvec per atom (acc[a] = agg[awave+a][lane]) ----
  float acc[MAW];
#pragma unroll
  for (int a = 0; a < MAW; ++a) acc[a] = 0.f;
  const float4* Kr4 = reinterpret_cast<const float4*>(Kr);
  const float4* Ts4 = reinterpret_cast<const float4*>(&T_s[wv * MAW][0]);
#pragma unroll 4
  for (int kj = 0; kj < 144; ++kj) {
    float4 Kv = Kr4[kj * 64 + lane];
#pragma unroll
    for (int a = 0; a < MAW; ++a) {
      float4 Tv = Ts4[a * 144 + kj];             // broadcast read
      acc[a] = fmaf(Kv.x, Tv.x, acc[a]);
      acc[a] = fmaf(Kv.y, Tv.y, acc[a]);
      acc[a] = fmaf(Kv.z, Tv.z, acc[a]);
      acc[a] = fmaf(Kv.w, Tv.w, acc[a]);
    }
  }

  // ---- Phase C: fused GRU via LDS-staged act + coalesced weights ----
  float hreg[MAW];
#pragma unroll
  for (int a = 0; a < MAW; ++a) hreg[a] = h_in[(awave + a) * 64 + lane];
  // stage acc & h into the wave's T_s region (dead after phase B; wave-private)
  float* AH = &T_s[wv * MAW][0];                 // first 1024 floats used
#pragma unroll
  for (int a = 0; a < MAW; ++a) {
    AH[a * 64 + lane] = acc[a];
    AH[MAW * 64 + a * 64 + lane] = hreg[a];
  }
  const float4* AH4 = reinterpret_cast<const float4*>(AH);
  const float4* wiT4 = reinterpret_cast<const float4*>(wiT);
  const float4* whT4 = reinterpret_cast<const float4*>(whT);
  float air[MAW], aiz[MAW], ain[MAW], ahr[MAW], ahz[MAW], ahn[MAW];
#pragma unroll
  for (int a = 0; a < MAW; ++a) { air[a]=0.f; aiz[a]=0.f; ain[a]=0.f; ahr[a]=0.f; ahz[a]=0.f; ahn[a]=0.f; }
#pragma unroll 2
  for (int j4 = 0; j4 < 16; ++j4) {
    const float4 wi0 = wiT4[j4 * 192 + lane];
    const float4 wi1 = wiT4[j4 * 192 + 64 + lane];
    const float4 wi2 = wiT4[j4 * 192 + 128 + lane];
    const float4 wh0 = whT4[j4 * 192 + lane];
    const float4 wh1 = whT4[j4 * 192 + 64 + lane];
    const float4 wh2 = whT4[j4 * 192 + 128 + lane];
#pragma unroll
    for (int a = 0; a < MAW; ++a) {
      const float4 av = AH4[a * 16 + j4];              // broadcast
      const float4 hv = AH4[MAW * 16 + a * 16 + j4];   // broadcast
      air[a] += wi0.x*av.x + wi0.y*av.y + wi0.z*av.z + wi0.w*av.w;
      aiz[a] += wi1.x*av.x + wi1.y*av.y + wi1.z*av.z + wi1.w*av.w;
      ain[a] += wi2.x*av.x + wi2.y*av.y + wi2.z*av.z + wi2.w*av.w;
      ahr[a] += wh0.x*hv.x + wh0.y*hv.y + wh0.z*hv.z + wh0.w*hv.w;
      ahz[a] += wh1.x*hv.x + wh1.y*hv.y + wh1.z*hv.z + wh1.w*hv.w;
      ahn[a] += wh2.x*hv.x + wh2.y*hv.y + wh2.z*hv.z + wh2.w*hv.w;
    }
  }
  const float bir = bih[lane], biz = bih[64 + lane], bin_ = bih[128 + lane];
  const float bhr = bhh[lane], bhz = bhh[64 + lane], bhn = bhh[128 + lane];
#pragma unroll
  for (int a = 0; a < MAW; ++a) {
    float r = sigmoidf_((air[a] + bir) + (ahr[a] + bhr));
    float z = sigmoidf_((aiz[a] + biz) + (ahz[a] + bhz));
    float nn = tanhf((ain[a] + bin_) + r * (ahn[a] + bhn));
    h_out[(awave + a) * 64 + lane] = (1.0f - z) * nn + z * hreg[a];
  }
}

// ============ qkv projection + valid mask ============
#define QABLK 4
__global__ __launch_bounds__(256, 1) void k_qkv(
    const float* __restrict__ h, const float* __restrict__ w,
    const float* __restrict__ b, float* __restrict__ qkv,
    int* __restrict__ valid) {
  __shared__ __align__(16) float w_s[192 * 64];
  __shared__ __align__(16) float x_s[4][QABLK][64];
  const int tid = threadIdx.x, lane = tid & 63, wv = tid >> 6;
  for (int idx = tid; idx < 192 * 64; idx += 256) {
    int r = idx >> 6, d = idx & 63;
    w_s[(r << 6) + ((((d >> 2) ^ (r & 7)) << 2) | (d & 3))] = w[idx];
  }
  __syncthreads();
  const float4* w4 = reinterpret_cast<const float4*>(w_s);
  const float bq = b[lane], bk = b[64 + lane], bv_ = b[128 + lane];
  const int swz = lane & 7;
  const int gw = blockIdx.x * 4 + wv;
  const int stride = gridDim.x * 4 * QABLK;
  for (int ag = gw * QABLK; ag < NA; ag += stride) {
#pragma unroll
    for (int e = 0; e < QABLK; ++e) x_s[wv][e][lane] = h[(ag + e) * 64 + lane];
    __syncthreads();
    const float4* x4 = reinterpret_cast<const float4*>(&x_s[wv][0][0]);
    float aq[QABLK] = {0,0,0,0}, ak[QABLK] = {0,0,0,0}, av_[QABLK] = {0,0,0,0};
    int nz[QABLK] = {0,0,0,0};
#pragma unroll 4
    for (int d4 = 0; d4 < 16; ++d4) {
      int sl = d4 ^ swz;
      float4 wq = w4[(lane << 4) + sl];
      float4 wk = w4[((lane + 64) << 4) + sl];
      float4 wvv = w4[((lane + 128) << 4) + sl];
#pragma unroll
      for (int e = 0; e < QABLK; ++e) {
        float4 xv = x4[e * 16 + d4];
        aq[e] += wq.x*xv.x + wq.y*xv.y + wq.z*xv.z + wq.w*xv.w;
        ak[e] += wk.x*xv.x + wk.y*xv.y + wk.z*xv.z + wk.w*xv.w;
        av_[e] += wvv.x*xv.x + wvv.y*xv.y + wvv.z*xv.z + wvv.w*xv.w;
        nz[e] |= (int)(xv.x != 0.f) | (int)(xv.y != 0.f) | (int)(xv.z != 0.f) | (int)(xv.w != 0.f);
      }
    }
#pragma unroll
    for (int e = 0; e < QABLK; ++e) {
      qkv[(ag + e) * 192 + lane] = aq[e] + bq;
      qkv[(ag + e) * 192 + 64 + lane] = ak[e] + bk;
      qkv[(ag + e) * 192 + 128 + lane] = av_[e] + bv_;
      if (lane == 0) valid[ag + e] = nz[e];
    }
    __syncthreads();
  }
}

// ============ attention: one wave per (molecule, head), online softmax ============
__global__ void k_attn(const float* __restrict__ qkv, const int* __restrict__ valid,
                       float* __restrict__ ao) {
  const int b = blockIdx.x >> 3, hh = blockIdx.x & 7;
  __shared__ float k_s[64][8];
  __shared__ float v_s[64][8];
  __shared__ int vd_s[64];
  const int lane = threadIdx.x;
  const int rowbase = (b * 64 + lane) * 192;
#pragma unroll
  for (int j = 0; j < 8; ++j) {
    k_s[lane][j] = qkv[rowbase + 64 + hh * 8 + j];
    v_s[lane][j] = qkv[rowbase + 128 + hh * 8 + j];
  }
  vd_s[lane] = valid[b * 64 + lane];
  __syncthreads();
  float q[8];
#pragma unroll
  for (int j = 0; j < 8; ++j) q[j] = qkv[rowbase + hh * 8 + j];
  float m = -3.0e38f, l = 0.f, o[8] = {0,0,0,0,0,0,0,0};
  for (int t = 0; t < 64; ++t) {
    float s = 0.f;
#pragma unroll
    for (int j = 0; j < 8; ++j) s += q[j] * k_s[t][j];
    s *= 0.35355339059327373f;
    s = vd_s[t] ? s : -1.0e9f;
    float mn = fmaxf(m, s);
    float c = expf(m - mn);
    float p = expf(s - mn);
    l = l * c + p;
#pragma unroll
    for (int j = 0; j < 8; ++j) o[j] = o[j] * c + p * v_s[t][j];
    m = mn;
  }
  const float inv = 1.0f / l;
  const int obase = (b * 64 + lane) * 64 + hh * 8;
#pragma unroll
  for (int j = 0; j < 8; ++j) ao[obase + j] = o[j] * inv;
}

// ============ out_proj + residual + LN1 ============
#define OABLK 4
__global__ __launch_bounds__(256, 1) void k_out_ln1(
    const float* __restrict__ x, const float* __restrict__ ao,
    const float* __restrict__ w, const float* __restrict__ bias,
    const float* __restrict__ g, const float* __restrict__ bb,
    float* __restrict__ y1) {
  __shared__ __align__(16) float w_s[64 * 64];
  __shared__ __align__(16) float a_s[4][OABLK][64];
  const int tid = threadIdx.x, lane = tid & 63, wv = tid >> 6;
  for (int idx = tid; idx < 64 * 64; idx += 256) {
    int r = idx >> 6, d = idx & 63;
    w_s[(r << 6) + ((((d >> 2) ^ (r & 7)) << 2) | (d & 3))] = w[idx];
  }
  __syncthreads();
  const float4* w4 = reinterpret_cast<const float4*>(w_s);
  const float bo = bias[lane], gg = g[lane], bbb = bb[lane];
  const int swz = lane & 7;
  const int gw = blockIdx.x * 4 + wv;
  const int stride = gridDim.x * 4 * OABLK;
  for (int ag = gw * OABLK; ag < NA; ag += stride) {
#pragma unroll
    for (int e = 0; e < OABLK; ++e) a_s[wv][e][lane] = ao[(ag + e) * 64 + lane];
    __syncthreads();
    const float4* a4 = reinterpret_cast<const float4*>(&a_s[wv][0][0]);
    float acc[OABLK] = {0,0,0,0};
#pragma unroll 4
    for (int d4 = 0; d4 < 16; ++d4) {
      int sl = d4 ^ swz;
      float4 wr = w4[(lane << 4) + sl];
#pragma unroll
      for (int e = 0; e < OABLK; ++e) {
        float4 av = a4[e * 16 + d4];
        acc[e] += wr.x*av.x + wr.y*av.y + wr.z*av.z + wr.w*av.w;
      }
    }
#pragma unroll
    for (int e = 0; e < OABLK; ++e) {
      float val = acc[e] + bo + x[(ag + e) * 64 + lane];
      float s1 = val, s2 = val * val;
#pragma unroll
      for (int mm = 1; mm < 64; mm <<= 1) {
        s1 += __shfl_xor(s1, mm, 64);
        s2 += __shfl_xor(s2, mm, 64);
      }
      float mu = s1 * 0.015625f;
      float var = s2 * 0.015625f - mu * mu;
      y1[(ag + e) * 64 + lane] = (val - mu) * rsqrtf(var + 1e-5f) * gg + bbb;
    }
    __syncthreads();
  }
}

// ============ FFN (512 hidden) + residual + LN2 ============
#define FW 4
#define FABLK 8
__global__ __launch_bounds__(256, 2) void k_ffn(
    const float* __restrict__ y1, const float* __restrict__ w1,
    const float* __restrict__ b1, const float* __restrict__ w2,
    const float* __restrict__ b2, const float* __restrict__ g,
    const float* __restrict__ bb, float* __restrict__ y2) {
  __shared__ __align__(16) float hbuf[FW][FABLK][512];   // 64 KB
  __shared__ __align__(16) float y1_s[FW][FABLK][64];    // 8 KB
  const int tid = threadIdx.x, lane = tid & 63, wv = tid >> 6;
  const float4* w1_4 = reinterpret_cast<const float4*>(w1);
  const float4* b1_4 = reinterpret_cast<const float4*>(b1);
  const float b2v = b2[lane], gg = g[lane], bbb = bb[lane];
  const int gw = blockIdx.x * FW + wv;
  const int stride = gridDim.x * FW * FABLK;
  for (int ag = gw * FABLK; ag < NA; ag += stride) {
#pragma unroll
    for (int e = 0; e < FABLK; ++e) y1_s[wv][e][lane] = y1[(ag + e) * 64 + lane];
    __syncthreads();
    float4 hv0[FABLK], hv1[FABLK];
    const float4 bq0 = b1_4[lane], bq1 = b1_4[64 + lane];
#pragma unroll
    for (int e = 0; e < FABLK; ++e) { hv0[e] = bq0; hv1[e] = bq1; }
#pragma unroll 4
    for (int d = 0; d < 64; ++d) {
      float4 w0 = w1_4[d * 128 + lane];
      float4 w1v = w1_4[d * 128 + 64 + lane];
#pragma unroll
      for (int e = 0; e < FABLK; ++e) {
        float yv = y1_s[wv][e][d];
        hv0[e].x = fmaf(yv, w0.x, hv0[e].x);
        hv0[e].y = fmaf(yv, w0.y, hv0[e].y);
        hv0[e].z = fmaf(yv, w0.z, hv0[e].z);
        hv0[e].w = fmaf(yv, w0.w, hv0[e].w);
        hv1[e].x = fmaf(yv, w1v.x, hv1[e].x);
        hv1[e].y = fmaf(yv, w1v.y, hv1[e].y);
        hv1[e].z = fmaf(yv, w1v.z, hv1[e].z);
        hv1[e].w = fmaf(yv, w1v.w, hv1[e].w);
      }
    }
    float4* hb4w = reinterpret_cast<float4*>(&hbuf[wv][0][0]);
#pragma unroll
    for (int e = 0; e < FABLK; ++e) {
      float4 r0 = hv0[e], r1 = hv1[e];
      r0.x = fmaxf(r0.x, 0.f); r0.y = fmaxf(r0.y, 0.f);
      r0.z = fmaxf(r0.z, 0.f); r0.w = fmaxf(r0.w, 0.f);
      r1.x = fmaxf(r1.x, 0.f); r1.y = fmaxf(r1.y, 0.f);
      r1.z = fmaxf(r1.z, 0.f); r1.w = fmaxf(r1.w, 0.f);
      hb4w[e * 128 + lane] = r0;
      hb4w[e * 128 + 64 + lane] = r1;
    }
    __syncthreads();
    float acc[FABLK] = {0,0,0,0,0,0,0,0};
    const float4* hb4 = reinterpret_cast<const float4*>(&hbuf[wv][0][0]);
#pragma unroll 4
    for (int c4 = 0; c4 < 128; ++c4) {
      float w2v0 = w2[(c4 * 4 + 0) * 64 + lane];
      float w2v1 = w2[(c4 * 4 + 1) * 64 + lane];
      float w2v2 = w2[(c4 * 4 + 2) * 64 + lane];
      float w2v3 = w2[(c4 * 4 + 3) * 64 + lane];
#pragma unroll
      for (int e = 0; e < FABLK; ++e) {
        float4 hq = hb4[e * 128 + c4];
        acc[e] = fmaf(hq.x, w2v0, acc[e]);
        acc[e] = fmaf(hq.y, w2v1, acc[e]);
        acc[e] = fmaf(hq.z, w2v2, acc[e]);
        acc[e] = fmaf(hq.w, w2v3, acc[e]);
      }
    }
#pragma unroll
    for (int e = 0; e < FABLK; ++e) {
      float val = y1_s[wv][e][lane] + acc[e] + b2v;
      float s1 = val, s2 = val * val;
#pragma unroll
      for (int mm = 1; mm < 64; mm <<= 1) {
        s1 += __shfl_xor(s1, mm, 64);
        s2 += __shfl_xor(s2, mm, 64);
      }
      float mu = s1 * 0.015625f;
      float var = s2 * 0.015625f - mu * mu;
      y2[(ag + e) * 64 + lane] = (val - mu) * rsqrtf(var + 1e-5f) * gg + bbb;
    }
    __syncthreads();
  }
}

// ============ mean-pool over tokens ============
__global__ void k_pool(const float* __restrict__ y2, float* __restrict__ pooled) {
  const int b = blockIdx.x, lane = threadIdx.x;
  float s = 0.f;
  for (int t = 0; t < 64; ++t) s += y2[(b * 64 + t) * 64 + lane];
  pooled[b * 64 + lane] = s * 0.015625f;
}

// ============ readout head ============
__global__ __launch_bounds__(256) void k_head(
    const float* __restrict__ pooled, const float* __restrict__ d1w,
    const float* __restrict__ d1b, const float* __restrict__ d2w,
    const float* __restrict__ d2b, float* __restrict__ out) {
  const int b = blockIdx.x;
  __shared__ float p_s[64];
  __shared__ float red_s[4];
  const int tid = threadIdx.x;
  if (tid < 64) p_s[tid] = pooled[b * 64 + tid];
  __syncthreads();
  float acc = 0.f;
#pragma unroll
  for (int rep = 0; rep < 2; ++rep) {
    int c = rep * 256 + tid;
    float hvv = d1b[c];
    for (int d = 0; d < 64; ++d) hvv += p_s[d] * d1w[d * 512 + c];
    acc += fmaxf(hvv, 0.f) * d2w[c];
  }
#pragma unroll
  for (int mm = 1; mm < 64; mm <<= 1) acc += __shfl_xor(acc, mm, 64);
  if ((tid & 63) == 0) red_s[tid >> 6] = acc;
  __syncthreads();
  if (tid == 0) {
    float t = red_s[0] + red_s[1] + red_s[2] + red_s[3] + d2b[0];
    out[b] = 1.0f / (1.0f + expf(-t));
  }
}

extern "C" void kernel_launch(void* const* d_in, const int* in_sizes, int n_in,
                              void* d_out, int out_size, void* d_ws, size_t ws_size,
                              hipStream_t stream) {
  (void)in_sizes; (void)n_in; (void)out_size; (void)ws_size;
  const float* af   = (const float*)d_in[0];
  const float* bfeat= (const float*)d_in[1];
  const int*   pairs= (const int*)d_in[2];
  // d_in[3] = molecule_indicator (identity layout; unused)
  const float* kern = (const float*)d_in[4];
  const float* kbias= (const float*)d_in[5];
  const float* wih  = (const float*)d_in[6];
  const float* whh  = (const float*)d_in[7];
  const float* bih  = (const float*)d_in[8];
  const float* bhh  = (const float*)d_in[9];
  const float* ipw  = (const float*)d_in[10];
  const float* ipb  = (const float*)d_in[11];
  const float* opw  = (const float*)d_in[12];
  const float* opb  = (const float*)d_in[13];
  const float* fw1  = (const float*)d_in[14];
  const float* fb1  = (const float*)d_in[15];
  const float* fw2  = (const float*)d_in[16];
  const float* fb2  = (const float*)d_in[17];
  const float* l1g  = (const float*)d_in[18];
  const float* l1b  = (const float*)d_in[19];
  const float* l2g  = (const float*)d_in[20];
  const float* l2b  = (const float*)d_in[21];
  const float* d1w  = (const float*)d_in[22];
  const float* d1b  = (const float*)d_in[23];
  const float* d2w  = (const float*)d_in[24];
  const float* d2b  = (const float*)d_in[25];
  float* out = (float*)d_out;

  // workspace layout (floats)
  float* ws = (float*)d_ws;
  float* h      = ws;                    // ping buffer (final h after 4 steps)
  float* h2     = h + (size_t)NA * 64;   // pong buffer
  float* qkv    = h2 + (size_t)NA * 64;
  float* ao     = qkv + (size_t)NA * 192;
  float* y1     = ao + (size_t)NA * 64;
  float* y2     = y1 + (size_t)NA * 64;
  float* pooled = y2 + (size_t)NA * 64;
  int*   valid  = (int*)(pooled + 256 * 64);

  // MP-loop scratch aliased into the qkv region (dead until after the loop):
  float* Kr     = qkv;                         // 36864 f
  int*   count  = (int*)(qkv + 36864);         // NA
  int*   start  = count + NA;                  // NA+1
  int*   cursor = start + NA + 1;              // NA
  int*   elist  = cursor + NA;                 // NE
  int*   bsum   = elist + NE;                  // 256
  int*   sdst   = bsum + 256;                  // NE + 8 pad
  float* sbf    = (float*)(sdst + NE + 8);     // NE*8 + 64 pad
  float* wiT    = sbf + (size_t)NE * 8 + 64;   // 12288
  float* whT    = wiT + 12288;                 // 12288

  k_init_h<<<NA * 64 / 256, 256, 0, stream>>>(af, h);
  k_prep_Kr<<<144, 256, 0, stream>>>(kern, kbias, Kr);
  k_prep_wT<<<48, 256, 0, stream>>>(wih, whh, wiT, whT);
  hipMemsetAsync(count, 0, (size_t)NA * sizeof(int), stream);
  k_count<<<NE / 256, 256, 0, stream>>>(pairs, count);
  k_scan1<<<64, 256, 0, stream>>>(count, bsum);
  k_scan2<<<64, 256, 0, stream>>>(count, bsum, start, cursor);
  k_place<<<NE / 256, 256, 0, stream>>>(pairs, cursor, elist);
  k_reorder<<<NE * 8 / 256, 256, 0, stream>>>(bfeat, pairs, elist, sdst, sbf);

  float* hin = h;
  float* hout = h2;
  for (int s = 0; s < 4; ++s) {
    k_msg<<<NA / (MW * MAW), 256, 0, stream>>>(hin, start, sdst, sbf, Kr,
                                               wiT, whT, bih, bhh, hout);
    float* tmp = hin; hin = hout; hout = tmp;
  }
  // 4 swaps -> final h is back in 'h'

  k_qkv<<<512, 256, 0, stream>>>(h, ipw, ipb, qkv, valid);
  k_attn<<<2048, 64, 0, stream>>>(qkv, valid, ao);
  k_out_ln1<<<512, 256, 0, stream>>>(h, ao, opw, opb, l1g, l1b, y1);
  k_ffn<<<512, 256, 0, stream>>>(y1, fw1, fb1, fw2, fb2, l2g, l2b, y2);
  k_pool<<<256, 64, 0, stream>>>(y2, pooled);
  k_head<<<256, 256, 0, stream>>>(pooled, d1w, d1b, d2w, d2b, out);
}

// Round 10
// 276.195 us; speedup vs baseline: 1.6068x; 1.4151x over previous
//
#include <hip/hip_runtime.h>
#include <hip/hip_bf16.h>
#include <math.h>

#define NA 16384
#define NE 65536
#define AD 29

typedef __attribute__((ext_vector_type(8))) short bfrag8;
typedef __attribute__((ext_vector_type(4))) float f32x4;

__device__ __forceinline__ float sigmoidf_(float x) { return 1.0f / (1.0f + expf(-x)); }
__device__ __forceinline__ unsigned short bf16bits(float x) {
  __hip_bfloat16 hb = __float2bfloat16(x);
  return *reinterpret_cast<unsigned short*>(&hb);
}

// ============ init h: pad atom features 29 -> 64 ============
__global__ void k_init_h(const float* __restrict__ af, float* __restrict__ h) {
  int idx = blockIdx.x * 256 + threadIdx.x;
  if (idx >= NA * 64) return;
  int a = idx >> 6, d = idx & 63;
  h[idx] = (d < AD) ? af[a * AD + d] : 0.0f;
}

// ============ K -> A-fragment relayout (once per call), bf16.
// KrA[((w*18+ks)*64+lane)*8+r] = bf16(K[k9][i][j]) with i = w*16+(lane&15),
// kj = ks*32 + (lane>>4)*8 + r, k9 = kj>>6, j = kj&63 (k9==8 -> bias matrix).
// Phase B then loads each wave's A-fragments as perfectly coalesced 1KB reads.
__global__ void k_prep_KrA(const float* __restrict__ kern, const float* __restrict__ kbias,
                           unsigned short* __restrict__ KrA) {
  int idx = blockIdx.x * 256 + threadIdx.x;    // 4*18*64*8 = 36864
  if (idx >= 36864) return;
  int r = idx & 7;
  int tmp = idx >> 3;
  int lane = tmp & 63;
  int tmp2 = tmp >> 6;            // w*18 + ks
  int ks = tmp2 % 18, w = tmp2 / 18;
  int i = w * 16 + (lane & 15);
  int kj = ks * 32 + ((lane >> 4) << 3) + r;
  int k9 = kj >> 6, j = kj & 63;
  float v = (k9 < 8) ? kern[k9 * 4096 + i * 64 + j] : kbias[i * 64 + j];
  KrA[idx] = bf16bits(v);
}

// ============ GRU weight relayout (once): wT4[j4*192 + r] = {w[r][4j4..+3]}
__global__ void k_prep_wT(const float* __restrict__ wih, const float* __restrict__ whh,
                          float* __restrict__ wiT, float* __restrict__ whT) {
  int idx = blockIdx.x * 256 + threadIdx.x;    // 12288 floats each
  if (idx >= 12288) return;
  int j4 = idx / 768, rem = idx % 768, r = rem >> 2, t = rem & 3;
  int src = r * 64 + j4 * 4 + t;
  wiT[idx] = wih[src];
  whT[idx] = whh[src];
}

// ============ edge bucketing by src (once per call; counting sort) ============
__global__ void k_count(const int* __restrict__ pairs, int* __restrict__ count) {
  int e = blockIdx.x * 256 + threadIdx.x;
  if (e >= NE) return;
  atomicAdd(&count[pairs[2 * e]], 1);
}
__global__ void k_scan1(const int* __restrict__ count, int* __restrict__ bsum) {
  __shared__ int red[256];
  int b = blockIdx.x, t = threadIdx.x;
  red[t] = count[b * 256 + t];
  __syncthreads();
  for (int s = 128; s > 0; s >>= 1) { if (t < s) red[t] += red[t + s]; __syncthreads(); }
  if (t == 0) bsum[b] = red[0];
}
__global__ void k_scan2(const int* __restrict__ count, const int* __restrict__ bsum,
                        int* __restrict__ start, int* __restrict__ cursor) {
  __shared__ int sc[256];
  __shared__ int basev;
  int b = blockIdx.x, t = threadIdx.x;
  if (t == 0) { int s = 0; for (int i = 0; i < b; ++i) s += bsum[i]; basev = s; }
  int v = count[b * 256 + t];
  sc[t] = v;
  __syncthreads();
  for (int off = 1; off < 256; off <<= 1) {
    int add = (t >= off) ? sc[t - off] : 0;
    __syncthreads();
    sc[t] += add;
    __syncthreads();
  }
  int excl = sc[t] - v + basev;
  start[b * 256 + t] = excl;
  cursor[b * 256 + t] = excl;
  if (b * 256 + t == NA - 1) start[NA] = excl + v;   // sentinel = NE
}
__global__ void k_place(const int* __restrict__ pairs, int* __restrict__ cursor,
                        int* __restrict__ elist) {
  int e = blockIdx.x * 256 + threadIdx.x;
  if (e >= NE) return;
  int pos = atomicAdd(&cursor[pairs[2 * e]], 1);
  elist[pos] = e;
}
__global__ void k_reorder(const float* __restrict__ bf, const int* __restrict__ pairs,
                          const int* __restrict__ elist, int* __restrict__ sdst,
                          float* __restrict__ sbf) {
  int idx = blockIdx.x * 256 + threadIdx.x;    // NE*8 threads
  if (idx >= NE * 8) return;
  int pos = idx >> 3, k = idx & 7;
  int e = elist[pos];
  sbf[idx] = bf[e * 8 + k];
  if (k == 0) sdst[pos] = pairs[2 * e + 1];
}

// ============ fused message + GRU step ============
// Block = 16 atoms (4 waves x 4). Phase A: per-atom gather with scalar
// (wave-uniform s_load) bond coefficients + 8-deep h-gather batches; T
// written to LDS as bf16 rows [16][584] (pad -> conflict-free b128 reads).
// Phase B: 18x mfma_f32_16x16x32_bf16 per wave; A-fragments = KrA (global,
// coalesced, fragment-serial); B-fragments = Tb rows (lane&15 = atom, 8
// consecutive kj per lane = m97's verified pattern). D (C/D layout m89:
// col=lane&15=atom, row=(lane>>4)*4+reg -> i) scattered to AHa[atom][68].
// Phase C: fp32 GRU matvec; agg broadcast from AHa, h via wave-uniform
// loads, weights coalesced float4; output convex-combine in registers.
#define MW 4
#define MAW 4
__global__ __launch_bounds__(256, 4) void k_msg(
    const float* __restrict__ h_in, const int* __restrict__ start,
    const int* __restrict__ sdst, const float* __restrict__ sbf,
    const unsigned short* __restrict__ KrA, const float* __restrict__ wiT,
    const float* __restrict__ whT, const float* __restrict__ bih,
    const float* __restrict__ bhh, float* __restrict__ h_out) {
  __shared__ __align__(16) unsigned short Tb[16 * 584];   // 18,688 B
  __shared__ __align__(16) float AHa[16 * 68];            // 4,352 B
  const int tid = threadIdx.x, lane = tid & 63, wv = tid >> 6;
  const int ablk = blockIdx.x * 16;
  const int awave = ablk + wv * MAW;

  // ---- Phase A: per-atom gather (scalar bf coeffs, fp32 accum, bf16 flush) ----
  for (int a = 0; a < MAW; ++a) {
    const int s0 = __builtin_amdgcn_readfirstlane(start[awave + a]);
    const int s1 = __builtin_amdgcn_readfirstlane(start[awave + a + 1]);
    float t[9] = {0.f, 0.f, 0.f, 0.f, 0.f, 0.f, 0.f, 0.f, 0.f};
    for (int base = s0; base < s1; base += 8) {
      const int nb = s1 - base;
      float hv[8];
#pragma unroll
      for (int i = 0; i < 8; ++i) {
        int d = (i < nb) ? sdst[base + i] : 0;
        hv[i] = (i < nb) ? h_in[d * 64 + lane] : 0.f;
      }
#pragma unroll
      for (int i = 0; i < 8; ++i) {
#pragma unroll
        for (int k = 0; k < 8; ++k)
          t[k] = fmaf(sbf[(base + i) * 8 + k], hv[i], t[k]);   // hv=0 kills pad terms
        t[8] += hv[i];
      }
    }
    const int row = wv * MAW + a;
#pragma unroll
    for (int k = 0; k < 9; ++k) Tb[row * 584 + k * 64 + lane] = bf16bits(t[k]);
  }
  __syncthreads();

  // ---- Phase B: MFMA  agg[i][atom] = sum_kj K[i][kj] * T[atom][kj] ----
  f32x4 acc = {0.f, 0.f, 0.f, 0.f};
  const bfrag8* KrA8 = reinterpret_cast<const bfrag8*>(KrA);
  const int tb_base = (lane & 15) * 584 + ((lane >> 4) << 3);
#pragma unroll 3
  for (int ks = 0; ks < 18; ++ks) {
    bfrag8 af = KrA8[(wv * 18 + ks) * 64 + lane];
    bfrag8 bfr = *reinterpret_cast<const bfrag8*>(&Tb[tb_base + ks * 32]);
    acc = __builtin_amdgcn_mfma_f32_16x16x32_bf16(af, bfr, acc, 0, 0, 0);
  }
#pragma unroll
  for (int reg = 0; reg < 4; ++reg) {
    const int ii = wv * 16 + ((lane >> 4) << 2) + reg;   // i index
    AHa[(lane & 15) * 68 + ii] = acc[reg];               // pad-68: conflict-free
  }
  __syncthreads();

  // ---- Phase C: fp32 GRU (lane = output i) ----
  float hreg[MAW];
#pragma unroll
  for (int a = 0; a < MAW; ++a) hreg[a] = h_in[(awave + a) * 64 + lane];
  float air[MAW], aiz[MAW], ain[MAW], ahr[MAW], ahz[MAW], ahn[MAW];
#pragma unroll
  for (int a = 0; a < MAW; ++a) { air[a]=0.f; aiz[a]=0.f; ain[a]=0.f; ahr[a]=0.f; ahz[a]=0.f; ahn[a]=0.f; }
  const float4* wiT4 = reinterpret_cast<const float4*>(wiT);
  const float4* whT4 = reinterpret_cast<const float4*>(whT);
#pragma unroll 2
  for (int j4 = 0; j4 < 16; ++j4) {
    const float4 wi0 = wiT4[j4 * 192 + lane];
    const float4 wi1 = wiT4[j4 * 192 + 64 + lane];
    const float4 wi2 = wiT4[j4 * 192 + 128 + lane];
    const float4 wh0 = whT4[j4 * 192 + lane];
    const float4 wh1 = whT4[j4 * 192 + 64 + lane];
    const float4 wh2 = whT4[j4 * 192 + 128 + lane];
#pragma unroll
    for (int a = 0; a < MAW; ++a) {
      const int arow = wv * MAW + a;
      const float4 av = *reinterpret_cast<const float4*>(&AHa[arow * 68 + j4 * 4]);
      const float4 hv = *reinterpret_cast<const float4*>(&h_in[(awave + a) * 64 + j4 * 4]);
      air[a] += wi0.x*av.x + wi0.y*av.y + wi0.z*av.z + wi0.w*av.w;
      aiz[a] += wi1.x*av.x + wi1.y*av.y + wi1.z*av.z + wi1.w*av.w;
      ain[a] += wi2.x*av.x + wi2.y*av.y + wi2.z*av.z + wi2.w*av.w;
      ahr[a] += wh0.x*hv.x + wh0.y*hv.y + wh0.z*hv.z + wh0.w*hv.w;
      ahz[a] += wh1.x*hv.x + wh1.y*hv.y + wh1.z*hv.z + wh1.w*hv.w;
      ahn[a] += wh2.x*hv.x + wh2.y*hv.y + wh2.z*hv.z + wh2.w*hv.w;
    }
  }
  const float bir = bih[lane], biz = bih[64 + lane], bin_ = bih[128 + lane];
  const float bhr = bhh[lane], bhz = bhh[64 + lane], bhn = bhh[128 + lane];
#pragma unroll
  for (int a = 0; a < MAW; ++a) {
    float r = sigmoidf_((air[a] + bir) + (ahr[a] + bhr));
    float z = sigmoidf_((aiz[a] + biz) + (ahz[a] + bhz));
    float nn = tanhf((ain[a] + bin_) + r * (ahn[a] + bhn));
    h_out[(awave + a) * 64 + lane] = (1.0f - z) * nn + z * hreg[a];
  }
}

// ============ qkv projection + valid mask ============
#define QABLK 4
__global__ __launch_bounds__(256, 1) void k_qkv(
    const float* __restrict__ h, const float* __restrict__ w,
    const float* __restrict__ b, float* __restrict__ qkv,
    int* __restrict__ valid) {
  __shared__ __align__(16) float w_s[192 * 64];
  __shared__ __align__(16) float x_s[4][QABLK][64];
  const int tid = threadIdx.x, lane = tid & 63, wv = tid >> 6;
  for (int idx = tid; idx < 192 * 64; idx += 256) {
    int r = idx >> 6, d = idx & 63;
    w_s[(r << 6) + ((((d >> 2) ^ (r & 7)) << 2) | (d & 3))] = w[idx];
  }
  __syncthreads();
  const float4* w4 = reinterpret_cast<const float4*>(w_s);
  const float bq = b[lane], bk = b[64 + lane], bv_ = b[128 + lane];
  const int swz = lane & 7;
  const int gw = blockIdx.x * 4 + wv;
  const int stride = gridDim.x * 4 * QABLK;
  for (int ag = gw * QABLK; ag < NA; ag += stride) {
#pragma unroll
    for (int e = 0; e < QABLK; ++e) x_s[wv][e][lane] = h[(ag + e) * 64 + lane];
    __syncthreads();
    const float4* x4 = reinterpret_cast<const float4*>(&x_s[wv][0][0]);
    float aq[QABLK] = {0,0,0,0}, ak[QABLK] = {0,0,0,0}, av_[QABLK] = {0,0,0,0};
    int nz[QABLK] = {0,0,0,0};
#pragma unroll 4
    for (int d4 = 0; d4 < 16; ++d4) {
      int sl = d4 ^ swz;
      float4 wq = w4[(lane << 4) + sl];
      float4 wk = w4[((lane + 64) << 4) + sl];
      float4 wvv = w4[((lane + 128) << 4) + sl];
#pragma unroll
      for (int e = 0; e < QABLK; ++e) {
        float4 xv = x4[e * 16 + d4];
        aq[e] += wq.x*xv.x + wq.y*xv.y + wq.z*xv.z + wq.w*xv.w;
        ak[e] += wk.x*xv.x + wk.y*xv.y + wk.z*xv.z + wk.w*xv.w;
        av_[e] += wvv.x*xv.x + wvv.y*xv.y + wvv.z*xv.z + wvv.w*xv.w;
        nz[e] |= (int)(xv.x != 0.f) | (int)(xv.y != 0.f) | (int)(xv.z != 0.f) | (int)(xv.w != 0.f);
      }
    }
#pragma unroll
    for (int e = 0; e < QABLK; ++e) {
      qkv[(ag + e) * 192 + lane] = aq[e] + bq;
      qkv[(ag + e) * 192 + 64 + lane] = ak[e] + bk;
      qkv[(ag + e) * 192 + 128 + lane] = av_[e] + bv_;
      if (lane == 0) valid[ag + e] = nz[e];
    }
    __syncthreads();
  }
}

// ============ attention: one wave per (molecule, head), online softmax ============
__global__ void k_attn(const float* __restrict__ qkv, const int* __restrict__ valid,
                       float* __restrict__ ao) {
  const int b = blockIdx.x >> 3, hh = blockIdx.x & 7;
  __shared__ float k_s[64][8];
  __shared__ float v_s[64][8];
  __shared__ int vd_s[64];
  const int lane = threadIdx.x;
  const int rowbase = (b * 64 + lane) * 192;
#pragma unroll
  for (int j = 0; j < 8; ++j) {
    k_s[lane][j] = qkv[rowbase + 64 + hh * 8 + j];
    v_s[lane][j] = qkv[rowbase + 128 + hh * 8 + j];
  }
  vd_s[lane] = valid[b * 64 + lane];
  __syncthreads();
  float q[8];
#pragma unroll
  for (int j = 0; j < 8; ++j) q[j] = qkv[rowbase + hh * 8 + j];
  float m = -3.0e38f, l = 0.f, o[8] = {0,0,0,0,0,0,0,0};
  for (int t = 0; t < 64; ++t) {
    float s = 0.f;
#pragma unroll
    for (int j = 0; j < 8; ++j) s += q[j] * k_s[t][j];
    s *= 0.35355339059327373f;
    s = vd_s[t] ? s : -1.0e9f;
    float mn = fmaxf(m, s);
    float c = expf(m - mn);
    float p = expf(s - mn);
    l = l * c + p;
#pragma unroll
    for (int j = 0; j < 8; ++j) o[j] = o[j] * c + p * v_s[t][j];
    m = mn;
  }
  const float inv = 1.0f / l;
  const int obase = (b * 64 + lane) * 64 + hh * 8;
#pragma unroll
  for (int j = 0; j < 8; ++j) ao[obase + j] = o[j] * inv;
}

// ============ out_proj + residual + LN1 ============
#define OABLK 4
__global__ __launch_bounds__(256, 1) void k_out_ln1(
    const float* __restrict__ x, const float* __restrict__ ao,
    const float* __restrict__ w, const float* __restrict__ bias,
    const float* __restrict__ g, const float* __restrict__ bb,
    float* __restrict__ y1) {
  __shared__ __align__(16) float w_s[64 * 64];
  __shared__ __align__(16) float a_s[4][OABLK][64];
  const int tid = threadIdx.x, lane = tid & 63, wv = tid >> 6;
  for (int idx = tid; idx < 64 * 64; idx += 256) {
    int r = idx >> 6, d = idx & 63;
    w_s[(r << 6) + ((((d >> 2) ^ (r & 7)) << 2) | (d & 3))] = w[idx];
  }
  __syncthreads();
  const float4* w4 = reinterpret_cast<const float4*>(w_s);
  const float bo = bias[lane], gg = g[lane], bbb = bb[lane];
  const int swz = lane & 7;
  const int gw = blockIdx.x * 4 + wv;
  const int stride = gridDim.x * 4 * OABLK;
  for (int ag = gw * OABLK; ag < NA; ag += stride) {
#pragma unroll
    for (int e = 0; e < OABLK; ++e) a_s[wv][e][lane] = ao[(ag + e) * 64 + lane];
    __syncthreads();
    const float4* a4 = reinterpret_cast<const float4*>(&a_s[wv][0][0]);
    float acc[OABLK] = {0,0,0,0};
#pragma unroll 4
    for (int d4 = 0; d4 < 16; ++d4) {
      int sl = d4 ^ swz;
      float4 wr = w4[(lane << 4) + sl];
#pragma unroll
      for (int e = 0; e < OABLK; ++e) {
        float4 av = a4[e * 16 + d4];
        acc[e] += wr.x*av.x + wr.y*av.y + wr.z*av.z + wr.w*av.w;
      }
    }
#pragma unroll
    for (int e = 0; e < OABLK; ++e) {
      float val = acc[e] + bo + x[(ag + e) * 64 + lane];
      float s1 = val, s2 = val * val;
#pragma unroll
      for (int mm = 1; mm < 64; mm <<= 1) {
        s1 += __shfl_xor(s1, mm, 64);
        s2 += __shfl_xor(s2, mm, 64);
      }
      float mu = s1 * 0.015625f;
      float var = s2 * 0.015625f - mu * mu;
      y1[(ag + e) * 64 + lane] = (val - mu) * rsqrtf(var + 1e-5f) * gg + bbb;
    }
    __syncthreads();
  }
}

// ============ FFN (512 hidden) + residual + LN2 ============
#define FW 4
#define FABLK 8
__global__ __launch_bounds__(256, 2) void k_ffn(
    const float* __restrict__ y1, const float* __restrict__ w1,
    const float* __restrict__ b1, const float* __restrict__ w2,
    const float* __restrict__ b2, const float* __restrict__ g,
    const float* __restrict__ bb, float* __restrict__ y2) {
  __shared__ __align__(16) float hbuf[FW][FABLK][512];   // 64 KB
  __shared__ __align__(16) float y1_s[FW][FABLK][64];    // 8 KB
  const int tid = threadIdx.x, lane = tid & 63, wv = tid >> 6;
  const float4* w1_4 = reinterpret_cast<const float4*>(w1);
  const float4* b1_4 = reinterpret_cast<const float4*>(b1);
  const float b2v = b2[lane], gg = g[lane], bbb = bb[lane];
  const int gw = blockIdx.x * FW + wv;
  const int stride = gridDim.x * FW * FABLK;
  for (int ag = gw * FABLK; ag < NA; ag += stride) {
#pragma unroll
    for (int e = 0; e < FABLK; ++e) y1_s[wv][e][lane] = y1[(ag + e) * 64 + lane];
    __syncthreads();
    float4 hv0[FABLK], hv1[FABLK];
    const float4 bq0 = b1_4[lane], bq1 = b1_4[64 + lane];
#pragma unroll
    for (int e = 0; e < FABLK; ++e) { hv0[e] = bq0; hv1[e] = bq1; }
#pragma unroll 4
    for (int d = 0; d < 64; ++d) {
      float4 w0 = w1_4[d * 128 + lane];
      float4 w1v = w1_4[d * 128 + 64 + lane];
#pragma unroll
      for (int e = 0; e < FABLK; ++e) {
        float yv = y1_s[wv][e][d];
        hv0[e].x = fmaf(yv, w0.x, hv0[e].x);
        hv0[e].y = fmaf(yv, w0.y, hv0[e].y);
        hv0[e].z = fmaf(yv, w0.z, hv0[e].z);
        hv0[e].w = fmaf(yv, w0.w, hv0[e].w);
        hv1[e].x = fmaf(yv, w1v.x, hv1[e].x);
        hv1[e].y = fmaf(yv, w1v.y, hv1[e].y);
        hv1[e].z = fmaf(yv, w1v.z, hv1[e].z);
        hv1[e].w = fmaf(yv, w1v.w, hv1[e].w);
      }
    }
    float4* hb4w = reinterpret_cast<float4*>(&hbuf[wv][0][0]);
#pragma unroll
    for (int e = 0; e < FABLK; ++e) {
      float4 r0 = hv0[e], r1 = hv1[e];
      r0.x = fmaxf(r0.x, 0.f); r0.y = fmaxf(r0.y, 0.f);
      r0.z = fmaxf(r0.z, 0.f); r0.w = fmaxf(r0.w, 0.f);
      r1.x = fmaxf(r1.x, 0.f); r1.y = fmaxf(r1.y, 0.f);
      r1.z = fmaxf(r1.z, 0.f); r1.w = fmaxf(r1.w, 0.f);
      hb4w[e * 128 + lane] = r0;
      hb4w[e * 128 + 64 + lane] = r1;
    }
    __syncthreads();
    float acc[FABLK] = {0,0,0,0,0,0,0,0};
    const float4* hb4 = reinterpret_cast<const float4*>(&hbuf[wv][0][0]);
#pragma unroll 4
    for (int c4 = 0; c4 < 128; ++c4) {
      float w2v0 = w2[(c4 * 4 + 0) * 64 + lane];
      float w2v1 = w2[(c4 * 4 + 1) * 64 + lane];
      float w2v2 = w2[(c4 * 4 + 2) * 64 + lane];
      float w2v3 = w2[(c4 * 4 + 3) * 64 + lane];
#pragma unroll
      for (int e = 0; e < FABLK; ++e) {
        float4 hq = hb4[e * 128 + c4];
        acc[e] = fmaf(hq.x, w2v0, acc[e]);
        acc[e] = fmaf(hq.y, w2v1, acc[e]);
        acc[e] = fmaf(hq.z, w2v2, acc[e]);
        acc[e] = fmaf(hq.w, w2v3, acc[e]);
      }
    }
#pragma unroll
    for (int e = 0; e < FABLK; ++e) {
      float val = y1_s[wv][e][lane] + acc[e] + b2v;
      float s1 = val, s2 = val * val;
#pragma unroll
      for (int mm = 1; mm < 64; mm <<= 1) {
        s1 += __shfl_xor(s1, mm, 64);
        s2 += __shfl_xor(s2, mm, 64);
      }
      float mu = s1 * 0.015625f;
      float var = s2 * 0.015625f - mu * mu;
      y2[(ag + e) * 64 + lane] = (val - mu) * rsqrtf(var + 1e-5f) * gg + bbb;
    }
    __syncthreads();
  }
}

// ============ mean-pool over tokens ============
__global__ void k_pool(const float* __restrict__ y2, float* __restrict__ pooled) {
  const int b = blockIdx.x, lane = threadIdx.x;
  float s = 0.f;
  for (int t = 0; t < 64; ++t) s += y2[(b * 64 + t) * 64 + lane];
  pooled[b * 64 + lane] = s * 0.015625f;
}

// ============ readout head ============
__global__ __launch_bounds__(256) void k_head(
    const float* __restrict__ pooled, const float* __restrict__ d1w,
    const float* __restrict__ d1b, const float* __restrict__ d2w,
    const float* __restrict__ d2b, float* __restrict__ out) {
  const int b = blockIdx.x;
  __shared__ float p_s[64];
  __shared__ float red_s[4];
  const int tid = threadIdx.x;
  if (tid < 64) p_s[tid] = pooled[b * 64 + tid];
  __syncthreads();
  float acc = 0.f;
#pragma unroll
  for (int rep = 0; rep < 2; ++rep) {
    int c = rep * 256 + tid;
    float hvv = d1b[c];
    for (int d = 0; d < 64; ++d) hvv += p_s[d] * d1w[d * 512 + c];
    acc += fmaxf(hvv, 0.f) * d2w[c];
  }
#pragma unroll
  for (int mm = 1; mm < 64; mm <<= 1) acc += __shfl_xor(acc, mm, 64);
  if ((tid & 63) == 0) red_s[tid >> 6] = acc;
  __syncthreads();
  if (tid == 0) {
    float t = red_s[0] + red_s[1] + red_s[2] + red_s[3] + d2b[0];
    out[b] = 1.0f / (1.0f + expf(-t));
  }
}

extern "C" void kernel_launch(void* const* d_in, const int* in_sizes, int n_in,
                              void* d_out, int out_size, void* d_ws, size_t ws_size,
                              hipStream_t stream) {
  (void)in_sizes; (void)n_in; (void)out_size; (void)ws_size;
  const float* af   = (const float*)d_in[0];
  const float* bfeat= (const float*)d_in[1];
  const int*   pairs= (const int*)d_in[2];
  // d_in[3] = molecule_indicator (identity layout; unused)
  const float* kern = (const float*)d_in[4];
  const float* kbias= (const float*)d_in[5];
  const float* wih  = (const float*)d_in[6];
  const float* whh  = (const float*)d_in[7];
  const float* bih  = (const float*)d_in[8];
  const float* bhh  = (const float*)d_in[9];
  const float* ipw  = (const float*)d_in[10];
  const float* ipb  = (const float*)d_in[11];
  const float* opw  = (const float*)d_in[12];
  const float* opb  = (const float*)d_in[13];
  const float* fw1  = (const float*)d_in[14];
  const float* fb1  = (const float*)d_in[15];
  const float* fw2  = (const float*)d_in[16];
  const float* fb2  = (const float*)d_in[17];
  const float* l1g  = (const float*)d_in[18];
  const float* l1b  = (const float*)d_in[19];
  const float* l2g  = (const float*)d_in[20];
  const float* l2b  = (const float*)d_in[21];
  const float* d1w  = (const float*)d_in[22];
  const float* d1b  = (const float*)d_in[23];
  const float* d2w  = (const float*)d_in[24];
  const float* d2b  = (const float*)d_in[25];
  float* out = (float*)d_out;

  // workspace layout (floats)
  float* ws = (float*)d_ws;
  float* h      = ws;                    // ping buffer (final h after 4 steps)
  float* h2     = h + (size_t)NA * 64;   // pong buffer
  float* qkv    = h2 + (size_t)NA * 64;
  float* ao     = qkv + (size_t)NA * 192;
  float* y1     = ao + (size_t)NA * 64;
  float* y2     = y1 + (size_t)NA * 64;
  float* pooled = y2 + (size_t)NA * 64;
  int*   valid  = (int*)(pooled + 256 * 64);

  // MP-loop scratch aliased into the qkv region (dead until after the loop):
  unsigned short* KrA = (unsigned short*)qkv;  // 36864 ushort (fits 36864-float slot)
  int*   count  = (int*)(qkv + 36864);         // NA
  int*   start  = count + NA;                  // NA+1
  int*   cursor = start + NA + 1;              // NA
  int*   elist  = cursor + NA;                 // NE
  int*   bsum   = elist + NE;                  // 256
  int*   sdst   = bsum + 256;                  // NE + 8 pad
  float* sbf    = (float*)(sdst + NE + 8);     // NE*8 + 64 pad
  float* wiT    = sbf + (size_t)NE * 8 + 64;   // 12288
  float* whT    = wiT + 12288;                 // 12288

  k_init_h<<<NA * 64 / 256, 256, 0, stream>>>(af, h);
  k_prep_KrA<<<144, 256, 0, stream>>>(kern, kbias, KrA);
  k_prep_wT<<<48, 256, 0, stream>>>(wih, whh, wiT, whT);
  hipMemsetAsync(count, 0, (size_t)NA * sizeof(int), stream);
  k_count<<<NE / 256, 256, 0, stream>>>(pairs, count);
  k_scan1<<<64, 256, 0, stream>>>(count, bsum);
  k_scan2<<<64, 256, 0, stream>>>(count, bsum, start, cursor);
  k_place<<<NE / 256, 256, 0, stream>>>(pairs, cursor, elist);
  k_reorder<<<NE * 8 / 256, 256, 0, stream>>>(bfeat, pairs, elist, sdst, sbf);

  float* hin = h;
  float* hout = h2;
  for (int s = 0; s < 4; ++s) {
    k_msg<<<NA / 16, 256, 0, stream>>>(hin, start, sdst, sbf, KrA,
                                       wiT, whT, bih, bhh, hout);
    float* tmp = hin; hin = hout; hout = tmp;
  }
  // 4 swaps -> final h is back in 'h'

  k_qkv<<<512, 256, 0, stream>>>(h, ipw, ipb, qkv, valid);
  k_attn<<<2048, 64, 0, stream>>>(qkv, valid, ao);
  k_out_ln1<<<512, 256, 0, stream>>>(h, ao, opw, opb, l1g, l1b, y1);
  k_ffn<<<512, 256, 0, stream>>>(y1, fw1, fb1, fw2, fb2, l2g, l2b, y2);
  k_pool<<<256, 64, 0, stream>>>(y2, pooled);
  k_head<<<256, 256, 0, stream>>>(pooled, d1w, d1b, d2w, d2b, out);
}

// Round 11
// 207.179 us; speedup vs baseline: 2.1421x; 1.3331x over previous
//
#include <hip/hip_runtime.h>
#include <hip/hip_bf16.h>
#include <math.h>

#define NA 16384
#define NE 65536
#define AD 29

typedef __attribute__((ext_vector_type(8))) short bfrag8;
typedef __attribute__((ext_vector_type(4))) float f32x4;

__device__ __forceinline__ float sigmoidf_(float x) { return 1.0f / (1.0f + expf(-x)); }
__device__ __forceinline__ unsigned short bf16bits(float x) {
  __hip_bfloat16 hb = __float2bfloat16(x);
  return *reinterpret_cast<unsigned short*>(&hb);
}
__device__ __forceinline__ float bf16val(unsigned short u) {
  unsigned int b = ((unsigned int)u) << 16;
  return __uint_as_float(b);
}

// ============ init h: pad atom features 29 -> 64 ============
__global__ void k_init_h(const float* __restrict__ af, float* __restrict__ h) {
  int idx = blockIdx.x * 256 + threadIdx.x;
  if (idx >= NA * 64) return;
  int a = idx >> 6, d = idx & 63;
  h[idx] = (d < AD) ? af[a * AD + d] : 0.0f;
}

// ============ K -> A-fragment relayout (once per call), bf16 (phase B).
__global__ void k_prep_KrA(const float* __restrict__ kern, const float* __restrict__ kbias,
                           unsigned short* __restrict__ KrA) {
  int idx = blockIdx.x * 256 + threadIdx.x;    // 4*18*64*8 = 36864
  if (idx >= 36864) return;
  int r = idx & 7;
  int tmp = idx >> 3;
  int lane = tmp & 63;
  int tmp2 = tmp >> 6;            // w*18 + ks
  int ks = tmp2 % 18, w = tmp2 / 18;
  int i = w * 16 + (lane & 15);
  int kj = ks * 32 + ((lane >> 4) << 3) + r;
  int k9 = kj >> 6, j = kj & 63;
  float v = (k9 < 8) ? kern[k9 * 4096 + i * 64 + j] : kbias[i * 64 + j];
  KrA[idx] = bf16bits(v);
}

// ============ GRU weights -> A-fragments, split-bf16 hi/lo (once per call).
// Tile slot q = s*3+g (s: 0=ih,1=hh; g: 0=r,1=z,2=n); wave w owns i-chunk w.
// idx = (((w*6+q)*2+ks)*64 + lane)*8 + r; A row i_loc = lane&15 ->
// weight row R = g*64 + w*16 + (lane&15); kk = ks*32 + (lane>>4)*8 + r.
__global__ void k_prep_Wg(const float* __restrict__ wih, const float* __restrict__ whh,
                          unsigned short* __restrict__ Wh, unsigned short* __restrict__ Wl) {
  int idx = blockIdx.x * 256 + threadIdx.x;    // 24576
  if (idx >= 24576) return;
  int r = idx & 7;
  int lane = (idx >> 3) & 63;
  int t2 = idx >> 9;            // (w*6+q)*2 + ks
  int ks = t2 & 1;
  int t3 = t2 >> 1;             // w*6 + q
  int q = t3 % 6, w = t3 / 6;
  int s = q / 3, g = q % 3;
  int R = g * 64 + w * 16 + (lane & 15);
  int kk = ks * 32 + ((lane >> 4) << 3) + r;
  float v = (s == 0) ? wih[R * 64 + kk] : whh[R * 64 + kk];
  unsigned short hi = bf16bits(v);
  Wh[idx] = hi;
  Wl[idx] = bf16bits(v - bf16val(hi));
}

// ============ edge bucketing by src (once per call; counting sort) ============
__global__ void k_count(const int* __restrict__ pairs, int* __restrict__ count) {
  int e = blockIdx.x * 256 + threadIdx.x;
  if (e >= NE) return;
  atomicAdd(&count[pairs[2 * e]], 1);
}
__global__ void k_scan1(const int* __restrict__ count, int* __restrict__ bsum) {
  __shared__ int red[256];
  int b = blockIdx.x, t = threadIdx.x;
  red[t] = count[b * 256 + t];
  __syncthreads();
  for (int s = 128; s > 0; s >>= 1) { if (t < s) red[t] += red[t + s]; __syncthreads(); }
  if (t == 0) bsum[b] = red[0];
}
__global__ void k_scan2(const int* __restrict__ count, const int* __restrict__ bsum,
                        int* __restrict__ start, int* __restrict__ cursor) {
  __shared__ int sc[256];
  __shared__ int basev;
  int b = blockIdx.x, t = threadIdx.x;
  if (t == 0) { int s = 0; for (int i = 0; i < b; ++i) s += bsum[i]; basev = s; }
  int v = count[b * 256 + t];
  sc[t] = v;
  __syncthreads();
  for (int off = 1; off < 256; off <<= 1) {
    int add = (t >= off) ? sc[t - off] : 0;
    __syncthreads();
    sc[t] += add;
    __syncthreads();
  }
  int excl = sc[t] - v + basev;
  start[b * 256 + t] = excl;
  cursor[b * 256 + t] = excl;
  if (b * 256 + t == NA - 1) start[NA] = excl + v;   // sentinel = NE
}
__global__ void k_place(const int* __restrict__ pairs, int* __restrict__ cursor,
                        int* __restrict__ elist) {
  int e = blockIdx.x * 256 + threadIdx.x;
  if (e >= NE) return;
  int pos = atomicAdd(&cursor[pairs[2 * e]], 1);
  elist[pos] = e;
}
__global__ void k_reorder(const float* __restrict__ bf, const int* __restrict__ pairs,
                          const int* __restrict__ elist, int* __restrict__ sdst,
                          float* __restrict__ sbf) {
  int idx = blockIdx.x * 256 + threadIdx.x;    // NE*8 threads
  if (idx >= NE * 8) return;
  int pos = idx >> 3, k = idx & 7;
  int e = elist[pos];
  sbf[idx] = bf[e * 8 + k];
  if (k == 0) sdst[pos] = pairs[2 * e + 1];
}

// ============ fused message + GRU step, fully MFMA'd dense parts ============
// Block = 16 atoms (4 waves x 4).
// Stage: h rows -> Hf (fp32) + Xh/Xl[.][64..127] (bf16 hi/lo).
// Phase A: per-atom edge gather -> Tb bf16 rows (unchanged from round 10).
// Phase B: 18x mfma_f32_16x16x32_bf16 -> agg; split into Xh/Xl[.][0..63].
// Phase C: GRU matvec as MFMA: D[gate-rows][atom] = W @ X with W prepped
//          hi/lo A-frags (3-product split-bf16 ~= fp32 accuracy); wave w owns
//          i-chunk w for all 6 (src,gate) tiles so each lane holds matched
//          (i_r,i_z,i_n,h_r,h_z,h_n); GRU nonlinearity in-register; result
//          staged to AHa for coalesced h_out write.
#define MW 4
#define MAW 4
__global__ __launch_bounds__(256, 4) void k_msg(
    const float* __restrict__ h_in, const int* __restrict__ start,
    const int* __restrict__ sdst, const float* __restrict__ sbf,
    const unsigned short* __restrict__ KrA,
    const unsigned short* __restrict__ Wh, const unsigned short* __restrict__ Wl,
    const float* __restrict__ bih, const float* __restrict__ bhh,
    float* __restrict__ h_out) {
  __shared__ __align__(16) unsigned short Tb[16 * 584];   // 18,688 B
  __shared__ __align__(16) unsigned short Xh[16 * 136];   // 4,352 B
  __shared__ __align__(16) unsigned short Xl[16 * 136];   // 4,352 B
  __shared__ __align__(16) float Hf[16 * 68];             // 4,352 B
  __shared__ __align__(16) float AHa[16 * 68];            // 4,352 B
  __shared__ float bias_s[384];                           // 1,536 B
  const int tid = threadIdx.x, lane = tid & 63, wv = tid >> 6;
  const int ablk = blockIdx.x * 16;
  const int awave = ablk + wv * MAW;

  // ---- stage h (fp32 + bf16 hi/lo) and biases ----
#pragma unroll
  for (int aa = 0; aa < MAW; ++aa) {
    const int a = wv * MAW + aa;
    const float v = h_in[(ablk + a) * 64 + lane];
    Hf[a * 68 + lane] = v;
    const unsigned short hi = bf16bits(v);
    Xh[a * 136 + 64 + lane] = hi;
    Xl[a * 136 + 64 + lane] = bf16bits(v - bf16val(hi));
  }
  if (tid < 192) { bias_s[tid] = bih[tid]; bias_s[192 + tid] = bhh[tid]; }

  // ---- Phase A: per-atom gather (scalar bf coeffs, fp32 accum, bf16 flush) ----
  const int bb = (lane <= MAW * 4) ? 0 : 0;  (void)bb;
  for (int a = 0; a < MAW; ++a) {
    const int s0 = __builtin_amdgcn_readfirstlane(start[awave + a]);
    const int s1 = __builtin_amdgcn_readfirstlane(start[awave + a + 1]);
    float t[9] = {0.f, 0.f, 0.f, 0.f, 0.f, 0.f, 0.f, 0.f, 0.f};
    for (int base = s0; base < s1; base += 8) {
      const int nb = s1 - base;
      float hv[8];
#pragma unroll
      for (int i = 0; i < 8; ++i) {
        int d = (i < nb) ? sdst[base + i] : 0;
        hv[i] = (i < nb) ? h_in[d * 64 + lane] : 0.f;
      }
#pragma unroll
      for (int i = 0; i < 8; ++i) {
#pragma unroll
        for (int k = 0; k < 8; ++k)
          t[k] = fmaf(sbf[(base + i) * 8 + k], hv[i], t[k]);   // hv=0 kills pad terms
        t[8] += hv[i];
      }
    }
    const int row = wv * MAW + a;
#pragma unroll
    for (int k = 0; k < 9; ++k) Tb[row * 584 + k * 64 + lane] = bf16bits(t[k]);
  }
  __syncthreads();

  // ---- Phase B: MFMA  agg[i][atom] = sum_kj K[i][kj] * T[atom][kj] ----
  f32x4 acc = {0.f, 0.f, 0.f, 0.f};
  const bfrag8* KrA8 = reinterpret_cast<const bfrag8*>(KrA);
  const int tb_base = (lane & 15) * 584 + ((lane >> 4) << 3);
#pragma unroll 3
  for (int ks = 0; ks < 18; ++ks) {
    bfrag8 af = KrA8[(wv * 18 + ks) * 64 + lane];
    bfrag8 bfr = *reinterpret_cast<const bfrag8*>(&Tb[tb_base + ks * 32]);
    acc = __builtin_amdgcn_mfma_f32_16x16x32_bf16(af, bfr, acc, 0, 0, 0);
  }
  // split agg into Xh/Xl (C/D layout: col=lane&15=atom, row=(lane>>4)*4+reg -> i)
#pragma unroll
  for (int reg = 0; reg < 4; ++reg) {
    const int ii = wv * 16 + ((lane >> 4) << 2) + reg;
    const unsigned short hi = bf16bits(acc[reg]);
    Xh[(lane & 15) * 136 + ii] = hi;
    Xl[(lane & 15) * 136 + ii] = bf16bits(acc[reg] - bf16val(hi));
  }
  __syncthreads();

  // ---- Phase C: GRU matvec via MFMA (3-product split-bf16) ----
  const bfrag8* Wh8 = reinterpret_cast<const bfrag8*>(Wh);
  const bfrag8* Wl8 = reinterpret_cast<const bfrag8*>(Wl);
  f32x4 g0 = {0,0,0,0}, g1 = {0,0,0,0}, g2 = {0,0,0,0};
  f32x4 g3 = {0,0,0,0}, g4 = {0,0,0,0}, g5 = {0,0,0,0};
  f32x4* gptr[6] = {&g0, &g1, &g2, &g3, &g4, &g5};
#pragma unroll
  for (int q = 0; q < 6; ++q) {
    const int s = q / 3;
    f32x4 g = *gptr[q];
#pragma unroll
    for (int ks = 0; ks < 2; ++ks) {
      const int fidx = ((wv * 6 + q) * 2 + ks) * 64 + lane;
      bfrag8 Ah = Wh8[fidx];
      bfrag8 Al = Wl8[fidx];
      const int xoff = (lane & 15) * 136 + (s * 2 + ks) * 32 + ((lane >> 4) << 3);
      bfrag8 Bh = *reinterpret_cast<const bfrag8*>(&Xh[xoff]);
      bfrag8 Bl = *reinterpret_cast<const bfrag8*>(&Xl[xoff]);
      g = __builtin_amdgcn_mfma_f32_16x16x32_bf16(Ah, Bh, g, 0, 0, 0);
      g = __builtin_amdgcn_mfma_f32_16x16x32_bf16(Ah, Bl, g, 0, 0, 0);
      g = __builtin_amdgcn_mfma_f32_16x16x32_bf16(Al, Bh, g, 0, 0, 0);
    }
    *gptr[q] = g;
  }
  // combine gates: lane holds atom=lane&15, i = wv*16+(lane>>4)*4+reg
#pragma unroll
  for (int reg = 0; reg < 4; ++reg) {
    const int i = wv * 16 + ((lane >> 4) << 2) + reg;
    const int atom = lane & 15;
    const float r = sigmoidf_(g0[reg] + bias_s[i] + g3[reg] + bias_s[192 + i]);
    const float z = sigmoidf_(g1[reg] + bias_s[64 + i] + g4[reg] + bias_s[256 + i]);
    const float nn = tanhf(g2[reg] + bias_s[128 + i] + r * (g5[reg] + bias_s[320 + i]));
    const float hold = Hf[atom * 68 + i];
    AHa[atom * 68 + i] = (1.0f - z) * nn + z * hold;
  }
  __syncthreads();
#pragma unroll
  for (int aa = 0; aa < MAW; ++aa) {
    const int a = wv * MAW + aa;
    h_out[(ablk + a) * 64 + lane] = AHa[a * 68 + lane];
  }
}

// ============ qkv projection + valid mask ============
#define QABLK 4
__global__ __launch_bounds__(256, 2) void k_qkv(
    const float* __restrict__ h, const float* __restrict__ w,
    const float* __restrict__ b, float* __restrict__ qkv,
    int* __restrict__ valid) {
  __shared__ __align__(16) float w_s[192 * 64];
  __shared__ __align__(16) float x_s[4][QABLK][64];
  const int tid = threadIdx.x, lane = tid & 63, wv = tid >> 6;
  for (int idx = tid; idx < 192 * 64; idx += 256) {
    int r = idx >> 6, d = idx & 63;
    w_s[(r << 6) + ((((d >> 2) ^ (r & 7)) << 2) | (d & 3))] = w[idx];
  }
  __syncthreads();
  const float4* w4 = reinterpret_cast<const float4*>(w_s);
  const float bq = b[lane], bk = b[64 + lane], bv_ = b[128 + lane];
  const int swz = lane & 7;
  const int gw = blockIdx.x * 4 + wv;
  const int stride = gridDim.x * 4 * QABLK;
  for (int ag = gw * QABLK; ag < NA; ag += stride) {
#pragma unroll
    for (int e = 0; e < QABLK; ++e) x_s[wv][e][lane] = h[(ag + e) * 64 + lane];
    __syncthreads();
    const float4* x4 = reinterpret_cast<const float4*>(&x_s[wv][0][0]);
    float aq[QABLK] = {0,0,0,0}, ak[QABLK] = {0,0,0,0}, av_[QABLK] = {0,0,0,0};
    int nz[QABLK] = {0,0,0,0};
#pragma unroll 4
    for (int d4 = 0; d4 < 16; ++d4) {
      int sl = d4 ^ swz;
      float4 wq = w4[(lane << 4) + sl];
      float4 wk = w4[((lane + 64) << 4) + sl];
      float4 wvv = w4[((lane + 128) << 4) + sl];
#pragma unroll
      for (int e = 0; e < QABLK; ++e) {
        float4 xv = x4[e * 16 + d4];
        aq[e] += wq.x*xv.x + wq.y*xv.y + wq.z*xv.z + wq.w*xv.w;
        ak[e] += wk.x*xv.x + wk.y*xv.y + wk.z*xv.z + wk.w*xv.w;
        av_[e] += wvv.x*xv.x + wvv.y*xv.y + wvv.z*xv.z + wvv.w*xv.w;
        nz[e] |= (int)(xv.x != 0.f) | (int)(xv.y != 0.f) | (int)(xv.z != 0.f) | (int)(xv.w != 0.f);
      }
    }
#pragma unroll
    for (int e = 0; e < QABLK; ++e) {
      qkv[(ag + e) * 192 + lane] = aq[e] + bq;
      qkv[(ag + e) * 192 + 64 + lane] = ak[e] + bk;
      qkv[(ag + e) * 192 + 128 + lane] = av_[e] + bv_;
      if (lane == 0) valid[ag + e] = nz[e];
    }
    __syncthreads();
  }
}

// ============ attention: one wave per (molecule, head), online softmax ============
__global__ void k_attn(const float* __restrict__ qkv, const int* __restrict__ valid,
                       float* __restrict__ ao) {
  const int b = blockIdx.x >> 3, hh = blockIdx.x & 7;
  __shared__ float k_s[64][8];
  __shared__ float v_s[64][8];
  __shared__ int vd_s[64];
  const int lane = threadIdx.x;
  const int rowbase = (b * 64 + lane) * 192;
#pragma unroll
  for (int j = 0; j < 8; ++j) {
    k_s[lane][j] = qkv[rowbase + 64 + hh * 8 + j];
    v_s[lane][j] = qkv[rowbase + 128 + hh * 8 + j];
  }
  vd_s[lane] = valid[b * 64 + lane];
  __syncthreads();
  float q[8];
#pragma unroll
  for (int j = 0; j < 8; ++j) q[j] = qkv[rowbase + hh * 8 + j];
  float m = -3.0e38f, l = 0.f, o[8] = {0,0,0,0,0,0,0,0};
  for (int t = 0; t < 64; ++t) {
    float s = 0.f;
#pragma unroll
    for (int j = 0; j < 8; ++j) s += q[j] * k_s[t][j];
    s *= 0.35355339059327373f;
    s = vd_s[t] ? s : -1.0e9f;
    float mn = fmaxf(m, s);
    float c = expf(m - mn);
    float p = expf(s - mn);
    l = l * c + p;
#pragma unroll
    for (int j = 0; j < 8; ++j) o[j] = o[j] * c + p * v_s[t][j];
    m = mn;
  }
  const float inv = 1.0f / l;
  const int obase = (b * 64 + lane) * 64 + hh * 8;
#pragma unroll
  for (int j = 0; j < 8; ++j) ao[obase + j] = o[j] * inv;
}

// ============ out_proj + residual + LN1 ============
#define OABLK 4
__global__ __launch_bounds__(256, 1) void k_out_ln1(
    const float* __restrict__ x, const float* __restrict__ ao,
    const float* __restrict__ w, const float* __restrict__ bias,
    const float* __restrict__ g, const float* __restrict__ bb,
    float* __restrict__ y1) {
  __shared__ __align__(16) float w_s[64 * 64];
  __shared__ __align__(16) float a_s[4][OABLK][64];
  const int tid = threadIdx.x, lane = tid & 63, wv = tid >> 6;
  for (int idx = tid; idx < 64 * 64; idx += 256) {
    int r = idx >> 6, d = idx & 63;
    w_s[(r << 6) + ((((d >> 2) ^ (r & 7)) << 2) | (d & 3))] = w[idx];
  }
  __syncthreads();
  const float4* w4 = reinterpret_cast<const float4*>(w_s);
  const float bo = bias[lane], gg = g[lane], bbb = bb[lane];
  const int swz = lane & 7;
  const int gw = blockIdx.x * 4 + wv;
  const int stride = gridDim.x * 4 * OABLK;
  for (int ag = gw * OABLK; ag < NA; ag += stride) {
#pragma unroll
    for (int e = 0; e < OABLK; ++e) a_s[wv][e][lane] = ao[(ag + e) * 64 + lane];
    __syncthreads();
    const float4* a4 = reinterpret_cast<const float4*>(&a_s[wv][0][0]);
    float acc[OABLK] = {0,0,0,0};
#pragma unroll 4
    for (int d4 = 0; d4 < 16; ++d4) {
      int sl = d4 ^ swz;
      float4 wr = w4[(lane << 4) + sl];
#pragma unroll
      for (int e = 0; e < OABLK; ++e) {
        float4 av = a4[e * 16 + d4];
        acc[e] += wr.x*av.x + wr.y*av.y + wr.z*av.z + wr.w*av.w;
      }
    }
#pragma unroll
    for (int e = 0; e < OABLK; ++e) {
      float val = acc[e] + bo + x[(ag + e) * 64 + lane];
      float s1 = val, s2 = val * val;
#pragma unroll
      for (int mm = 1; mm < 64; mm <<= 1) {
        s1 += __shfl_xor(s1, mm, 64);
        s2 += __shfl_xor(s2, mm, 64);
      }
      float mu = s1 * 0.015625f;
      float var = s2 * 0.015625f - mu * mu;
      y1[(ag + e) * 64 + lane] = (val - mu) * rsqrtf(var + 1e-5f) * gg + bbb;
    }
    __syncthreads();
  }
}

// ============ FFN (512 hidden) + residual + LN2 ============
// FABLK 8->4: LDS 36 KB -> 4 blocks/CU (round-10 counters: latency-bound at
// 16% occupancy; doubling resident waves targets VALUBusy 50->80%).
#define FW 4
#define FABLK 4
__global__ __launch_bounds__(256, 4) void k_ffn(
    const float* __restrict__ y1, const float* __restrict__ w1,
    const float* __restrict__ b1, const float* __restrict__ w2,
    const float* __restrict__ b2, const float* __restrict__ g,
    const float* __restrict__ bb, float* __restrict__ y2) {
  __shared__ __align__(16) float hbuf[FW][FABLK][512];   // 32 KB
  __shared__ __align__(16) float y1_s[FW][FABLK][64];    // 4 KB
  const int tid = threadIdx.x, lane = tid & 63, wv = tid >> 6;
  const float4* w1_4 = reinterpret_cast<const float4*>(w1);
  const float4* b1_4 = reinterpret_cast<const float4*>(b1);
  const float b2v = b2[lane], gg = g[lane], bbb = bb[lane];
  const int gw = blockIdx.x * FW + wv;
  const int stride = gridDim.x * FW * FABLK;   // grid=1024 -> 1 iter
  for (int ag = gw * FABLK; ag < NA; ag += stride) {
#pragma unroll
    for (int e = 0; e < FABLK; ++e) y1_s[wv][e][lane] = y1[(ag + e) * 64 + lane];
    __syncthreads();
    float4 hv0[FABLK], hv1[FABLK];
    const float4 bq0 = b1_4[lane], bq1 = b1_4[64 + lane];
#pragma unroll
    for (int e = 0; e < FABLK; ++e) { hv0[e] = bq0; hv1[e] = bq1; }
#pragma unroll 4
    for (int d = 0; d < 64; ++d) {
      float4 w0 = w1_4[d * 128 + lane];
      float4 w1v = w1_4[d * 128 + 64 + lane];
#pragma unroll
      for (int e = 0; e < FABLK; ++e) {
        float yv = y1_s[wv][e][d];
        hv0[e].x = fmaf(yv, w0.x, hv0[e].x);
        hv0[e].y = fmaf(yv, w0.y, hv0[e].y);
        hv0[e].z = fmaf(yv, w0.z, hv0[e].z);
        hv0[e].w = fmaf(yv, w0.w, hv0[e].w);
        hv1[e].x = fmaf(yv, w1v.x, hv1[e].x);
        hv1[e].y = fmaf(yv, w1v.y, hv1[e].y);
        hv1[e].z = fmaf(yv, w1v.z, hv1[e].z);
        hv1[e].w = fmaf(yv, w1v.w, hv1[e].w);
      }
    }
    float4* hb4w = reinterpret_cast<float4*>(&hbuf[wv][0][0]);
#pragma unroll
    for (int e = 0; e < FABLK; ++e) {
      float4 r0 = hv0[e], r1 = hv1[e];
      r0.x = fmaxf(r0.x, 0.f); r0.y = fmaxf(r0.y, 0.f);
      r0.z = fmaxf(r0.z, 0.f); r0.w = fmaxf(r0.w, 0.f);
      r1.x = fmaxf(r1.x, 0.f); r1.y = fmaxf(r1.y, 0.f);
      r1.z = fmaxf(r1.z, 0.f); r1.w = fmaxf(r1.w, 0.f);
      hb4w[e * 128 + lane] = r0;
      hb4w[e * 128 + 64 + lane] = r1;
    }
    __syncthreads();
    float acc[FABLK] = {0,0,0,0};
    const float4* hb4 = reinterpret_cast<const float4*>(&hbuf[wv][0][0]);
#pragma unroll 4
    for (int c4 = 0; c4 < 128; ++c4) {
      float w2v0 = w2[(c4 * 4 + 0) * 64 + lane];
      float w2v1 = w2[(c4 * 4 + 1) * 64 + lane];
      float w2v2 = w2[(c4 * 4 + 2) * 64 + lane];
      float w2v3 = w2[(c4 * 4 + 3) * 64 + lane];
#pragma unroll
      for (int e = 0; e < FABLK; ++e) {
        float4 hq = hb4[e * 128 + c4];
        acc[e] = fmaf(hq.x, w2v0, acc[e]);
        acc[e] = fmaf(hq.y, w2v1, acc[e]);
        acc[e] = fmaf(hq.z, w2v2, acc[e]);
        acc[e] = fmaf(hq.w, w2v3, acc[e]);
      }
    }
#pragma unroll
    for (int e = 0; e < FABLK; ++e) {
      float val = y1_s[wv][e][lane] + acc[e] + b2v;
      float s1 = val, s2 = val * val;
#pragma unroll
      for (int mm = 1; mm < 64; mm <<= 1) {
        s1 += __shfl_xor(s1, mm, 64);
        s2 += __shfl_xor(s2, mm, 64);
      }
      float mu = s1 * 0.015625f;
      float var = s2 * 0.015625f - mu * mu;
      y2[(ag + e) * 64 + lane] = (val - mu) * rsqrtf(var + 1e-5f) * gg + bbb;
    }
    __syncthreads();
  }
}

// ============ mean-pool over tokens ============
__global__ void k_pool(const float* __restrict__ y2, float* __restrict__ pooled) {
  const int b = blockIdx.x, lane = threadIdx.x;
  float s = 0.f;
  for (int t = 0; t < 64; ++t) s += y2[(b * 64 + t) * 64 + lane];
  pooled[b * 64 + lane] = s * 0.015625f;
}

// ============ readout head ============
__global__ __launch_bounds__(256) void k_head(
    const float* __restrict__ pooled, const float* __restrict__ d1w,
    const float* __restrict__ d1b, const float* __restrict__ d2w,
    const float* __restrict__ d2b, float* __restrict__ out) {
  const int b = blockIdx.x;
  __shared__ float p_s[64];
  __shared__ float red_s[4];
  const int tid = threadIdx.x;
  if (tid < 64) p_s[tid] = pooled[b * 64 + tid];
  __syncthreads();
  float acc = 0.f;
#pragma unroll
  for (int rep = 0; rep < 2; ++rep) {
    int c = rep * 256 + tid;
    float hvv = d1b[c];
    for (int d = 0; d < 64; ++d) hvv += p_s[d] * d1w[d * 512 + c];
    acc += fmaxf(hvv, 0.f) * d2w[c];
  }
#pragma unroll
  for (int mm = 1; mm < 64; mm <<= 1) acc += __shfl_xor(acc, mm, 64);
  if ((tid & 63) == 0) red_s[tid >> 6] = acc;
  __syncthreads();
  if (tid == 0) {
    float t = red_s[0] + red_s[1] + red_s[2] + red_s[3] + d2b[0];
    out[b] = 1.0f / (1.0f + expf(-t));
  }
}

extern "C" void kernel_launch(void* const* d_in, const int* in_sizes, int n_in,
                              void* d_out, int out_size, void* d_ws, size_t ws_size,
                              hipStream_t stream) {
  (void)in_sizes; (void)n_in; (void)out_size; (void)ws_size;
  const float* af   = (const float*)d_in[0];
  const float* bfeat= (const float*)d_in[1];
  const int*   pairs= (const int*)d_in[2];
  // d_in[3] = molecule_indicator (identity layout; unused)
  const float* kern = (const float*)d_in[4];
  const float* kbias= (const float*)d_in[5];
  const float* wih  = (const float*)d_in[6];
  const float* whh  = (const float*)d_in[7];
  const float* bih  = (const float*)d_in[8];
  const float* bhh  = (const float*)d_in[9];
  const float* ipw  = (const float*)d_in[10];
  const float* ipb  = (const float*)d_in[11];
  const float* opw  = (const float*)d_in[12];
  const float* opb  = (const float*)d_in[13];
  const float* fw1  = (const float*)d_in[14];
  const float* fb1  = (const float*)d_in[15];
  const float* fw2  = (const float*)d_in[16];
  const float* fb2  = (const float*)d_in[17];
  const float* l1g  = (const float*)d_in[18];
  const float* l1b  = (const float*)d_in[19];
  const float* l2g  = (const float*)d_in[20];
  const float* l2b  = (const float*)d_in[21];
  const float* d1w  = (const float*)d_in[22];
  const float* d1b  = (const float*)d_in[23];
  const float* d2w  = (const float*)d_in[24];
  const float* d2b  = (const float*)d_in[25];
  float* out = (float*)d_out;

  // workspace layout (floats)
  float* ws = (float*)d_ws;
  float* h      = ws;                    // ping buffer (final h after 4 steps)
  float* h2     = h + (size_t)NA * 64;   // pong buffer
  float* qkv    = h2 + (size_t)NA * 64;
  float* ao     = qkv + (size_t)NA * 192;
  float* y1     = ao + (size_t)NA * 64;
  float* y2     = y1 + (size_t)NA * 64;
  float* pooled = y2 + (size_t)NA * 64;
  int*   valid  = (int*)(pooled + 256 * 64);

  // MP-loop scratch aliased into the qkv region (dead until after the loop):
  unsigned short* KrA = (unsigned short*)qkv;  // 36864 ushort
  int*   count  = (int*)(qkv + 36864);         // NA
  int*   start  = count + NA;                  // NA+1
  int*   cursor = start + NA + 1;              // NA
  int*   elist  = cursor + NA;                 // NE
  int*   bsum   = elist + NE;                  // 256
  int*   sdst   = bsum + 256;                  // NE + 8 pad
  float* sbf    = (float*)(sdst + NE + 8);     // NE*8 + 64 pad
  unsigned short* Wh = (unsigned short*)(sbf + (size_t)NE * 8 + 64);   // 24576 ushort
  unsigned short* Wl = Wh + 24576;                                     // 24576 ushort

  k_init_h<<<NA * 64 / 256, 256, 0, stream>>>(af, h);
  k_prep_KrA<<<144, 256, 0, stream>>>(kern, kbias, KrA);
  k_prep_Wg<<<96, 256, 0, stream>>>(wih, whh, Wh, Wl);
  hipMemsetAsync(count, 0, (size_t)NA * sizeof(int), stream);
  k_count<<<NE / 256, 256, 0, stream>>>(pairs, count);
  k_scan1<<<64, 256, 0, stream>>>(count, bsum);
  k_scan2<<<64, 256, 0, stream>>>(count, bsum, start, cursor);
  k_place<<<NE / 256, 256, 0, stream>>>(pairs, cursor, elist);
  k_reorder<<<NE * 8 / 256, 256, 0, stream>>>(bfeat, pairs, elist, sdst, sbf);

  float* hin = h;
  float* hout = h2;
  for (int s = 0; s < 4; ++s) {
    k_msg<<<NA / 16, 256, 0, stream>>>(hin, start, sdst, sbf, KrA,
                                       Wh, Wl, bih, bhh, hout);
    float* tmp = hin; hin = hout; hout = tmp;
  }
  // 4 swaps -> final h is back in 'h'

  k_qkv<<<512, 256, 0, stream>>>(h, ipw, ipb, qkv, valid);
  k_attn<<<2048, 64, 0, stream>>>(qkv, valid, ao);
  k_out_ln1<<<512, 256, 0, stream>>>(h, ao, opw, opb, l1g, l1b, y1);
  k_ffn<<<1024, 256, 0, stream>>>(y1, fw1, fb1, fw2, fb2, l2g, l2b, y2);
  k_pool<<<256, 64, 0, stream>>>(y2, pooled);
  k_head<<<256, 256, 0, stream>>>(pooled, d1w, d1b, d2w, d2b, out);
}

// Round 12
// 189.710 us; speedup vs baseline: 2.3394x; 1.0921x over previous
//
#include <hip/hip_runtime.h>
#include <hip/hip_bf16.h>
#include <math.h>

#define NA 16384
#define NE 65536
#define AD 29

typedef __attribute__((ext_vector_type(8))) short bfrag8;
typedef __attribute__((ext_vector_type(4))) float f32x4;

__device__ __forceinline__ float sigmoidf_(float x) { return 1.0f / (1.0f + expf(-x)); }
__device__ __forceinline__ unsigned short bf16bits(float x) {
  __hip_bfloat16 hb = __float2bfloat16(x);
  return *reinterpret_cast<unsigned short*>(&hb);
}
__device__ __forceinline__ float bf16val(unsigned short u) {
  unsigned int b = ((unsigned int)u) << 16;
  return __uint_as_float(b);
}

// ============ init h: pad atom features 29 -> 64 ============
__global__ void k_init_h(const float* __restrict__ af, float* __restrict__ h) {
  int idx = blockIdx.x * 256 + threadIdx.x;
  if (idx >= NA * 64) return;
  int a = idx >> 6, d = idx & 63;
  h[idx] = (d < AD) ? af[a * AD + d] : 0.0f;
}

// ============ K -> A-fragment relayout (once per call), bf16 (phase B).
__global__ void k_prep_KrA(const float* __restrict__ kern, const float* __restrict__ kbias,
                           unsigned short* __restrict__ KrA) {
  int idx = blockIdx.x * 256 + threadIdx.x;    // 4*18*64*8 = 36864
  if (idx >= 36864) return;
  int r = idx & 7;
  int tmp = idx >> 3;
  int lane = tmp & 63;
  int tmp2 = tmp >> 6;            // w*18 + ks
  int ks = tmp2 % 18, w = tmp2 / 18;
  int i = w * 16 + (lane & 15);
  int kj = ks * 32 + ((lane >> 4) << 3) + r;
  int k9 = kj >> 6, j = kj & 63;
  float v = (k9 < 8) ? kern[k9 * 4096 + i * 64 + j] : kbias[i * 64 + j];
  KrA[idx] = bf16bits(v);
}

// ============ GRU weights -> A-fragments, split-bf16 hi/lo (once per call).
__global__ void k_prep_Wg(const float* __restrict__ wih, const float* __restrict__ whh,
                          unsigned short* __restrict__ Wh, unsigned short* __restrict__ Wl) {
  int idx = blockIdx.x * 256 + threadIdx.x;    // 24576
  if (idx >= 24576) return;
  int r = idx & 7;
  int lane = (idx >> 3) & 63;
  int t2 = idx >> 9;            // (w*6+q)*2 + ks
  int ks = t2 & 1;
  int t3 = t2 >> 1;             // w*6 + q
  int q = t3 % 6, w = t3 / 6;
  int s = q / 3, g = q % 3;
  int R = g * 64 + w * 16 + (lane & 15);
  int kk = ks * 32 + ((lane >> 4) << 3) + r;
  float v = (s == 0) ? wih[R * 64 + kk] : whh[R * 64 + kk];
  unsigned short hi = bf16bits(v);
  Wh[idx] = hi;
  Wl[idx] = bf16bits(v - bf16val(hi));
}

// ============ FFN weights -> A-fragments, split-bf16 hi/lo (once per call).
// W1: 32 tiles (hid rows) x 2 ksteps (K=64).  idx=((tile*2+ks)*64+lane)*8+r;
//     hid = tile*16+(lane&15); kk = ks*32+(lane>>4)*8+r; v = w1[kk*512+hid].
// W2: 4 tiles (out rows) x 16 ksteps (K=512). idx=((tile*16+ks)*64+lane)*8+r;
//     out = tile*16+(lane&15); kk = ks*32+(lane>>4)*8+r; v = w2[kk*64+out].
__global__ void k_prep_Wffn(const float* __restrict__ w1, const float* __restrict__ w2,
                            unsigned short* __restrict__ W1h, unsigned short* __restrict__ W1l,
                            unsigned short* __restrict__ W2h, unsigned short* __restrict__ W2l) {
  int idx = blockIdx.x * 256 + threadIdx.x;    // 2*32768
  if (idx >= 65536) return;
  int r = idx & 7;
  int lane = (idx >> 3) & 63;
  int rest = (idx >> 9) & 63;   // 64 frag-groups per matrix
  int kk, v_ok;
  float v;
  if (idx < 32768) {            // W1: rest = tile*2+ks, tile 0..31
    int tile = rest >> 1, ks = rest & 1;
    int hid = tile * 16 + (lane & 15);
    kk = ks * 32 + ((lane >> 4) << 3) + r;
    v = w1[kk * 512 + hid];
    unsigned short hi = bf16bits(v);
    W1h[idx] = hi;
    W1l[idx] = bf16bits(v - bf16val(hi));
  } else {                      // W2: rest = tile*16+ks, tile 0..3
    int i2 = idx - 32768;
    int tile = rest >> 4, ks = rest & 15;
    int out = tile * 16 + (lane & 15);
    kk = ks * 32 + ((lane >> 4) << 3) + r;
    v = w2[kk * 64 + out];
    unsigned short hi = bf16bits(v);
    W2h[i2] = hi;
    W2l[i2] = bf16bits(v - bf16val(hi));
  }
  (void)v_ok;
}

// ============ edge bucketing by src (once per call; counting sort) ============
__global__ void k_count(const int* __restrict__ pairs, int* __restrict__ count) {
  int e = blockIdx.x * 256 + threadIdx.x;
  if (e >= NE) return;
  atomicAdd(&count[pairs[2 * e]], 1);
}
__global__ void k_scan1(const int* __restrict__ count, int* __restrict__ bsum) {
  __shared__ int red[256];
  int b = blockIdx.x, t = threadIdx.x;
  red[t] = count[b * 256 + t];
  __syncthreads();
  for (int s = 128; s > 0; s >>= 1) { if (t < s) red[t] += red[t + s]; __syncthreads(); }
  if (t == 0) bsum[b] = red[0];
}
__global__ void k_scan2(const int* __restrict__ count, const int* __restrict__ bsum,
                        int* __restrict__ start, int* __restrict__ cursor) {
  __shared__ int sc[256];
  __shared__ int basev;
  int b = blockIdx.x, t = threadIdx.x;
  if (t == 0) { int s = 0; for (int i = 0; i < b; ++i) s += bsum[i]; basev = s; }
  int v = count[b * 256 + t];
  sc[t] = v;
  __syncthreads();
  for (int off = 1; off < 256; off <<= 1) {
    int add = (t >= off) ? sc[t - off] : 0;
    __syncthreads();
    sc[t] += add;
    __syncthreads();
  }
  int excl = sc[t] - v + basev;
  start[b * 256 + t] = excl;
  cursor[b * 256 + t] = excl;
  if (b * 256 + t == NA - 1) start[NA] = excl + v;   // sentinel = NE
}
__global__ void k_place(const int* __restrict__ pairs, int* __restrict__ cursor,
                        int* __restrict__ elist) {
  int e = blockIdx.x * 256 + threadIdx.x;
  if (e >= NE) return;
  int pos = atomicAdd(&cursor[pairs[2 * e]], 1);
  elist[pos] = e;
}
__global__ void k_reorder(const float* __restrict__ bf, const int* __restrict__ pairs,
                          const int* __restrict__ elist, int* __restrict__ sdst,
                          float* __restrict__ sbf) {
  int idx = blockIdx.x * 256 + threadIdx.x;    // NE*8 threads
  if (idx >= NE * 8) return;
  int pos = idx >> 3, k = idx & 7;
  int e = elist[pos];
  sbf[idx] = bf[e * 8 + k];
  if (k == 0) sdst[pos] = pairs[2 * e + 1];
}

// ============ fused message + GRU step, fully MFMA'd dense parts ============
#define MW 4
#define MAW 4
__global__ __launch_bounds__(256, 4) void k_msg(
    const float* __restrict__ h_in, const int* __restrict__ start,
    const int* __restrict__ sdst, const float* __restrict__ sbf,
    const unsigned short* __restrict__ KrA,
    const unsigned short* __restrict__ Wh, const unsigned short* __restrict__ Wl,
    const float* __restrict__ bih, const float* __restrict__ bhh,
    float* __restrict__ h_out) {
  __shared__ __align__(16) unsigned short Tb[16 * 584];   // 18,688 B
  __shared__ __align__(16) unsigned short Xh[16 * 136];   // 4,352 B
  __shared__ __align__(16) unsigned short Xl[16 * 136];   // 4,352 B
  __shared__ __align__(16) float Hf[16 * 68];             // 4,352 B
  __shared__ __align__(16) float AHa[16 * 68];            // 4,352 B
  __shared__ float bias_s[384];                           // 1,536 B
  const int tid = threadIdx.x, lane = tid & 63, wv = tid >> 6;
  const int ablk = blockIdx.x * 16;
  const int awave = ablk + wv * MAW;

  // ---- stage h (fp32 + bf16 hi/lo) and biases ----
#pragma unroll
  for (int aa = 0; aa < MAW; ++aa) {
    const int a = wv * MAW + aa;
    const float v = h_in[(ablk + a) * 64 + lane];
    Hf[a * 68 + lane] = v;
    const unsigned short hi = bf16bits(v);
    Xh[a * 136 + 64 + lane] = hi;
    Xl[a * 136 + 64 + lane] = bf16bits(v - bf16val(hi));
  }
  if (tid < 192) { bias_s[tid] = bih[tid]; bias_s[192 + tid] = bhh[tid]; }

  // ---- Phase A: per-atom gather (scalar bf coeffs, fp32 accum, bf16 flush) ----
  for (int a = 0; a < MAW; ++a) {
    const int s0 = __builtin_amdgcn_readfirstlane(start[awave + a]);
    const int s1 = __builtin_amdgcn_readfirstlane(start[awave + a + 1]);
    float t[9] = {0.f, 0.f, 0.f, 0.f, 0.f, 0.f, 0.f, 0.f, 0.f};
    for (int base = s0; base < s1; base += 8) {
      const int nb = s1 - base;
      float hv[8];
#pragma unroll
      for (int i = 0; i < 8; ++i) {
        int d = (i < nb) ? sdst[base + i] : 0;
        hv[i] = (i < nb) ? h_in[d * 64 + lane] : 0.f;
      }
#pragma unroll
      for (int i = 0; i < 8; ++i) {
#pragma unroll
        for (int k = 0; k < 8; ++k)
          t[k] = fmaf(sbf[(base + i) * 8 + k], hv[i], t[k]);   // hv=0 kills pad terms
        t[8] += hv[i];
      }
    }
    const int row = wv * MAW + a;
#pragma unroll
    for (int k = 0; k < 9; ++k) Tb[row * 584 + k * 64 + lane] = bf16bits(t[k]);
  }
  __syncthreads();

  // ---- Phase B: MFMA  agg[i][atom] = sum_kj K[i][kj] * T[atom][kj] ----
  f32x4 acc = {0.f, 0.f, 0.f, 0.f};
  const bfrag8* KrA8 = reinterpret_cast<const bfrag8*>(KrA);
  const int tb_base = (lane & 15) * 584 + ((lane >> 4) << 3);
#pragma unroll 3
  for (int ks = 0; ks < 18; ++ks) {
    bfrag8 af = KrA8[(wv * 18 + ks) * 64 + lane];
    bfrag8 bfr = *reinterpret_cast<const bfrag8*>(&Tb[tb_base + ks * 32]);
    acc = __builtin_amdgcn_mfma_f32_16x16x32_bf16(af, bfr, acc, 0, 0, 0);
  }
#pragma unroll
  for (int reg = 0; reg < 4; ++reg) {
    const int ii = wv * 16 + ((lane >> 4) << 2) + reg;
    const unsigned short hi = bf16bits(acc[reg]);
    Xh[(lane & 15) * 136 + ii] = hi;
    Xl[(lane & 15) * 136 + ii] = bf16bits(acc[reg] - bf16val(hi));
  }
  __syncthreads();

  // ---- Phase C: GRU matvec via MFMA (3-product split-bf16) ----
  const bfrag8* Wh8 = reinterpret_cast<const bfrag8*>(Wh);
  const bfrag8* Wl8 = reinterpret_cast<const bfrag8*>(Wl);
  f32x4 g0 = {0,0,0,0}, g1 = {0,0,0,0}, g2 = {0,0,0,0};
  f32x4 g3 = {0,0,0,0}, g4 = {0,0,0,0}, g5 = {0,0,0,0};
  f32x4* gptr[6] = {&g0, &g1, &g2, &g3, &g4, &g5};
#pragma unroll
  for (int q = 0; q < 6; ++q) {
    const int s = q / 3;
    f32x4 g = *gptr[q];
#pragma unroll
    for (int ks = 0; ks < 2; ++ks) {
      const int fidx = ((wv * 6 + q) * 2 + ks) * 64 + lane;
      bfrag8 Ah = Wh8[fidx];
      bfrag8 Al = Wl8[fidx];
      const int xoff = (lane & 15) * 136 + (s * 2 + ks) * 32 + ((lane >> 4) << 3);
      bfrag8 Bh = *reinterpret_cast<const bfrag8*>(&Xh[xoff]);
      bfrag8 Bl = *reinterpret_cast<const bfrag8*>(&Xl[xoff]);
      g = __builtin_amdgcn_mfma_f32_16x16x32_bf16(Ah, Bh, g, 0, 0, 0);
      g = __builtin_amdgcn_mfma_f32_16x16x32_bf16(Ah, Bl, g, 0, 0, 0);
      g = __builtin_amdgcn_mfma_f32_16x16x32_bf16(Al, Bh, g, 0, 0, 0);
    }
    *gptr[q] = g;
  }
#pragma unroll
  for (int reg = 0; reg < 4; ++reg) {
    const int i = wv * 16 + ((lane >> 4) << 2) + reg;
    const int atom = lane & 15;
    const float r = sigmoidf_(g0[reg] + bias_s[i] + g3[reg] + bias_s[192 + i]);
    const float z = sigmoidf_(g1[reg] + bias_s[64 + i] + g4[reg] + bias_s[256 + i]);
    const float nn = tanhf(g2[reg] + bias_s[128 + i] + r * (g5[reg] + bias_s[320 + i]));
    const float hold = Hf[atom * 68 + i];
    AHa[atom * 68 + i] = (1.0f - z) * nn + z * hold;
  }
  __syncthreads();
#pragma unroll
  for (int aa = 0; aa < MAW; ++aa) {
    const int a = wv * MAW + aa;
    h_out[(ablk + a) * 64 + lane] = AHa[a * 68 + lane];
  }
}

// ============ qkv projection + valid mask ============
#define QABLK 4
__global__ __launch_bounds__(256, 2) void k_qkv(
    const float* __restrict__ h, const float* __restrict__ w,
    const float* __restrict__ b, float* __restrict__ qkv,
    int* __restrict__ valid) {
  __shared__ __align__(16) float w_s[192 * 64];
  __shared__ __align__(16) float x_s[4][QABLK][64];
  const int tid = threadIdx.x, lane = tid & 63, wv = tid >> 6;
  for (int idx = tid; idx < 192 * 64; idx += 256) {
    int r = idx >> 6, d = idx & 63;
    w_s[(r << 6) + ((((d >> 2) ^ (r & 7)) << 2) | (d & 3))] = w[idx];
  }
  __syncthreads();
  const float4* w4 = reinterpret_cast<const float4*>(w_s);
  const float bq = b[lane], bk = b[64 + lane], bv_ = b[128 + lane];
  const int swz = lane & 7;
  const int gw = blockIdx.x * 4 + wv;
  const int stride = gridDim.x * 4 * QABLK;
  for (int ag = gw * QABLK; ag < NA; ag += stride) {
#pragma unroll
    for (int e = 0; e < QABLK; ++e) x_s[wv][e][lane] = h[(ag + e) * 64 + lane];
    __syncthreads();
    const float4* x4 = reinterpret_cast<const float4*>(&x_s[wv][0][0]);
    float aq[QABLK] = {0,0,0,0}, ak[QABLK] = {0,0,0,0}, av_[QABLK] = {0,0,0,0};
    int nz[QABLK] = {0,0,0,0};
#pragma unroll 4
    for (int d4 = 0; d4 < 16; ++d4) {
      int sl = d4 ^ swz;
      float4 wq = w4[(lane << 4) + sl];
      float4 wk = w4[((lane + 64) << 4) + sl];
      float4 wvv = w4[((lane + 128) << 4) + sl];
#pragma unroll
      for (int e = 0; e < QABLK; ++e) {
        float4 xv = x4[e * 16 + d4];
        aq[e] += wq.x*xv.x + wq.y*xv.y + wq.z*xv.z + wq.w*xv.w;
        ak[e] += wk.x*xv.x + wk.y*xv.y + wk.z*xv.z + wk.w*xv.w;
        av_[e] += wvv.x*xv.x + wvv.y*xv.y + wvv.z*xv.z + wvv.w*xv.w;
        nz[e] |= (int)(xv.x != 0.f) | (int)(xv.y != 0.f) | (int)(xv.z != 0.f) | (int)(xv.w != 0.f);
      }
    }
#pragma unroll
    for (int e = 0; e < QABLK; ++e) {
      qkv[(ag + e) * 192 + lane] = aq[e] + bq;
      qkv[(ag + e) * 192 + 64 + lane] = ak[e] + bk;
      qkv[(ag + e) * 192 + 128 + lane] = av_[e] + bv_;
      if (lane == 0) valid[ag + e] = nz[e];
    }
    __syncthreads();
  }
}

// ============ attention: one wave per (molecule, head), online softmax ============
__global__ void k_attn(const float* __restrict__ qkv, const int* __restrict__ valid,
                       float* __restrict__ ao) {
  const int b = blockIdx.x >> 3, hh = blockIdx.x & 7;
  __shared__ float k_s[64][8];
  __shared__ float v_s[64][8];
  __shared__ int vd_s[64];
  const int lane = threadIdx.x;
  const int rowbase = (b * 64 + lane) * 192;
#pragma unroll
  for (int j = 0; j < 8; ++j) {
    k_s[lane][j] = qkv[rowbase + 64 + hh * 8 + j];
    v_s[lane][j] = qkv[rowbase + 128 + hh * 8 + j];
  }
  vd_s[lane] = valid[b * 64 + lane];
  __syncthreads();
  float q[8];
#pragma unroll
  for (int j = 0; j < 8; ++j) q[j] = qkv[rowbase + hh * 8 + j];
  float m = -3.0e38f, l = 0.f, o[8] = {0,0,0,0,0,0,0,0};
  for (int t = 0; t < 64; ++t) {
    float s = 0.f;
#pragma unroll
    for (int j = 0; j < 8; ++j) s += q[j] * k_s[t][j];
    s *= 0.35355339059327373f;
    s = vd_s[t] ? s : -1.0e9f;
    float mn = fmaxf(m, s);
    float c = expf(m - mn);
    float p = expf(s - mn);
    l = l * c + p;
#pragma unroll
    for (int j = 0; j < 8; ++j) o[j] = o[j] * c + p * v_s[t][j];
    m = mn;
  }
  const float inv = 1.0f / l;
  const int obase = (b * 64 + lane) * 64 + hh * 8;
#pragma unroll
  for (int j = 0; j < 8; ++j) ao[obase + j] = o[j] * inv;
}

// ============ out_proj + residual + LN1 ============
#define OABLK 4
__global__ __launch_bounds__(256, 1) void k_out_ln1(
    const float* __restrict__ x, const float* __restrict__ ao,
    const float* __restrict__ w, const float* __restrict__ bias,
    const float* __restrict__ g, const float* __restrict__ bb,
    float* __restrict__ y1) {
  __shared__ __align__(16) float w_s[64 * 64];
  __shared__ __align__(16) float a_s[4][OABLK][64];
  const int tid = threadIdx.x, lane = tid & 63, wv = tid >> 6;
  for (int idx = tid; idx < 64 * 64; idx += 256) {
    int r = idx >> 6, d = idx & 63;
    w_s[(r << 6) + ((((d >> 2) ^ (r & 7)) << 2) | (d & 3))] = w[idx];
  }
  __syncthreads();
  const float4* w4 = reinterpret_cast<const float4*>(w_s);
  const float bo = bias[lane], gg = g[lane], bbb = bb[lane];
  const int swz = lane & 7;
  const int gw = blockIdx.x * 4 + wv;
  const int stride = gridDim.x * 4 * OABLK;
  for (int ag = gw * OABLK; ag < NA; ag += stride) {
#pragma unroll
    for (int e = 0; e < OABLK; ++e) a_s[wv][e][lane] = ao[(ag + e) * 64 + lane];
    __syncthreads();
    const float4* a4 = reinterpret_cast<const float4*>(&a_s[wv][0][0]);
    float acc[OABLK] = {0,0,0,0};
#pragma unroll 4
    for (int d4 = 0; d4 < 16; ++d4) {
      int sl = d4 ^ swz;
      float4 wr = w4[(lane << 4) + sl];
#pragma unroll
      for (int e = 0; e < OABLK; ++e) {
        float4 av = a4[e * 16 + d4];
        acc[e] += wr.x*av.x + wr.y*av.y + wr.z*av.z + wr.w*av.w;
      }
    }
#pragma unroll
    for (int e = 0; e < OABLK; ++e) {
      float val = acc[e] + bo + x[(ag + e) * 64 + lane];
      float s1 = val, s2 = val * val;
#pragma unroll
      for (int mm = 1; mm < 64; mm <<= 1) {
        s1 += __shfl_xor(s1, mm, 64);
        s2 += __shfl_xor(s2, mm, 64);
      }
      float mu = s1 * 0.015625f;
      float var = s2 * 0.015625f - mu * mu;
      y1[(ag + e) * 64 + lane] = (val - mu) * rsqrtf(var + 1e-5f) * gg + bbb;
    }
    __syncthreads();
  }
}

// ============ FFN via MFMA (split-bf16 3-product) + residual + LN2 ============
// Block = 16 atoms. GEMM1: D[hid][atom], 32 tiles (8/wave), K=64 (2 ksteps);
// bias+ReLU fused at fragment level, re-split to bf16 hi/lo in LDS.
// GEMM2: D[out][atom], 4 tiles (1/wave), K=512 (16 ksteps). Residual+LN after.
// Fragment layout identical to k_msg phase B (on-device validated).
__global__ __launch_bounds__(256, 3) void k_ffn(
    const float* __restrict__ y1,
    const unsigned short* __restrict__ W1h, const unsigned short* __restrict__ W1l,
    const unsigned short* __restrict__ W2h, const unsigned short* __restrict__ W2l,
    const float* __restrict__ b1, const float* __restrict__ b2,
    const float* __restrict__ g, const float* __restrict__ bb,
    float* __restrict__ y2) {
  __shared__ __align__(16) unsigned short Xh[16 * 72];    // 2,304 B (y1 bf16 hi)
  __shared__ __align__(16) unsigned short Xl[16 * 72];    // 2,304 B
  __shared__ __align__(16) unsigned short Hh[16 * 520];   // 16,640 B (hidden hi)
  __shared__ __align__(16) unsigned short Hl[16 * 520];   // 16,640 B
  __shared__ __align__(16) float Y1f[16 * 68];            // 4,352 B
  __shared__ __align__(16) float Of[16 * 68];             // 4,352 B
  const int tid = threadIdx.x, lane = tid & 63, wv = tid >> 6;
  const int ablk = blockIdx.x * 16;

  // stage y1 (fp32 for residual + bf16 hi/lo for GEMM1 B-operand)
#pragma unroll
  for (int aa = 0; aa < 4; ++aa) {
    const int a = wv * 4 + aa;
    const float v = y1[(ablk + a) * 64 + lane];
    Y1f[a * 68 + lane] = v;
    const unsigned short hi = bf16bits(v);
    Xh[a * 72 + lane] = hi;
    Xl[a * 72 + lane] = bf16bits(v - bf16val(hi));
  }
  __syncthreads();

  // ---- GEMM1: 8 tiles/wave, each K=64 ----
  const bfrag8* W1h8 = reinterpret_cast<const bfrag8*>(W1h);
  const bfrag8* W1l8 = reinterpret_cast<const bfrag8*>(W1l);
  const int xoff_base = (lane & 15) * 72 + ((lane >> 4) << 3);
#pragma unroll 2
  for (int t = 0; t < 8; ++t) {
    f32x4 acc = {0.f, 0.f, 0.f, 0.f};
    const int tile = wv * 8 + t;
#pragma unroll
    for (int ks = 0; ks < 2; ++ks) {
      const int fidx = (tile * 2 + ks) * 64 + lane;
      bfrag8 Ah = W1h8[fidx];
      bfrag8 Al = W1l8[fidx];
      bfrag8 Bh = *reinterpret_cast<const bfrag8*>(&Xh[xoff_base + ks * 32]);
      bfrag8 Bl = *reinterpret_cast<const bfrag8*>(&Xl[xoff_base + ks * 32]);
      acc = __builtin_amdgcn_mfma_f32_16x16x32_bf16(Ah, Bh, acc, 0, 0, 0);
      acc = __builtin_amdgcn_mfma_f32_16x16x32_bf16(Ah, Bl, acc, 0, 0, 0);
      acc = __builtin_amdgcn_mfma_f32_16x16x32_bf16(Al, Bh, acc, 0, 0, 0);
    }
#pragma unroll
    for (int reg = 0; reg < 4; ++reg) {
      const int hid = tile * 16 + ((lane >> 4) << 2) + reg;
      float val = fmaxf(acc[reg] + b1[hid], 0.f);
      const unsigned short hi = bf16bits(val);
      Hh[(lane & 15) * 520 + hid] = hi;
      Hl[(lane & 15) * 520 + hid] = bf16bits(val - bf16val(hi));
    }
  }
  __syncthreads();

  // ---- GEMM2: 1 tile/wave, K=512 ----
  const bfrag8* W2h8 = reinterpret_cast<const bfrag8*>(W2h);
  const bfrag8* W2l8 = reinterpret_cast<const bfrag8*>(W2l);
  f32x4 acc2 = {0.f, 0.f, 0.f, 0.f};
  const int hoff_base = (lane & 15) * 520 + ((lane >> 4) << 3);
#pragma unroll 4
  for (int ks = 0; ks < 16; ++ks) {
    const int fidx = (wv * 16 + ks) * 64 + lane;
    bfrag8 Ah = W2h8[fidx];
    bfrag8 Al = W2l8[fidx];
    bfrag8 Bh = *reinterpret_cast<const bfrag8*>(&Hh[hoff_base + ks * 32]);
    bfrag8 Bl = *reinterpret_cast<const bfrag8*>(&Hl[hoff_base + ks * 32]);
    acc2 = __builtin_amdgcn_mfma_f32_16x16x32_bf16(Ah, Bh, acc2, 0, 0, 0);
    acc2 = __builtin_amdgcn_mfma_f32_16x16x32_bf16(Ah, Bl, acc2, 0, 0, 0);
    acc2 = __builtin_amdgcn_mfma_f32_16x16x32_bf16(Al, Bh, acc2, 0, 0, 0);
  }
#pragma unroll
  for (int reg = 0; reg < 4; ++reg) {
    const int outr = wv * 16 + ((lane >> 4) << 2) + reg;
    Of[(lane & 15) * 68 + outr] = acc2[reg] + b2[outr];
  }
  __syncthreads();

  // ---- residual + LN2 (per atom) ----
  const float gg = g[lane], bbb = bb[lane];
#pragma unroll
  for (int aa = 0; aa < 4; ++aa) {
    const int a = wv * 4 + aa;
    float val = Y1f[a * 68 + lane] + Of[a * 68 + lane];
    float s1 = val, s2 = val * val;
#pragma unroll
    for (int mm = 1; mm < 64; mm <<= 1) {
      s1 += __shfl_xor(s1, mm, 64);
      s2 += __shfl_xor(s2, mm, 64);
    }
    float mu = s1 * 0.015625f;
    float var = s2 * 0.015625f - mu * mu;
    y2[(ablk + a) * 64 + lane] = (val - mu) * rsqrtf(var + 1e-5f) * gg + bbb;
  }
}

// ============ mean-pool over tokens ============
__global__ void k_pool(const float* __restrict__ y2, float* __restrict__ pooled) {
  const int b = blockIdx.x, lane = threadIdx.x;
  float s = 0.f;
  for (int t = 0; t < 64; ++t) s += y2[(b * 64 + t) * 64 + lane];
  pooled[b * 64 + lane] = s * 0.015625f;
}

// ============ readout head ============
__global__ __launch_bounds__(256) void k_head(
    const float* __restrict__ pooled, const float* __restrict__ d1w,
    const float* __restrict__ d1b, const float* __restrict__ d2w,
    const float* __restrict__ d2b, float* __restrict__ out) {
  const int b = blockIdx.x;
  __shared__ float p_s[64];
  __shared__ float red_s[4];
  const int tid = threadIdx.x;
  if (tid < 64) p_s[tid] = pooled[b * 64 + tid];
  __syncthreads();
  float acc = 0.f;
#pragma unroll
  for (int rep = 0; rep < 2; ++rep) {
    int c = rep * 256 + tid;
    float hvv = d1b[c];
    for (int d = 0; d < 64; ++d) hvv += p_s[d] * d1w[d * 512 + c];
    acc += fmaxf(hvv, 0.f) * d2w[c];
  }
#pragma unroll
  for (int mm = 1; mm < 64; mm <<= 1) acc += __shfl_xor(acc, mm, 64);
  if ((tid & 63) == 0) red_s[tid >> 6] = acc;
  __syncthreads();
  if (tid == 0) {
    float t = red_s[0] + red_s[1] + red_s[2] + red_s[3] + d2b[0];
    out[b] = 1.0f / (1.0f + expf(-t));
  }
}

extern "C" void kernel_launch(void* const* d_in, const int* in_sizes, int n_in,
                              void* d_out, int out_size, void* d_ws, size_t ws_size,
                              hipStream_t stream) {
  (void)in_sizes; (void)n_in; (void)out_size; (void)ws_size;
  const float* af   = (const float*)d_in[0];
  const float* bfeat= (const float*)d_in[1];
  const int*   pairs= (const int*)d_in[2];
  // d_in[3] = molecule_indicator (identity layout; unused)
  const float* kern = (const float*)d_in[4];
  const float* kbias= (const float*)d_in[5];
  const float* wih  = (const float*)d_in[6];
  const float* whh  = (const float*)d_in[7];
  const float* bih  = (const float*)d_in[8];
  const float* bhh  = (const float*)d_in[9];
  const float* ipw  = (const float*)d_in[10];
  const float* ipb  = (const float*)d_in[11];
  const float* opw  = (const float*)d_in[12];
  const float* opb  = (const float*)d_in[13];
  const float* fw1  = (const float*)d_in[14];
  const float* fb1  = (const float*)d_in[15];
  const float* fw2  = (const float*)d_in[16];
  const float* fb2  = (const float*)d_in[17];
  const float* l1g  = (const float*)d_in[18];
  const float* l1b  = (const float*)d_in[19];
  const float* l2g  = (const float*)d_in[20];
  const float* l2b  = (const float*)d_in[21];
  const float* d1w  = (const float*)d_in[22];
  const float* d1b  = (const float*)d_in[23];
  const float* d2w  = (const float*)d_in[24];
  const float* d2b  = (const float*)d_in[25];
  float* out = (float*)d_out;

  // workspace layout (floats)
  float* ws = (float*)d_ws;
  float* h      = ws;                    // ping buffer (final h after 4 steps)
  float* h2     = h + (size_t)NA * 64;   // pong buffer
  float* qkv    = h2 + (size_t)NA * 64;
  float* ao     = qkv + (size_t)NA * 192;
  float* y1     = ao + (size_t)NA * 64;
  float* y2     = y1 + (size_t)NA * 64;
  float* pooled = y2 + (size_t)NA * 64;
  int*   valid  = (int*)(pooled + 256 * 64);

  // FFN weight fragments: AFTER base layout (ws >= base+37MB proven: round-3
  // fp32-G path ran with absmax 0). 4 x 32768 ushort = 256 KB.
  unsigned short* W1h = (unsigned short*)(valid + NA);
  unsigned short* W1l = W1h + 32768;
  unsigned short* W2h = W1l + 32768;
  unsigned short* W2l = W2h + 32768;

  // MP-loop scratch aliased into the qkv region (dead until after the loop):
  unsigned short* KrA = (unsigned short*)qkv;  // 36864 ushort
  int*   count  = (int*)(qkv + 36864);         // NA
  int*   start  = count + NA;                  // NA+1
  int*   cursor = start + NA + 1;              // NA
  int*   elist  = cursor + NA;                 // NE
  int*   bsum   = elist + NE;                  // 256
  int*   sdst   = bsum + 256;                  // NE + 8 pad
  float* sbf    = (float*)(sdst + NE + 8);     // NE*8 + 64 pad
  unsigned short* Wh = (unsigned short*)(sbf + (size_t)NE * 8 + 64);   // 24576 ushort
  unsigned short* Wl = Wh + 24576;                                     // 24576 ushort

  k_init_h<<<NA * 64 / 256, 256, 0, stream>>>(af, h);
  k_prep_KrA<<<144, 256, 0, stream>>>(kern, kbias, KrA);
  k_prep_Wg<<<96, 256, 0, stream>>>(wih, whh, Wh, Wl);
  k_prep_Wffn<<<256, 256, 0, stream>>>(fw1, fw2, W1h, W1l, W2h, W2l);
  hipMemsetAsync(count, 0, (size_t)NA * sizeof(int), stream);
  k_count<<<NE / 256, 256, 0, stream>>>(pairs, count);
  k_scan1<<<64, 256, 0, stream>>>(count, bsum);
  k_scan2<<<64, 256, 0, stream>>>(count, bsum, start, cursor);
  k_place<<<NE / 256, 256, 0, stream>>>(pairs, cursor, elist);
  k_reorder<<<NE * 8 / 256, 256, 0, stream>>>(bfeat, pairs, elist, sdst, sbf);

  float* hin = h;
  float* hout = h2;
  for (int s = 0; s < 4; ++s) {
    k_msg<<<NA / 16, 256, 0, stream>>>(hin, start, sdst, sbf, KrA,
                                       Wh, Wl, bih, bhh, hout);
    float* tmp = hin; hin = hout; hout = tmp;
  }
  // 4 swaps -> final h is back in 'h'

  k_qkv<<<512, 256, 0, stream>>>(h, ipw, ipb, qkv, valid);
  k_attn<<<2048, 64, 0, stream>>>(qkv, valid, ao);
  k_out_ln1<<<512, 256, 0, stream>>>(h, ao, opw, opb, l1g, l1b, y1);
  k_ffn<<<NA / 16, 256, 0, stream>>>(y1, W1h, W1l, W2h, W2l, fb1, fb2, l2g, l2b, y2);
  k_pool<<<256, 64, 0, stream>>>(y2, pooled);
  k_head<<<256, 256, 0, stream>>>(pooled, d1w, d1b, d2w, d2b, out);
}

// Round 13
// 187.659 us; speedup vs baseline: 2.3649x; 1.0109x over previous
//
#include <hip/hip_runtime.h>
#include <hip/hip_bf16.h>
#include <math.h>

#define NA 16384
#define NE 65536
#define AD 29

typedef __attribute__((ext_vector_type(8))) short bfrag8;
typedef __attribute__((ext_vector_type(4))) float f32x4;

__device__ __forceinline__ float sigmoidf_(float x) { return 1.0f / (1.0f + expf(-x)); }
__device__ __forceinline__ unsigned short bf16bits(float x) {
  __hip_bfloat16 hb = __float2bfloat16(x);
  return *reinterpret_cast<unsigned short*>(&hb);
}
__device__ __forceinline__ float bf16val(unsigned short u) {
  unsigned int b = ((unsigned int)u) << 16;
  return __uint_as_float(b);
}

// ============ init h: pad atom features 29 -> 64; also zero count[] ============
// (count zeroing fused here: the rocclr fillBuffer kernel for the old
//  hipMemsetAsync ran ~41 us/replay with a tiny grid — round-12 profile.)
__global__ void k_init_h(const float* __restrict__ af, float* __restrict__ h,
                         int* __restrict__ count) {
  int idx = blockIdx.x * 256 + threadIdx.x;
  if (idx >= NA * 64) return;
  if (idx < NA) count[idx] = 0;
  int a = idx >> 6, d = idx & 63;
  h[idx] = (d < AD) ? af[a * AD + d] : 0.0f;
}

// ============ K -> A-fragment relayout (once per call), bf16 (phase B).
__global__ void k_prep_KrA(const float* __restrict__ kern, const float* __restrict__ kbias,
                           unsigned short* __restrict__ KrA) {
  int idx = blockIdx.x * 256 + threadIdx.x;    // 4*18*64*8 = 36864
  if (idx >= 36864) return;
  int r = idx & 7;
  int tmp = idx >> 3;
  int lane = tmp & 63;
  int tmp2 = tmp >> 6;            // w*18 + ks
  int ks = tmp2 % 18, w = tmp2 / 18;
  int i = w * 16 + (lane & 15);
  int kj = ks * 32 + ((lane >> 4) << 3) + r;
  int k9 = kj >> 6, j = kj & 63;
  float v = (k9 < 8) ? kern[k9 * 4096 + i * 64 + j] : kbias[i * 64 + j];
  KrA[idx] = bf16bits(v);
}

// ============ GRU weights -> A-fragments, split-bf16 hi/lo (once per call).
__global__ void k_prep_Wg(const float* __restrict__ wih, const float* __restrict__ whh,
                          unsigned short* __restrict__ Wh, unsigned short* __restrict__ Wl) {
  int idx = blockIdx.x * 256 + threadIdx.x;    // 24576
  if (idx >= 24576) return;
  int r = idx & 7;
  int lane = (idx >> 3) & 63;
  int t2 = idx >> 9;            // (w*6+q)*2 + ks
  int ks = t2 & 1;
  int t3 = t2 >> 1;             // w*6 + q
  int q = t3 % 6, w = t3 / 6;
  int s = q / 3, g = q % 3;
  int R = g * 64 + w * 16 + (lane & 15);
  int kk = ks * 32 + ((lane >> 4) << 3) + r;
  float v = (s == 0) ? wih[R * 64 + kk] : whh[R * 64 + kk];
  unsigned short hi = bf16bits(v);
  Wh[idx] = hi;
  Wl[idx] = bf16bits(v - bf16val(hi));
}

// ============ FFN weights -> A-fragments, split-bf16 hi/lo (once per call).
__global__ void k_prep_Wffn(const float* __restrict__ w1, const float* __restrict__ w2,
                            unsigned short* __restrict__ W1h, unsigned short* __restrict__ W1l,
                            unsigned short* __restrict__ W2h, unsigned short* __restrict__ W2l) {
  int idx = blockIdx.x * 256 + threadIdx.x;    // 2*32768
  if (idx >= 65536) return;
  int r = idx & 7;
  int lane = (idx >> 3) & 63;
  int rest = (idx >> 9) & 63;   // 64 frag-groups per matrix
  if (idx < 32768) {            // W1: rest = tile*2+ks, tile 0..31
    int tile = rest >> 1, ks = rest & 1;
    int hid = tile * 16 + (lane & 15);
    int kk = ks * 32 + ((lane >> 4) << 3) + r;
    float v = w1[kk * 512 + hid];
    unsigned short hi = bf16bits(v);
    W1h[idx] = hi;
    W1l[idx] = bf16bits(v - bf16val(hi));
  } else {                      // W2: rest = tile*16+ks, tile 0..3
    int i2 = idx - 32768;
    int tile = rest >> 4, ks = rest & 15;
    int out = tile * 16 + (lane & 15);
    int kk = ks * 32 + ((lane >> 4) << 3) + r;
    float v = w2[kk * 64 + out];
    unsigned short hi = bf16bits(v);
    W2h[i2] = hi;
    W2l[i2] = bf16bits(v - bf16val(hi));
  }
}

// ============ edge bucketing by src (once per call; counting sort) ============
__global__ void k_count(const int* __restrict__ pairs, int* __restrict__ count) {
  int e = blockIdx.x * 256 + threadIdx.x;
  if (e >= NE) return;
  atomicAdd(&count[pairs[2 * e]], 1);
}
__global__ void k_scan1(const int* __restrict__ count, int* __restrict__ bsum) {
  __shared__ int red[256];
  int b = blockIdx.x, t = threadIdx.x;
  red[t] = count[b * 256 + t];
  __syncthreads();
  for (int s = 128; s > 0; s >>= 1) { if (t < s) red[t] += red[t + s]; __syncthreads(); }
  if (t == 0) bsum[b] = red[0];
}
__global__ void k_scan2(const int* __restrict__ count, const int* __restrict__ bsum,
                        int* __restrict__ start, int* __restrict__ cursor) {
  __shared__ int sc[256];
  __shared__ int basev;
  int b = blockIdx.x, t = threadIdx.x;
  if (t == 0) { int s = 0; for (int i = 0; i < b; ++i) s += bsum[i]; basev = s; }
  int v = count[b * 256 + t];
  sc[t] = v;
  __syncthreads();
  for (int off = 1; off < 256; off <<= 1) {
    int add = (t >= off) ? sc[t - off] : 0;
    __syncthreads();
    sc[t] += add;
    __syncthreads();
  }
  int excl = sc[t] - v + basev;
  start[b * 256 + t] = excl;
  cursor[b * 256 + t] = excl;
  if (b * 256 + t == NA - 1) start[NA] = excl + v;   // sentinel = NE
}
__global__ void k_place(const int* __restrict__ pairs, int* __restrict__ cursor,
                        int* __restrict__ elist) {
  int e = blockIdx.x * 256 + threadIdx.x;
  if (e >= NE) return;
  int pos = atomicAdd(&cursor[pairs[2 * e]], 1);
  elist[pos] = e;
}
__global__ void k_reorder(const float* __restrict__ bf, const int* __restrict__ pairs,
                          const int* __restrict__ elist, int* __restrict__ sdst,
                          float* __restrict__ sbf) {
  int idx = blockIdx.x * 256 + threadIdx.x;    // NE*8 threads
  if (idx >= NE * 8) return;
  int pos = idx >> 3, k = idx & 7;
  int e = elist[pos];
  sbf[idx] = bf[e * 8 + k];
  if (k == 0) sdst[pos] = pairs[2 * e + 1];
}

// ============ fused message + GRU step, fully MFMA'd dense parts ============
#define MW 4
#define MAW 4
__global__ __launch_bounds__(256, 4) void k_msg(
    const float* __restrict__ h_in, const int* __restrict__ start,
    const int* __restrict__ sdst, const float* __restrict__ sbf,
    const unsigned short* __restrict__ KrA,
    const unsigned short* __restrict__ Wh, const unsigned short* __restrict__ Wl,
    const float* __restrict__ bih, const float* __restrict__ bhh,
    float* __restrict__ h_out) {
  __shared__ __align__(16) unsigned short Tb[16 * 584];   // 18,688 B
  __shared__ __align__(16) unsigned short Xh[16 * 136];   // 4,352 B
  __shared__ __align__(16) unsigned short Xl[16 * 136];   // 4,352 B
  __shared__ __align__(16) float Hf[16 * 68];             // 4,352 B
  __shared__ __align__(16) float AHa[16 * 68];            // 4,352 B
  __shared__ float bias_s[384];                           // 1,536 B
  const int tid = threadIdx.x, lane = tid & 63, wv = tid >> 6;
  const int ablk = blockIdx.x * 16;
  const int awave = ablk + wv * MAW;

  // ---- stage h (fp32 + bf16 hi/lo) and biases ----
#pragma unroll
  for (int aa = 0; aa < MAW; ++aa) {
    const int a = wv * MAW + aa;
    const float v = h_in[(ablk + a) * 64 + lane];
    Hf[a * 68 + lane] = v;
    const unsigned short hi = bf16bits(v);
    Xh[a * 136 + 64 + lane] = hi;
    Xl[a * 136 + 64 + lane] = bf16bits(v - bf16val(hi));
  }
  if (tid < 192) { bias_s[tid] = bih[tid]; bias_s[192 + tid] = bhh[tid]; }

  // ---- Phase A: per-atom gather (scalar bf coeffs, fp32 accum, bf16 flush) ----
  for (int a = 0; a < MAW; ++a) {
    const int s0 = __builtin_amdgcn_readfirstlane(start[awave + a]);
    const int s1 = __builtin_amdgcn_readfirstlane(start[awave + a + 1]);
    float t[9] = {0.f, 0.f, 0.f, 0.f, 0.f, 0.f, 0.f, 0.f, 0.f};
    for (int base = s0; base < s1; base += 8) {
      const int nb = s1 - base;
      float hv[8];
#pragma unroll
      for (int i = 0; i < 8; ++i) {
        int d = (i < nb) ? sdst[base + i] : 0;
        hv[i] = (i < nb) ? h_in[d * 64 + lane] : 0.f;
      }
#pragma unroll
      for (int i = 0; i < 8; ++i) {
#pragma unroll
        for (int k = 0; k < 8; ++k)
          t[k] = fmaf(sbf[(base + i) * 8 + k], hv[i], t[k]);   // hv=0 kills pad terms
        t[8] += hv[i];
      }
    }
    const int row = wv * MAW + a;
#pragma unroll
    for (int k = 0; k < 9; ++k) Tb[row * 584 + k * 64 + lane] = bf16bits(t[k]);
  }
  __syncthreads();

  // ---- Phase B: MFMA  agg[i][atom] = sum_kj K[i][kj] * T[atom][kj] ----
  f32x4 acc = {0.f, 0.f, 0.f, 0.f};
  const bfrag8* KrA8 = reinterpret_cast<const bfrag8*>(KrA);
  const int tb_base = (lane & 15) * 584 + ((lane >> 4) << 3);
#pragma unroll 3
  for (int ks = 0; ks < 18; ++ks) {
    bfrag8 af = KrA8[(wv * 18 + ks) * 64 + lane];
    bfrag8 bfr = *reinterpret_cast<const bfrag8*>(&Tb[tb_base + ks * 32]);
    acc = __builtin_amdgcn_mfma_f32_16x16x32_bf16(af, bfr, acc, 0, 0, 0);
  }
#pragma unroll
  for (int reg = 0; reg < 4; ++reg) {
    const int ii = wv * 16 + ((lane >> 4) << 2) + reg;
    const unsigned short hi = bf16bits(acc[reg]);
    Xh[(lane & 15) * 136 + ii] = hi;
    Xl[(lane & 15) * 136 + ii] = bf16bits(acc[reg] - bf16val(hi));
  }
  __syncthreads();

  // ---- Phase C: GRU matvec via MFMA (3-product split-bf16) ----
  const bfrag8* Wh8 = reinterpret_cast<const bfrag8*>(Wh);
  const bfrag8* Wl8 = reinterpret_cast<const bfrag8*>(Wl);
  f32x4 g0 = {0,0,0,0}, g1 = {0,0,0,0}, g2 = {0,0,0,0};
  f32x4 g3 = {0,0,0,0}, g4 = {0,0,0,0}, g5 = {0,0,0,0};
  f32x4* gptr[6] = {&g0, &g1, &g2, &g3, &g4, &g5};
#pragma unroll
  for (int q = 0; q < 6; ++q) {
    const int s = q / 3;
    f32x4 g = *gptr[q];
#pragma unroll
    for (int ks = 0; ks < 2; ++ks) {
      const int fidx = ((wv * 6 + q) * 2 + ks) * 64 + lane;
      bfrag8 Ah = Wh8[fidx];
      bfrag8 Al = Wl8[fidx];
      const int xoff = (lane & 15) * 136 + (s * 2 + ks) * 32 + ((lane >> 4) << 3);
      bfrag8 Bh = *reinterpret_cast<const bfrag8*>(&Xh[xoff]);
      bfrag8 Bl = *reinterpret_cast<const bfrag8*>(&Xl[xoff]);
      g = __builtin_amdgcn_mfma_f32_16x16x32_bf16(Ah, Bh, g, 0, 0, 0);
      g = __builtin_amdgcn_mfma_f32_16x16x32_bf16(Ah, Bl, g, 0, 0, 0);
      g = __builtin_amdgcn_mfma_f32_16x16x32_bf16(Al, Bh, g, 0, 0, 0);
    }
    *gptr[q] = g;
  }
#pragma unroll
  for (int reg = 0; reg < 4; ++reg) {
    const int i = wv * 16 + ((lane >> 4) << 2) + reg;
    const int atom = lane & 15;
    const float r = sigmoidf_(g0[reg] + bias_s[i] + g3[reg] + bias_s[192 + i]);
    const float z = sigmoidf_(g1[reg] + bias_s[64 + i] + g4[reg] + bias_s[256 + i]);
    const float nn = tanhf(g2[reg] + bias_s[128 + i] + r * (g5[reg] + bias_s[320 + i]));
    const float hold = Hf[atom * 68 + i];
    AHa[atom * 68 + i] = (1.0f - z) * nn + z * hold;
  }
  __syncthreads();
#pragma unroll
  for (int aa = 0; aa < MAW; ++aa) {
    const int a = wv * MAW + aa;
    h_out[(ablk + a) * 64 + lane] = AHa[a * 68 + lane];
  }
}

// ============ qkv projection + valid mask ============
#define QABLK 4
__global__ __launch_bounds__(256, 2) void k_qkv(
    const float* __restrict__ h, const float* __restrict__ w,
    const float* __restrict__ b, float* __restrict__ qkv,
    int* __restrict__ valid) {
  __shared__ __align__(16) float w_s[192 * 64];
  __shared__ __align__(16) float x_s[4][QABLK][64];
  const int tid = threadIdx.x, lane = tid & 63, wv = tid >> 6;
  for (int idx = tid; idx < 192 * 64; idx += 256) {
    int r = idx >> 6, d = idx & 63;
    w_s[(r << 6) + ((((d >> 2) ^ (r & 7)) << 2) | (d & 3))] = w[idx];
  }
  __syncthreads();
  const float4* w4 = reinterpret_cast<const float4*>(w_s);
  const float bq = b[lane], bk = b[64 + lane], bv_ = b[128 + lane];
  const int swz = lane & 7;
  const int gw = blockIdx.x * 4 + wv;
  const int stride = gridDim.x * 4 * QABLK;
  for (int ag = gw * QABLK; ag < NA; ag += stride) {
#pragma unroll
    for (int e = 0; e < QABLK; ++e) x_s[wv][e][lane] = h[(ag + e) * 64 + lane];
    __syncthreads();
    const float4* x4 = reinterpret_cast<const float4*>(&x_s[wv][0][0]);
    float aq[QABLK] = {0,0,0,0}, ak[QABLK] = {0,0,0,0}, av_[QABLK] = {0,0,0,0};
    int nz[QABLK] = {0,0,0,0};
#pragma unroll 4
    for (int d4 = 0; d4 < 16; ++d4) {
      int sl = d4 ^ swz;
      float4 wq = w4[(lane << 4) + sl];
      float4 wk = w4[((lane + 64) << 4) + sl];
      float4 wvv = w4[((lane + 128) << 4) + sl];
#pragma unroll
      for (int e = 0; e < QABLK; ++e) {
        float4 xv = x4[e * 16 + d4];
        aq[e] += wq.x*xv.x + wq.y*xv.y + wq.z*xv.z + wq.w*xv.w;
        ak[e] += wk.x*xv.x + wk.y*xv.y + wk.z*xv.z + wk.w*xv.w;
        av_[e] += wvv.x*xv.x + wvv.y*xv.y + wvv.z*xv.z + wvv.w*xv.w;
        nz[e] |= (int)(xv.x != 0.f) | (int)(xv.y != 0.f) | (int)(xv.z != 0.f) | (int)(xv.w != 0.f);
      }
    }
#pragma unroll
    for (int e = 0; e < QABLK; ++e) {
      qkv[(ag + e) * 192 + lane] = aq[e] + bq;
      qkv[(ag + e) * 192 + 64 + lane] = ak[e] + bk;
      qkv[(ag + e) * 192 + 128 + lane] = av_[e] + bv_;
      if (lane == 0) valid[ag + e] = nz[e];
    }
    __syncthreads();
  }
}

// ============ attention: one wave per (molecule, head), online softmax ============
__global__ void k_attn(const float* __restrict__ qkv, const int* __restrict__ valid,
                       float* __restrict__ ao) {
  const int b = blockIdx.x >> 3, hh = blockIdx.x & 7;
  __shared__ float k_s[64][8];
  __shared__ float v_s[64][8];
  __shared__ int vd_s[64];
  const int lane = threadIdx.x;
  const int rowbase = (b * 64 + lane) * 192;
#pragma unroll
  for (int j = 0; j < 8; ++j) {
    k_s[lane][j] = qkv[rowbase + 64 + hh * 8 + j];
    v_s[lane][j] = qkv[rowbase + 128 + hh * 8 + j];
  }
  vd_s[lane] = valid[b * 64 + lane];
  __syncthreads();
  float q[8];
#pragma unroll
  for (int j = 0; j < 8; ++j) q[j] = qkv[rowbase + hh * 8 + j];
  float m = -3.0e38f, l = 0.f, o[8] = {0,0,0,0,0,0,0,0};
  for (int t = 0; t < 64; ++t) {
    float s = 0.f;
#pragma unroll
    for (int j = 0; j < 8; ++j) s += q[j] * k_s[t][j];
    s *= 0.35355339059327373f;
    s = vd_s[t] ? s : -1.0e9f;
    float mn = fmaxf(m, s);
    float c = expf(m - mn);
    float p = expf(s - mn);
    l = l * c + p;
#pragma unroll
    for (int j = 0; j < 8; ++j) o[j] = o[j] * c + p * v_s[t][j];
    m = mn;
  }
  const float inv = 1.0f / l;
  const int obase = (b * 64 + lane) * 64 + hh * 8;
#pragma unroll
  for (int j = 0; j < 8; ++j) ao[obase + j] = o[j] * inv;
}

// ============ out_proj + residual + LN1 ============
#define OABLK 4
__global__ __launch_bounds__(256, 1) void k_out_ln1(
    const float* __restrict__ x, const float* __restrict__ ao,
    const float* __restrict__ w, const float* __restrict__ bias,
    const float* __restrict__ g, const float* __restrict__ bb,
    float* __restrict__ y1) {
  __shared__ __align__(16) float w_s[64 * 64];
  __shared__ __align__(16) float a_s[4][OABLK][64];
  const int tid = threadIdx.x, lane = tid & 63, wv = tid >> 6;
  for (int idx = tid; idx < 64 * 64; idx += 256) {
    int r = idx >> 6, d = idx & 63;
    w_s[(r << 6) + ((((d >> 2) ^ (r & 7)) << 2) | (d & 3))] = w[idx];
  }
  __syncthreads();
  const float4* w4 = reinterpret_cast<const float4*>(w_s);
  const float bo = bias[lane], gg = g[lane], bbb = bb[lane];
  const int swz = lane & 7;
  const int gw = blockIdx.x * 4 + wv;
  const int stride = gridDim.x * 4 * OABLK;
  for (int ag = gw * OABLK; ag < NA; ag += stride) {
#pragma unroll
    for (int e = 0; e < OABLK; ++e) a_s[wv][e][lane] = ao[(ag + e) * 64 + lane];
    __syncthreads();
    const float4* a4 = reinterpret_cast<const float4*>(&a_s[wv][0][0]);
    float acc[OABLK] = {0,0,0,0};
#pragma unroll 4
    for (int d4 = 0; d4 < 16; ++d4) {
      int sl = d4 ^ swz;
      float4 wr = w4[(lane << 4) + sl];
#pragma unroll
      for (int e = 0; e < OABLK; ++e) {
        float4 av = a4[e * 16 + d4];
        acc[e] += wr.x*av.x + wr.y*av.y + wr.z*av.z + wr.w*av.w;
      }
    }
#pragma unroll
    for (int e = 0; e < OABLK; ++e) {
      float val = acc[e] + bo + x[(ag + e) * 64 + lane];
      float s1 = val, s2 = val * val;
#pragma unroll
      for (int mm = 1; mm < 64; mm <<= 1) {
        s1 += __shfl_xor(s1, mm, 64);
        s2 += __shfl_xor(s2, mm, 64);
      }
      float mu = s1 * 0.015625f;
      float var = s2 * 0.015625f - mu * mu;
      y1[(ag + e) * 64 + lane] = (val - mu) * rsqrtf(var + 1e-5f) * gg + bbb;
    }
    __syncthreads();
  }
}

// ============ FFN via MFMA (split-bf16 3-product) + residual + LN2 ============
__global__ __launch_bounds__(256, 3) void k_ffn(
    const float* __restrict__ y1,
    const unsigned short* __restrict__ W1h, const unsigned short* __restrict__ W1l,
    const unsigned short* __restrict__ W2h, const unsigned short* __restrict__ W2l,
    const float* __restrict__ b1, const float* __restrict__ b2,
    const float* __restrict__ g, const float* __restrict__ bb,
    float* __restrict__ y2) {
  __shared__ __align__(16) unsigned short Xh[16 * 72];    // 2,304 B (y1 bf16 hi)
  __shared__ __align__(16) unsigned short Xl[16 * 72];    // 2,304 B
  __shared__ __align__(16) unsigned short Hh[16 * 520];   // 16,640 B (hidden hi)
  __shared__ __align__(16) unsigned short Hl[16 * 520];   // 16,640 B
  __shared__ __align__(16) float Y1f[16 * 68];            // 4,352 B
  __shared__ __align__(16) float Of[16 * 68];             // 4,352 B
  const int tid = threadIdx.x, lane = tid & 63, wv = tid >> 6;
  const int ablk = blockIdx.x * 16;

  // stage y1 (fp32 for residual + bf16 hi/lo for GEMM1 B-operand)
#pragma unroll
  for (int aa = 0; aa < 4; ++aa) {
    const int a = wv * 4 + aa;
    const float v = y1[(ablk + a) * 64 + lane];
    Y1f[a * 68 + lane] = v;
    const unsigned short hi = bf16bits(v);
    Xh[a * 72 + lane] = hi;
    Xl[a * 72 + lane] = bf16bits(v - bf16val(hi));
  }
  __syncthreads();

  // ---- GEMM1: 8 tiles/wave, each K=64 ----
  const bfrag8* W1h8 = reinterpret_cast<const bfrag8*>(W1h);
  const bfrag8* W1l8 = reinterpret_cast<const bfrag8*>(W1l);
  const int xoff_base = (lane & 15) * 72 + ((lane >> 4) << 3);
#pragma unroll 2
  for (int t = 0; t < 8; ++t) {
    f32x4 acc = {0.f, 0.f, 0.f, 0.f};
    const int tile = wv * 8 + t;
#pragma unroll
    for (int ks = 0; ks < 2; ++ks) {
      const int fidx = (tile * 2 + ks) * 64 + lane;
      bfrag8 Ah = W1h8[fidx];
      bfrag8 Al = W1l8[fidx];
      bfrag8 Bh = *reinterpret_cast<const bfrag8*>(&Xh[xoff_base + ks * 32]);
      bfrag8 Bl = *reinterpret_cast<const bfrag8*>(&Xl[xoff_base + ks * 32]);
      acc = __builtin_amdgcn_mfma_f32_16x16x32_bf16(Ah, Bh, acc, 0, 0, 0);
      acc = __builtin_amdgcn_mfma_f32_16x16x32_bf16(Ah, Bl, acc, 0, 0, 0);
      acc = __builtin_amdgcn_mfma_f32_16x16x32_bf16(Al, Bh, acc, 0, 0, 0);
    }
#pragma unroll
    for (int reg = 0; reg < 4; ++reg) {
      const int hid = tile * 16 + ((lane >> 4) << 2) + reg;
      float val = fmaxf(acc[reg] + b1[hid], 0.f);
      const unsigned short hi = bf16bits(val);
      Hh[(lane & 15) * 520 + hid] = hi;
      Hl[(lane & 15) * 520 + hid] = bf16bits(val - bf16val(hi));
    }
  }
  __syncthreads();

  // ---- GEMM2: 1 tile/wave, K=512 ----
  const bfrag8* W2h8 = reinterpret_cast<const bfrag8*>(W2h);
  const bfrag8* W2l8 = reinterpret_cast<const bfrag8*>(W2l);
  f32x4 acc2 = {0.f, 0.f, 0.f, 0.f};
  const int hoff_base = (lane & 15) * 520 + ((lane >> 4) << 3);
#pragma unroll 4
  for (int ks = 0; ks < 16; ++ks) {
    const int fidx = (wv * 16 + ks) * 64 + lane;
    bfrag8 Ah = W2h8[fidx];
    bfrag8 Al = W2l8[fidx];
    bfrag8 Bh = *reinterpret_cast<const bfrag8*>(&Hh[hoff_base + ks * 32]);
    bfrag8 Bl = *reinterpret_cast<const bfrag8*>(&Hl[hoff_base + ks * 32]);
    acc2 = __builtin_amdgcn_mfma_f32_16x16x32_bf16(Ah, Bh, acc2, 0, 0, 0);
    acc2 = __builtin_amdgcn_mfma_f32_16x16x32_bf16(Ah, Bl, acc2, 0, 0, 0);
    acc2 = __builtin_amdgcn_mfma_f32_16x16x32_bf16(Al, Bh, acc2, 0, 0, 0);
  }
#pragma unroll
  for (int reg = 0; reg < 4; ++reg) {
    const int outr = wv * 16 + ((lane >> 4) << 2) + reg;
    Of[(lane & 15) * 68 + outr] = acc2[reg] + b2[outr];
  }
  __syncthreads();

  // ---- residual + LN2 (per atom) ----
  const float gg = g[lane], bbb = bb[lane];
#pragma unroll
  for (int aa = 0; aa < 4; ++aa) {
    const int a = wv * 4 + aa;
    float val = Y1f[a * 68 + lane] + Of[a * 68 + lane];
    float s1 = val, s2 = val * val;
#pragma unroll
    for (int mm = 1; mm < 64; mm <<= 1) {
      s1 += __shfl_xor(s1, mm, 64);
      s2 += __shfl_xor(s2, mm, 64);
    }
    float mu = s1 * 0.015625f;
    float var = s2 * 0.015625f - mu * mu;
    y2[(ablk + a) * 64 + lane] = (val - mu) * rsqrtf(var + 1e-5f) * gg + bbb;
  }
}

// ============ mean-pool over tokens (4 waves split the 64 tokens) ============
__global__ __launch_bounds__(256) void k_pool(const float* __restrict__ y2,
                                              float* __restrict__ pooled) {
  const int b = blockIdx.x;
  const int tid = threadIdx.x, lane = tid & 63, wv = tid >> 6;
  __shared__ float part[4][64];
  float s = 0.f;
#pragma unroll 4
  for (int t = wv * 16; t < wv * 16 + 16; ++t) s += y2[(b * 64 + t) * 64 + lane];
  part[wv][lane] = s;
  __syncthreads();
  if (wv == 0)
    pooled[b * 64 + lane] =
        (part[0][lane] + part[1][lane] + part[2][lane] + part[3][lane]) * 0.015625f;
}

// ============ readout head ============
__global__ __launch_bounds__(256) void k_head(
    const float* __restrict__ pooled, const float* __restrict__ d1w,
    const float* __restrict__ d1b, const float* __restrict__ d2w,
    const float* __restrict__ d2b, float* __restrict__ out) {
  const int b = blockIdx.x;
  __shared__ float p_s[64];
  __shared__ float red_s[4];
  const int tid = threadIdx.x;
  if (tid < 64) p_s[tid] = pooled[b * 64 + tid];
  __syncthreads();
  float acc = 0.f;
#pragma unroll
  for (int rep = 0; rep < 2; ++rep) {
    int c = rep * 256 + tid;
    float hvv = d1b[c];
    for (int d = 0; d < 64; ++d) hvv += p_s[d] * d1w[d * 512 + c];
    acc += fmaxf(hvv, 0.f) * d2w[c];
  }
#pragma unroll
  for (int mm = 1; mm < 64; mm <<= 1) acc += __shfl_xor(acc, mm, 64);
  if ((tid & 63) == 0) red_s[tid >> 6] = acc;
  __syncthreads();
  if (tid == 0) {
    float t = red_s[0] + red_s[1] + red_s[2] + red_s[3] + d2b[0];
    out[b] = 1.0f / (1.0f + expf(-t));
  }
}

extern "C" void kernel_launch(void* const* d_in, const int* in_sizes, int n_in,
                              void* d_out, int out_size, void* d_ws, size_t ws_size,
                              hipStream_t stream) {
  (void)in_sizes; (void)n_in; (void)out_size; (void)ws_size;
  const float* af   = (const float*)d_in[0];
  const float* bfeat= (const float*)d_in[1];
  const int*   pairs= (const int*)d_in[2];
  // d_in[3] = molecule_indicator (identity layout; unused)
  const float* kern = (const float*)d_in[4];
  const float* kbias= (const float*)d_in[5];
  const float* wih  = (const float*)d_in[6];
  const float* whh  = (const float*)d_in[7];
  const float* bih  = (const float*)d_in[8];
  const float* bhh  = (const float*)d_in[9];
  const float* ipw  = (const float*)d_in[10];
  const float* ipb  = (const float*)d_in[11];
  const float* opw  = (const float*)d_in[12];
  const float* opb  = (const float*)d_in[13];
  const float* fw1  = (const float*)d_in[14];
  const float* fb1  = (const float*)d_in[15];
  const float* fw2  = (const float*)d_in[16];
  const float* fb2  = (const float*)d_in[17];
  const float* l1g  = (const float*)d_in[18];
  const float* l1b  = (const float*)d_in[19];
  const float* l2g  = (const float*)d_in[20];
  const float* l2b  = (const float*)d_in[21];
  const float* d1w  = (const float*)d_in[22];
  const float* d1b  = (const float*)d_in[23];
  const float* d2w  = (const float*)d_in[24];
  const float* d2b  = (const float*)d_in[25];
  float* out = (float*)d_out;

  // workspace layout (floats)
  float* ws = (float*)d_ws;
  float* h      = ws;                    // ping buffer (final h after 4 steps)
  float* h2     = h + (size_t)NA * 64;   // pong buffer
  float* qkv    = h2 + (size_t)NA * 64;
  float* ao     = qkv + (size_t)NA * 192;
  float* y1     = ao + (size_t)NA * 64;
  float* y2     = y1 + (size_t)NA * 64;
  float* pooled = y2 + (size_t)NA * 64;
  int*   valid  = (int*)(pooled + 256 * 64);

  // FFN weight fragments: AFTER base layout (ws headroom proven in round 3).
  unsigned short* W1h = (unsigned short*)(valid + NA);
  unsigned short* W1l = W1h + 32768;
  unsigned short* W2h = W1l + 32768;
  unsigned short* W2l = W2h + 32768;

  // MP-loop scratch aliased into the qkv region (dead until after the loop):
  unsigned short* KrA = (unsigned short*)qkv;  // 36864 ushort
  int*   count  = (int*)(qkv + 36864);         // NA
  int*   start  = count + NA;                  // NA+1
  int*   cursor = start + NA + 1;              // NA
  int*   elist  = cursor + NA;                 // NE
  int*   bsum   = elist + NE;                  // 256
  int*   sdst   = bsum + 256;                  // NE + 8 pad
  float* sbf    = (float*)(sdst + NE + 8);     // NE*8 + 64 pad
  unsigned short* Wh = (unsigned short*)(sbf + (size_t)NE * 8 + 64);   // 24576 ushort
  unsigned short* Wl = Wh + 24576;                                     // 24576 ushort

  k_init_h<<<NA * 64 / 256, 256, 0, stream>>>(af, h, count);
  k_prep_KrA<<<144, 256, 0, stream>>>(kern, kbias, KrA);
  k_prep_Wg<<<96, 256, 0, stream>>>(wih, whh, Wh, Wl);
  k_prep_Wffn<<<256, 256, 0, stream>>>(fw1, fw2, W1h, W1l, W2h, W2l);
  k_count<<<NE / 256, 256, 0, stream>>>(pairs, count);
  k_scan1<<<64, 256, 0, stream>>>(count, bsum);
  k_scan2<<<64, 256, 0, stream>>>(count, bsum, start, cursor);
  k_place<<<NE / 256, 256, 0, stream>>>(pairs, cursor, elist);
  k_reorder<<<NE * 8 / 256, 256, 0, stream>>>(bfeat, pairs, elist, sdst, sbf);

  float* hin = h;
  float* hout = h2;
  for (int s = 0; s < 4; ++s) {
    k_msg<<<NA / 16, 256, 0, stream>>>(hin, start, sdst, sbf, KrA,
                                       Wh, Wl, bih, bhh, hout);
    float* tmp = hin; hin = hout; hout = tmp;
  }
  // 4 swaps -> final h is back in 'h'

  k_qkv<<<512, 256, 0, stream>>>(h, ipw, ipb, qkv, valid);
  k_attn<<<2048, 64, 0, stream>>>(qkv, valid, ao);
  k_out_ln1<<<512, 256, 0, stream>>>(h, ao, opw, opb, l1g, l1b, y1);
  k_ffn<<<NA / 16, 256, 0, stream>>>(y1, W1h, W1l, W2h, W2l, fb1, fb2, l2g, l2b, y2);
  k_pool<<<256, 256, 0, stream>>>(y2, pooled);
  k_head<<<256, 256, 0, stream>>>(pooled, d1w, d1b, d2w, d2b, out);
}

// Round 14
// 161.725 us; speedup vs baseline: 2.7442x; 1.1604x over previous
//
#include <hip/hip_runtime.h>
#include <hip/hip_bf16.h>
#include <math.h>

#define NA 16384
#define NE 65536
#define AD 29

typedef __attribute__((ext_vector_type(8))) short bfrag8;
typedef __attribute__((ext_vector_type(4))) float f32x4;

__device__ __forceinline__ float sigmoidf_(float x) { return 1.0f / (1.0f + expf(-x)); }
__device__ __forceinline__ unsigned short bf16bits(float x) {
  __hip_bfloat16 hb = __float2bfloat16(x);
  return *reinterpret_cast<unsigned short*>(&hb);
}
__device__ __forceinline__ float bf16val(unsigned short u) {
  unsigned int b = ((unsigned int)u) << 16;
  return __uint_as_float(b);
}

// ============ init h: pad atom features 29 -> 64; also zero count[] ============
__global__ void k_init_h(const float* __restrict__ af, float* __restrict__ h,
                         int* __restrict__ count) {
  int idx = blockIdx.x * 256 + threadIdx.x;
  if (idx >= NA * 64) return;
  if (idx < NA) count[idx] = 0;
  int a = idx >> 6, d = idx & 63;
  h[idx] = (d < AD) ? af[a * AD + d] : 0.0f;
}

// ============ ALL weight fragment preps fused (once per call) ============
// ranges: [0,36864) KrA bf16 | [36864,61440) GRU Wg hi/lo | [61440,126976)
// FFN W1/W2 hi/lo | [126976,143360) attn ipw/opw hi/lo.
__global__ void k_prep_all(
    const float* __restrict__ kern, const float* __restrict__ kbias,
    const float* __restrict__ wih, const float* __restrict__ whh,
    const float* __restrict__ w1, const float* __restrict__ w2,
    const float* __restrict__ ipw, const float* __restrict__ opw,
    unsigned short* __restrict__ KrA,
    unsigned short* __restrict__ Wh, unsigned short* __restrict__ Wl,
    unsigned short* __restrict__ W1h, unsigned short* __restrict__ W1l,
    unsigned short* __restrict__ W2h, unsigned short* __restrict__ W2l,
    unsigned short* __restrict__ PQh, unsigned short* __restrict__ PQl,
    unsigned short* __restrict__ POh, unsigned short* __restrict__ POl) {
  int idx0 = blockIdx.x * 256 + threadIdx.x;
  if (idx0 < 36864) {                     // KrA (message kernel, bf16 single)
    int idx = idx0;
    int r = idx & 7;
    int lane = (idx >> 3) & 63;
    int tmp2 = idx >> 9;                  // w*18 + ks
    int ks = tmp2 % 18, w = tmp2 / 18;
    int i = w * 16 + (lane & 15);
    int kj = ks * 32 + ((lane >> 4) << 3) + r;
    int k9 = kj >> 6, j = kj & 63;
    float v = (k9 < 8) ? kern[k9 * 4096 + i * 64 + j] : kbias[i * 64 + j];
    KrA[idx] = bf16bits(v);
  } else if (idx0 < 61440) {              // GRU weights hi/lo
    int idx = idx0 - 36864;
    int r = idx & 7;
    int lane = (idx >> 3) & 63;
    int t2 = idx >> 9;
    int ks = t2 & 1;
    int t3 = t2 >> 1;
    int q = t3 % 6, w = t3 / 6;
    int s = q / 3, g = q % 3;
    int R = g * 64 + w * 16 + (lane & 15);
    int kk = ks * 32 + ((lane >> 4) << 3) + r;
    float v = (s == 0) ? wih[R * 64 + kk] : whh[R * 64 + kk];
    unsigned short hi = bf16bits(v);
    Wh[idx] = hi;
    Wl[idx] = bf16bits(v - bf16val(hi));
  } else if (idx0 < 126976) {             // FFN weights hi/lo
    int idx = idx0 - 61440;
    int r = idx & 7;
    int lane = (idx >> 3) & 63;
    int rest = (idx >> 9) & 63;
    if (idx < 32768) {                    // W1
      int tile = rest >> 1, ks = rest & 1;
      int hid = tile * 16 + (lane & 15);
      int kk = ks * 32 + ((lane >> 4) << 3) + r;
      float v = w1[kk * 512 + hid];
      unsigned short hi = bf16bits(v);
      W1h[idx] = hi;
      W1l[idx] = bf16bits(v - bf16val(hi));
    } else {                              // W2
      int i2 = idx - 32768;
      int tile = rest >> 4, ks = rest & 15;
      int outr = tile * 16 + (lane & 15);
      int kk = ks * 32 + ((lane >> 4) << 3) + r;
      float v = w2[kk * 64 + outr];
      unsigned short hi = bf16bits(v);
      W2h[i2] = hi;
      W2l[i2] = bf16bits(v - bf16val(hi));
    }
  } else if (idx0 < 143360) {             // attn in_proj / out_proj hi/lo
    int i = idx0 - 126976;
    if (i < 12288) {                      // ipw: 12 tiles x 2 ksteps
      int r = i & 7;
      int lane = (i >> 3) & 63;
      int rest = i >> 9;                  // 0..23
      int t = rest >> 1, ks = rest & 1;
      int R = t * 16 + (lane & 15);
      int kk = ks * 32 + ((lane >> 4) << 3) + r;
      float v = ipw[R * 64 + kk];
      unsigned short hi = bf16bits(v);
      PQh[i] = hi;
      PQl[i] = bf16bits(v - bf16val(hi));
    } else {                              // opw: 4 tiles x 2 ksteps
      int i2 = i - 12288;
      int r = i2 & 7;
      int lane = (i2 >> 3) & 63;
      int rest = i2 >> 9;                 // 0..7
      int t = rest >> 1, ks = rest & 1;
      int R = t * 16 + (lane & 15);
      int kk = ks * 32 + ((lane >> 4) << 3) + r;
      float v = opw[R * 64 + kk];
      unsigned short hi = bf16bits(v);
      POh[i2] = hi;
      POl[i2] = bf16bits(v - bf16val(hi));
    }
  }
}

// ============ edge bucketing by src (once per call; counting sort) ============
__global__ void k_count(const int* __restrict__ pairs, int* __restrict__ count) {
  int e = blockIdx.x * 256 + threadIdx.x;
  if (e >= NE) return;
  atomicAdd(&count[pairs[2 * e]], 1);
}
__global__ void k_scan1(const int* __restrict__ count, int* __restrict__ bsum) {
  __shared__ int red[256];
  int b = blockIdx.x, t = threadIdx.x;
  red[t] = count[b * 256 + t];
  __syncthreads();
  for (int s = 128; s > 0; s >>= 1) { if (t < s) red[t] += red[t + s]; __syncthreads(); }
  if (t == 0) bsum[b] = red[0];
}
__global__ void k_scan2(const int* __restrict__ count, const int* __restrict__ bsum,
                        int* __restrict__ start, int* __restrict__ cursor) {
  __shared__ int sc[256];
  __shared__ int basev;
  int b = blockIdx.x, t = threadIdx.x;
  if (t == 0) { int s = 0; for (int i = 0; i < b; ++i) s += bsum[i]; basev = s; }
  int v = count[b * 256 + t];
  sc[t] = v;
  __syncthreads();
  for (int off = 1; off < 256; off <<= 1) {
    int add = (t >= off) ? sc[t - off] : 0;
    __syncthreads();
    sc[t] += add;
    __syncthreads();
  }
  int excl = sc[t] - v + basev;
  start[b * 256 + t] = excl;
  cursor[b * 256 + t] = excl;
  if (b * 256 + t == NA - 1) start[NA] = excl + v;   // sentinel = NE
}
__global__ void k_place(const int* __restrict__ pairs, int* __restrict__ cursor,
                        int* __restrict__ elist) {
  int e = blockIdx.x * 256 + threadIdx.x;
  if (e >= NE) return;
  int pos = atomicAdd(&cursor[pairs[2 * e]], 1);
  elist[pos] = e;
}
__global__ void k_reorder(const float* __restrict__ bf, const int* __restrict__ pairs,
                          const int* __restrict__ elist, int* __restrict__ sdst,
                          float* __restrict__ sbf) {
  int idx = blockIdx.x * 256 + threadIdx.x;    // NE*8 threads
  if (idx >= NE * 8) return;
  int pos = idx >> 3, k = idx & 7;
  int e = elist[pos];
  sbf[idx] = bf[e * 8 + k];
  if (k == 0) sdst[pos] = pairs[2 * e + 1];
}

// ============ fused message + GRU step, fully MFMA'd dense parts ============
#define MW 4
#define MAW 4
__global__ __launch_bounds__(256, 4) void k_msg(
    const float* __restrict__ h_in, const int* __restrict__ start,
    const int* __restrict__ sdst, const float* __restrict__ sbf,
    const unsigned short* __restrict__ KrA,
    const unsigned short* __restrict__ Wh, const unsigned short* __restrict__ Wl,
    const float* __restrict__ bih, const float* __restrict__ bhh,
    float* __restrict__ h_out) {
  __shared__ __align__(16) unsigned short Tb[16 * 584];   // 18,688 B
  __shared__ __align__(16) unsigned short Xh[16 * 136];   // 4,352 B
  __shared__ __align__(16) unsigned short Xl[16 * 136];   // 4,352 B
  __shared__ __align__(16) float Hf[16 * 68];             // 4,352 B
  __shared__ __align__(16) float AHa[16 * 68];            // 4,352 B
  __shared__ float bias_s[384];                           // 1,536 B
  const int tid = threadIdx.x, lane = tid & 63, wv = tid >> 6;
  const int ablk = blockIdx.x * 16;
  const int awave = ablk + wv * MAW;

  // ---- stage h (fp32 + bf16 hi/lo) and biases ----
#pragma unroll
  for (int aa = 0; aa < MAW; ++aa) {
    const int a = wv * MAW + aa;
    const float v = h_in[(ablk + a) * 64 + lane];
    Hf[a * 68 + lane] = v;
    const unsigned short hi = bf16bits(v);
    Xh[a * 136 + 64 + lane] = hi;
    Xl[a * 136 + 64 + lane] = bf16bits(v - bf16val(hi));
  }
  if (tid < 192) { bias_s[tid] = bih[tid]; bias_s[192 + tid] = bhh[tid]; }

  // ---- Phase A: per-atom gather (scalar bf coeffs, fp32 accum, bf16 flush) ----
  for (int a = 0; a < MAW; ++a) {
    const int s0 = __builtin_amdgcn_readfirstlane(start[awave + a]);
    const int s1 = __builtin_amdgcn_readfirstlane(start[awave + a + 1]);
    float t[9] = {0.f, 0.f, 0.f, 0.f, 0.f, 0.f, 0.f, 0.f, 0.f};
    for (int base = s0; base < s1; base += 8) {
      const int nb = s1 - base;
      float hv[8];
#pragma unroll
      for (int i = 0; i < 8; ++i) {
        int d = (i < nb) ? sdst[base + i] : 0;
        hv[i] = (i < nb) ? h_in[d * 64 + lane] : 0.f;
      }
#pragma unroll
      for (int i = 0; i < 8; ++i) {
#pragma unroll
        for (int k = 0; k < 8; ++k)
          t[k] = fmaf(sbf[(base + i) * 8 + k], hv[i], t[k]);   // hv=0 kills pad terms
        t[8] += hv[i];
      }
    }
    const int row = wv * MAW + a;
#pragma unroll
    for (int k = 0; k < 9; ++k) Tb[row * 584 + k * 64 + lane] = bf16bits(t[k]);
  }
  __syncthreads();

  // ---- Phase B: MFMA  agg[i][atom] = sum_kj K[i][kj] * T[atom][kj] ----
  f32x4 acc = {0.f, 0.f, 0.f, 0.f};
  const bfrag8* KrA8 = reinterpret_cast<const bfrag8*>(KrA);
  const int tb_base = (lane & 15) * 584 + ((lane >> 4) << 3);
#pragma unroll 3
  for (int ks = 0; ks < 18; ++ks) {
    bfrag8 af = KrA8[(wv * 18 + ks) * 64 + lane];
    bfrag8 bfr = *reinterpret_cast<const bfrag8*>(&Tb[tb_base + ks * 32]);
    acc = __builtin_amdgcn_mfma_f32_16x16x32_bf16(af, bfr, acc, 0, 0, 0);
  }
#pragma unroll
  for (int reg = 0; reg < 4; ++reg) {
    const int ii = wv * 16 + ((lane >> 4) << 2) + reg;
    const unsigned short hi = bf16bits(acc[reg]);
    Xh[(lane & 15) * 136 + ii] = hi;
    Xl[(lane & 15) * 136 + ii] = bf16bits(acc[reg] - bf16val(hi));
  }
  __syncthreads();

  // ---- Phase C: GRU matvec via MFMA (3-product split-bf16) ----
  const bfrag8* Wh8 = reinterpret_cast<const bfrag8*>(Wh);
  const bfrag8* Wl8 = reinterpret_cast<const bfrag8*>(Wl);
  f32x4 g0 = {0,0,0,0}, g1 = {0,0,0,0}, g2 = {0,0,0,0};
  f32x4 g3 = {0,0,0,0}, g4 = {0,0,0,0}, g5 = {0,0,0,0};
  f32x4* gptr[6] = {&g0, &g1, &g2, &g3, &g4, &g5};
#pragma unroll
  for (int q = 0; q < 6; ++q) {
    const int s = q / 3;
    f32x4 g = *gptr[q];
#pragma unroll
    for (int ks = 0; ks < 2; ++ks) {
      const int fidx = ((wv * 6 + q) * 2 + ks) * 64 + lane;
      bfrag8 Ah = Wh8[fidx];
      bfrag8 Al = Wl8[fidx];
      const int xoff = (lane & 15) * 136 + (s * 2 + ks) * 32 + ((lane >> 4) << 3);
      bfrag8 Bh = *reinterpret_cast<const bfrag8*>(&Xh[xoff]);
      bfrag8 Bl = *reinterpret_cast<const bfrag8*>(&Xl[xoff]);
      g = __builtin_amdgcn_mfma_f32_16x16x32_bf16(Ah, Bh, g, 0, 0, 0);
      g = __builtin_amdgcn_mfma_f32_16x16x32_bf16(Ah, Bl, g, 0, 0, 0);
      g = __builtin_amdgcn_mfma_f32_16x16x32_bf16(Al, Bh, g, 0, 0, 0);
    }
    *gptr[q] = g;
  }
#pragma unroll
  for (int reg = 0; reg < 4; ++reg) {
    const int i = wv * 16 + ((lane >> 4) << 2) + reg;
    const int atom = lane & 15;
    const float r = sigmoidf_(g0[reg] + bias_s[i] + g3[reg] + bias_s[192 + i]);
    const float z = sigmoidf_(g1[reg] + bias_s[64 + i] + g4[reg] + bias_s[256 + i]);
    const float nn = tanhf(g2[reg] + bias_s[128 + i] + r * (g5[reg] + bias_s[320 + i]));
    const float hold = Hf[atom * 68 + i];
    AHa[atom * 68 + i] = (1.0f - z) * nn + z * hold;
  }
  __syncthreads();
#pragma unroll
  for (int aa = 0; aa < MAW; ++aa) {
    const int a = wv * MAW + aa;
    h_out[(ablk + a) * 64 + lane] = AHa[a * 68 + lane];
  }
}

// ============ fused per-molecule: QKV (MFMA) + attention + out_proj (MFMA)
//              + residual + LN1.  1 block = 1 molecule = 64 atoms. ============
__global__ __launch_bounds__(256, 1) void k_mol(
    const float* __restrict__ h,
    const unsigned short* __restrict__ PQh, const unsigned short* __restrict__ PQl,
    const unsigned short* __restrict__ POh, const unsigned short* __restrict__ POl,
    const float* __restrict__ ipb, const float* __restrict__ opb,
    const float* __restrict__ l1g, const float* __restrict__ l1b,
    float* __restrict__ y1) {
  __shared__ __align__(16) float Hf[64 * 65];             // 16,640 B
  __shared__ __align__(16) unsigned short Xh[64 * 72];    //  9,216 B
  __shared__ __align__(16) unsigned short Xl[64 * 72];    //  9,216 B
  __shared__ __align__(16) float QKVs[192 * 65];          // 49,920 B
  __shared__ __align__(16) unsigned short AOh[64 * 72];   //  9,216 B
  __shared__ __align__(16) unsigned short AOl[64 * 72];   //  9,216 B
  __shared__ __align__(16) float Of[64 * 65];             // 16,640 B
  __shared__ int vd[64];
  const int tid = threadIdx.x, lane = tid & 63, wv = tid >> 6;
  const int mol = blockIdx.x;

  // ---- stage h (fp32 + bf16 hi/lo) + valid mask ----
  for (int aa = 0; aa < 16; ++aa) {
    const int a = wv * 16 + aa;
    const float v = h[(mol * 64 + a) * 64 + lane];
    Hf[a * 65 + lane] = v;
    const unsigned short hi = bf16bits(v);
    Xh[a * 72 + lane] = hi;
    Xl[a * 72 + lane] = bf16bits(v - bf16val(hi));
    int nz = __any(v != 0.0f);
    if (lane == 0) vd[a] = nz;
  }
  __syncthreads();

  // ---- QKV GEMM: D[192 rows][atoms]; wave wv owns atom-group wv ----
  const bfrag8* PQh8 = reinterpret_cast<const bfrag8*>(PQh);
  const bfrag8* PQl8 = reinterpret_cast<const bfrag8*>(PQl);
  const int xoff_b = (wv * 16 + (lane & 15)) * 72 + ((lane >> 4) << 3);
#pragma unroll 3
  for (int tile = 0; tile < 12; ++tile) {
    f32x4 acc = {0.f, 0.f, 0.f, 0.f};
#pragma unroll
    for (int ks = 0; ks < 2; ++ks) {
      const int fidx = (tile * 2 + ks) * 64 + lane;
      bfrag8 Ah = PQh8[fidx];
      bfrag8 Al = PQl8[fidx];
      bfrag8 Bh = *reinterpret_cast<const bfrag8*>(&Xh[xoff_b + ks * 32]);
      bfrag8 Bl = *reinterpret_cast<const bfrag8*>(&Xl[xoff_b + ks * 32]);
      acc = __builtin_amdgcn_mfma_f32_16x16x32_bf16(Ah, Bh, acc, 0, 0, 0);
      acc = __builtin_amdgcn_mfma_f32_16x16x32_bf16(Ah, Bl, acc, 0, 0, 0);
      acc = __builtin_amdgcn_mfma_f32_16x16x32_bf16(Al, Bh, acc, 0, 0, 0);
    }
#pragma unroll
    for (int reg = 0; reg < 4; ++reg) {
      const int row = tile * 16 + ((lane >> 4) << 2) + reg;
      QKVs[row * 65 + wv * 16 + (lane & 15)] = acc[reg] + ipb[row];
    }
  }
  __syncthreads();

  // ---- attention: 2 heads per wave; lane = query atom; online softmax ----
#pragma unroll
  for (int hp = 0; hp < 2; ++hp) {
    const int hh = wv * 2 + hp;
    float q[8];
#pragma unroll
    for (int j = 0; j < 8; ++j) q[j] = QKVs[(hh * 8 + j) * 65 + lane];
    float m = -3.0e38f, l = 0.f, o[8] = {0,0,0,0,0,0,0,0};
    for (int t = 0; t < 64; ++t) {
      float s = 0.f;
#pragma unroll
      for (int j = 0; j < 8; ++j) s += q[j] * QKVs[(64 + hh * 8 + j) * 65 + t];
      s *= 0.35355339059327373f;
      s = vd[t] ? s : -1.0e9f;
      float mn = fmaxf(m, s);
      float c = expf(m - mn);
      float p = expf(s - mn);
      l = l * c + p;
#pragma unroll
      for (int j = 0; j < 8; ++j) o[j] = o[j] * c + p * QKVs[(128 + hh * 8 + j) * 65 + t];
      m = mn;
    }
    const float inv = 1.0f / l;
#pragma unroll
    for (int j = 0; j < 8; ++j) {
      const float v = o[j] * inv;
      const unsigned short hi = bf16bits(v);
      AOh[lane * 72 + hh * 8 + j] = hi;
      AOl[lane * 72 + hh * 8 + j] = bf16bits(v - bf16val(hi));
    }
  }
  __syncthreads();

  // ---- out_proj GEMM: D[64 rows][atoms]; wave wv owns atom-group wv ----
  const bfrag8* POh8 = reinterpret_cast<const bfrag8*>(POh);
  const bfrag8* POl8 = reinterpret_cast<const bfrag8*>(POl);
  const int aoff_b = (wv * 16 + (lane & 15)) * 72 + ((lane >> 4) << 3);
#pragma unroll
  for (int tile = 0; tile < 4; ++tile) {
    f32x4 acc = {0.f, 0.f, 0.f, 0.f};
#pragma unroll
    for (int ks = 0; ks < 2; ++ks) {
      const int fidx = (tile * 2 + ks) * 64 + lane;
      bfrag8 Ah = POh8[fidx];
      bfrag8 Al = POl8[fidx];
      bfrag8 Bh = *reinterpret_cast<const bfrag8*>(&AOh[aoff_b + ks * 32]);
      bfrag8 Bl = *reinterpret_cast<const bfrag8*>(&AOl[aoff_b + ks * 32]);
      acc = __builtin_amdgcn_mfma_f32_16x16x32_bf16(Ah, Bh, acc, 0, 0, 0);
      acc = __builtin_amdgcn_mfma_f32_16x16x32_bf16(Ah, Bl, acc, 0, 0, 0);
      acc = __builtin_amdgcn_mfma_f32_16x16x32_bf16(Al, Bh, acc, 0, 0, 0);
    }
#pragma unroll
    for (int reg = 0; reg < 4; ++reg) {
      const int dim = tile * 16 + ((lane >> 4) << 2) + reg;
      Of[(wv * 16 + (lane & 15)) * 65 + dim] = acc[reg] + opb[dim];
    }
  }
  __syncthreads();

  // ---- residual + LN1 (wave wv: its 16 atoms; lane = dim) ----
  const float gg = l1g[lane], bbb = l1b[lane];
  for (int aa = 0; aa < 16; ++aa) {
    const int a = wv * 16 + aa;
    float val = Hf[a * 65 + lane] + Of[a * 65 + lane];
    float s1 = val, s2 = val * val;
#pragma unroll
    for (int mm = 1; mm < 64; mm <<= 1) {
      s1 += __shfl_xor(s1, mm, 64);
      s2 += __shfl_xor(s2, mm, 64);
    }
    float mu = s1 * 0.015625f;
    float var = s2 * 0.015625f - mu * mu;
    y1[(mol * 64 + a) * 64 + lane] = (val - mu) * rsqrtf(var + 1e-5f) * gg + bbb;
  }
}

// ============ FFN via MFMA (split-bf16 3-product) + residual + LN2 ============
__global__ __launch_bounds__(256, 3) void k_ffn(
    const float* __restrict__ y1,
    const unsigned short* __restrict__ W1h, const unsigned short* __restrict__ W1l,
    const unsigned short* __restrict__ W2h, const unsigned short* __restrict__ W2l,
    const float* __restrict__ b1, const float* __restrict__ b2,
    const float* __restrict__ g, const float* __restrict__ bb,
    float* __restrict__ y2) {
  __shared__ __align__(16) unsigned short Xh[16 * 72];
  __shared__ __align__(16) unsigned short Xl[16 * 72];
  __shared__ __align__(16) unsigned short Hh[16 * 520];
  __shared__ __align__(16) unsigned short Hl[16 * 520];
  __shared__ __align__(16) float Y1f[16 * 68];
  __shared__ __align__(16) float Of[16 * 68];
  const int tid = threadIdx.x, lane = tid & 63, wv = tid >> 6;
  const int ablk = blockIdx.x * 16;

#pragma unroll
  for (int aa = 0; aa < 4; ++aa) {
    const int a = wv * 4 + aa;
    const float v = y1[(ablk + a) * 64 + lane];
    Y1f[a * 68 + lane] = v;
    const unsigned short hi = bf16bits(v);
    Xh[a * 72 + lane] = hi;
    Xl[a * 72 + lane] = bf16bits(v - bf16val(hi));
  }
  __syncthreads();

  const bfrag8* W1h8 = reinterpret_cast<const bfrag8*>(W1h);
  const bfrag8* W1l8 = reinterpret_cast<const bfrag8*>(W1l);
  const int xoff_base = (lane & 15) * 72 + ((lane >> 4) << 3);
#pragma unroll 2
  for (int t = 0; t < 8; ++t) {
    f32x4 acc = {0.f, 0.f, 0.f, 0.f};
    const int tile = wv * 8 + t;
#pragma unroll
    for (int ks = 0; ks < 2; ++ks) {
      const int fidx = (tile * 2 + ks) * 64 + lane;
      bfrag8 Ah = W1h8[fidx];
      bfrag8 Al = W1l8[fidx];
      bfrag8 Bh = *reinterpret_cast<const bfrag8*>(&Xh[xoff_base + ks * 32]);
      bfrag8 Bl = *reinterpret_cast<const bfrag8*>(&Xl[xoff_base + ks * 32]);
      acc = __builtin_amdgcn_mfma_f32_16x16x32_bf16(Ah, Bh, acc, 0, 0, 0);
      acc = __builtin_amdgcn_mfma_f32_16x16x32_bf16(Ah, Bl, acc, 0, 0, 0);
      acc = __builtin_amdgcn_mfma_f32_16x16x32_bf16(Al, Bh, acc, 0, 0, 0);
    }
#pragma unroll
    for (int reg = 0; reg < 4; ++reg) {
      const int hid = tile * 16 + ((lane >> 4) << 2) + reg;
      float val = fmaxf(acc[reg] + b1[hid], 0.f);
      const unsigned short hi = bf16bits(val);
      Hh[(lane & 15) * 520 + hid] = hi;
      Hl[(lane & 15) * 520 + hid] = bf16bits(val - bf16val(hi));
    }
  }
  __syncthreads();

  const bfrag8* W2h8 = reinterpret_cast<const bfrag8*>(W2h);
  const bfrag8* W2l8 = reinterpret_cast<const bfrag8*>(W2l);
  f32x4 acc2 = {0.f, 0.f, 0.f, 0.f};
  const int hoff_base = (lane & 15) * 520 + ((lane >> 4) << 3);
#pragma unroll 4
  for (int ks = 0; ks < 16; ++ks) {
    const int fidx = (wv * 16 + ks) * 64 + lane;
    bfrag8 Ah = W2h8[fidx];
    bfrag8 Al = W2l8[fidx];
    bfrag8 Bh = *reinterpret_cast<const bfrag8*>(&Hh[hoff_base + ks * 32]);
    bfrag8 Bl = *reinterpret_cast<const bfrag8*>(&Hl[hoff_base + ks * 32]);
    acc2 = __builtin_amdgcn_mfma_f32_16x16x32_bf16(Ah, Bh, acc2, 0, 0, 0);
    acc2 = __builtin_amdgcn_mfma_f32_16x16x32_bf16(Ah, Bl, acc2, 0, 0, 0);
    acc2 = __builtin_amdgcn_mfma_f32_16x16x32_bf16(Al, Bh, acc2, 0, 0, 0);
  }
#pragma unroll
  for (int reg = 0; reg < 4; ++reg) {
    const int outr = wv * 16 + ((lane >> 4) << 2) + reg;
    Of[(lane & 15) * 68 + outr] = acc2[reg] + b2[outr];
  }
  __syncthreads();

  const float gg = g[lane], bbb = bb[lane];
#pragma unroll
  for (int aa = 0; aa < 4; ++aa) {
    const int a = wv * 4 + aa;
    float val = Y1f[a * 68 + lane] + Of[a * 68 + lane];
    float s1 = val, s2 = val * val;
#pragma unroll
    for (int mm = 1; mm < 64; mm <<= 1) {
      s1 += __shfl_xor(s1, mm, 64);
      s2 += __shfl_xor(s2, mm, 64);
    }
    float mu = s1 * 0.015625f;
    float var = s2 * 0.015625f - mu * mu;
    y2[(ablk + a) * 64 + lane] = (val - mu) * rsqrtf(var + 1e-5f) * gg + bbb;
  }
}

// ============ mean-pool + readout head fused (1 block per molecule) ============
__global__ __launch_bounds__(256) void k_head(
    const float* __restrict__ y2, const float* __restrict__ d1w,
    const float* __restrict__ d1b, const float* __restrict__ d2w,
    const float* __restrict__ d2b, float* __restrict__ out) {
  const int b = blockIdx.x;
  const int tid = threadIdx.x, lane = tid & 63, wv = tid >> 6;
  __shared__ float part[4][64];
  __shared__ float p_s[64];
  __shared__ float red_s[4];
  float s = 0.f;
#pragma unroll 4
  for (int t = wv * 16; t < wv * 16 + 16; ++t) s += y2[(b * 64 + t) * 64 + lane];
  part[wv][lane] = s;
  __syncthreads();
  if (tid < 64)
    p_s[tid] = (part[0][tid] + part[1][tid] + part[2][tid] + part[3][tid]) * 0.015625f;
  __syncthreads();
  float acc = 0.f;
#pragma unroll
  for (int rep = 0; rep < 2; ++rep) {
    int c = rep * 256 + tid;
    float hvv = d1b[c];
    for (int d = 0; d < 64; ++d) hvv += p_s[d] * d1w[d * 512 + c];
    acc += fmaxf(hvv, 0.f) * d2w[c];
  }
#pragma unroll
  for (int mm = 1; mm < 64; mm <<= 1) acc += __shfl_xor(acc, mm, 64);
  if ((tid & 63) == 0) red_s[tid >> 6] = acc;
  __syncthreads();
  if (tid == 0) {
    float t = red_s[0] + red_s[1] + red_s[2] + red_s[3] + d2b[0];
    out[b] = 1.0f / (1.0f + expf(-t));
  }
}

extern "C" void kernel_launch(void* const* d_in, const int* in_sizes, int n_in,
                              void* d_out, int out_size, void* d_ws, size_t ws_size,
                              hipStream_t stream) {
  (void)in_sizes; (void)n_in; (void)out_size; (void)ws_size;
  const float* af   = (const float*)d_in[0];
  const float* bfeat= (const float*)d_in[1];
  const int*   pairs= (const int*)d_in[2];
  // d_in[3] = molecule_indicator (identity layout; unused)
  const float* kern = (const float*)d_in[4];
  const float* kbias= (const float*)d_in[5];
  const float* wih  = (const float*)d_in[6];
  const float* whh  = (const float*)d_in[7];
  const float* bih  = (const float*)d_in[8];
  const float* bhh  = (const float*)d_in[9];
  const float* ipw  = (const float*)d_in[10];
  const float* ipb  = (const float*)d_in[11];
  const float* opw  = (const float*)d_in[12];
  const float* opb  = (const float*)d_in[13];
  const float* fw1  = (const float*)d_in[14];
  const float* fb1  = (const float*)d_in[15];
  const float* fw2  = (const float*)d_in[16];
  const float* fb2  = (const float*)d_in[17];
  const float* l1g  = (const float*)d_in[18];
  const float* l1b  = (const float*)d_in[19];
  const float* l2g  = (const float*)d_in[20];
  const float* l2b  = (const float*)d_in[21];
  const float* d1w  = (const float*)d_in[22];
  const float* d1b  = (const float*)d_in[23];
  const float* d2w  = (const float*)d_in[24];
  const float* d2b  = (const float*)d_in[25];
  float* out = (float*)d_out;

  // workspace layout (floats)
  float* ws = (float*)d_ws;
  float* h      = ws;                    // ping buffer (final h after 4 steps)
  float* h2     = h + (size_t)NA * 64;   // pong buffer
  float* qkv    = h2 + (size_t)NA * 64;  // region reused as MP scratch
  float* ao     = qkv + (size_t)NA * 192;
  float* y1     = ao + (size_t)NA * 64;
  float* y2     = y1 + (size_t)NA * 64;
  float* pooled = y2 + (size_t)NA * 64;
  int*   valid  = (int*)(pooled + 256 * 64);
  (void)ao; (void)pooled;

  // weight fragments AFTER base layout (ws headroom proven in round 3).
  unsigned short* W1h = (unsigned short*)(valid + NA);
  unsigned short* W1l = W1h + 32768;
  unsigned short* W2h = W1l + 32768;
  unsigned short* W2l = W2h + 32768;
  unsigned short* PQh = W2l + 32768;     // 12288
  unsigned short* PQl = PQh + 12288;
  unsigned short* POh = PQl + 12288;     // 4096
  unsigned short* POl = POh + 4096;

  // MP-loop scratch aliased into the qkv region (dead until after the loop):
  unsigned short* KrA = (unsigned short*)qkv;  // 36864 ushort
  int*   count  = (int*)(qkv + 36864);         // NA
  int*   start  = count + NA;                  // NA+1
  int*   cursor = start + NA + 1;              // NA
  int*   elist  = cursor + NA;                 // NE
  int*   bsum   = elist + NE;                  // 256
  int*   sdst   = bsum + 256;                  // NE + 8 pad
  float* sbf    = (float*)(sdst + NE + 8);     // NE*8 + 64 pad
  unsigned short* Wh = (unsigned short*)(sbf + (size_t)NE * 8 + 64);   // 24576 ushort
  unsigned short* Wl = Wh + 24576;                                     // 24576 ushort

  k_init_h<<<NA * 64 / 256, 256, 0, stream>>>(af, h, count);
  k_prep_all<<<560, 256, 0, stream>>>(kern, kbias, wih, whh, fw1, fw2, ipw, opw,
                                      KrA, Wh, Wl, W1h, W1l, W2h, W2l,
                                      PQh, PQl, POh, POl);
  k_count<<<NE / 256, 256, 0, stream>>>(pairs, count);
  k_scan1<<<64, 256, 0, stream>>>(count, bsum);
  k_scan2<<<64, 256, 0, stream>>>(count, bsum, start, cursor);
  k_place<<<NE / 256, 256, 0, stream>>>(pairs, cursor, elist);
  k_reorder<<<NE * 8 / 256, 256, 0, stream>>>(bfeat, pairs, elist, sdst, sbf);

  float* hin = h;
  float* hout = h2;
  for (int s = 0; s < 4; ++s) {
    k_msg<<<NA / 16, 256, 0, stream>>>(hin, start, sdst, sbf, KrA,
                                       Wh, Wl, bih, bhh, hout);
    float* tmp = hin; hin = hout; hout = tmp;
  }
  // 4 swaps -> final h is back in 'h'

  k_mol<<<256, 256, 0, stream>>>(h, PQh, PQl, POh, POl, ipb, opb, l1g, l1b, y1);
  k_ffn<<<NA / 16, 256, 0, stream>>>(y1, W1h, W1l, W2h, W2l, fb1, fb2, l2g, l2b, y2);
  k_head<<<256, 256, 0, stream>>>(y2, d1w, d1b, d2w, d2b, out);
}

// Round 15
// 154.604 us; speedup vs baseline: 2.8706x; 1.0461x over previous
//
#include <hip/hip_runtime.h>
#include <hip/hip_bf16.h>
#include <math.h>

#define NA 16384
#define NE 65536
#define AD 29

typedef __attribute__((ext_vector_type(8))) short bfrag8;
typedef __attribute__((ext_vector_type(4))) float f32x4;

__device__ __forceinline__ float sigmoidf_(float x) { return 1.0f / (1.0f + expf(-x)); }
__device__ __forceinline__ unsigned short bf16bits(float x) {
  __hip_bfloat16 hb = __float2bfloat16(x);
  return *reinterpret_cast<unsigned short*>(&hb);
}
__device__ __forceinline__ float bf16val(unsigned short u) {
  unsigned int b = ((unsigned int)u) << 16;
  return __uint_as_float(b);
}

// ============ init h + zero count + ALL weight-fragment preps (one kernel) ====
// idx < NA*64: pad atom features into h (and idx<NA zeroes count).
// idx < 143360 additionally does one element of the weight prep:
//   [0,36864) KrA | [36864,61440) GRU hi/lo | [61440,126976) FFN hi/lo |
//   [126976,143360) attn ipw/opw hi/lo.
__global__ void k_init_prep(
    const float* __restrict__ af, float* __restrict__ h, int* __restrict__ count,
    const float* __restrict__ kern, const float* __restrict__ kbias,
    const float* __restrict__ wih, const float* __restrict__ whh,
    const float* __restrict__ w1, const float* __restrict__ w2,
    const float* __restrict__ ipw, const float* __restrict__ opw,
    unsigned short* __restrict__ KrA,
    unsigned short* __restrict__ Wh, unsigned short* __restrict__ Wl,
    unsigned short* __restrict__ W1h, unsigned short* __restrict__ W1l,
    unsigned short* __restrict__ W2h, unsigned short* __restrict__ W2l,
    unsigned short* __restrict__ PQh, unsigned short* __restrict__ PQl,
    unsigned short* __restrict__ POh, unsigned short* __restrict__ POl) {
  int idx0 = blockIdx.x * 256 + threadIdx.x;
  if (idx0 >= NA * 64) return;
  if (idx0 < NA) count[idx0] = 0;
  {
    int a = idx0 >> 6, d = idx0 & 63;
    h[idx0] = (d < AD) ? af[a * AD + d] : 0.0f;
  }
  if (idx0 < 36864) {                     // KrA (message kernel, bf16 single)
    int idx = idx0;
    int r = idx & 7;
    int lane = (idx >> 3) & 63;
    int tmp2 = idx >> 9;                  // w*18 + ks
    int ks = tmp2 % 18, w = tmp2 / 18;
    int i = w * 16 + (lane & 15);
    int kj = ks * 32 + ((lane >> 4) << 3) + r;
    int k9 = kj >> 6, j = kj & 63;
    float v = (k9 < 8) ? kern[k9 * 4096 + i * 64 + j] : kbias[i * 64 + j];
    KrA[idx] = bf16bits(v);
  } else if (idx0 < 61440) {              // GRU weights hi/lo
    int idx = idx0 - 36864;
    int r = idx & 7;
    int lane = (idx >> 3) & 63;
    int t2 = idx >> 9;
    int ks = t2 & 1;
    int t3 = t2 >> 1;
    int q = t3 % 6, w = t3 / 6;
    int s = q / 3, g = q % 3;
    int R = g * 64 + w * 16 + (lane & 15);
    int kk = ks * 32 + ((lane >> 4) << 3) + r;
    float v = (s == 0) ? wih[R * 64 + kk] : whh[R * 64 + kk];
    unsigned short hi = bf16bits(v);
    Wh[idx] = hi;
    Wl[idx] = bf16bits(v - bf16val(hi));
  } else if (idx0 < 126976) {             // FFN weights hi/lo
    int idx = idx0 - 61440;
    int r = idx & 7;
    int lane = (idx >> 3) & 63;
    int rest = (idx >> 9) & 63;
    if (idx < 32768) {                    // W1
      int tile = rest >> 1, ks = rest & 1;
      int hid = tile * 16 + (lane & 15);
      int kk = ks * 32 + ((lane >> 4) << 3) + r;
      float v = w1[kk * 512 + hid];
      unsigned short hi = bf16bits(v);
      W1h[idx] = hi;
      W1l[idx] = bf16bits(v - bf16val(hi));
    } else {                              // W2
      int i2 = idx - 32768;
      int tile = rest >> 4, ks = rest & 15;
      int outr = tile * 16 + (lane & 15);
      int kk = ks * 32 + ((lane >> 4) << 3) + r;
      float v = w2[kk * 64 + outr];
      unsigned short hi = bf16bits(v);
      W2h[i2] = hi;
      W2l[i2] = bf16bits(v - bf16val(hi));
    }
  } else if (idx0 < 143360) {             // attn in_proj / out_proj hi/lo
    int i = idx0 - 126976;
    if (i < 12288) {                      // ipw: 12 tiles x 2 ksteps
      int r = i & 7;
      int lane = (i >> 3) & 63;
      int rest = i >> 9;                  // 0..23
      int t = rest >> 1, ks = rest & 1;
      int R = t * 16 + (lane & 15);
      int kk = ks * 32 + ((lane >> 4) << 3) + r;
      float v = ipw[R * 64 + kk];
      unsigned short hi = bf16bits(v);
      PQh[i] = hi;
      PQl[i] = bf16bits(v - bf16val(hi));
    } else {                              // opw: 4 tiles x 2 ksteps
      int i2 = i - 12288;
      int r = i2 & 7;
      int lane = (i2 >> 3) & 63;
      int rest = i2 >> 9;                 // 0..7
      int t = rest >> 1, ks = rest & 1;
      int R = t * 16 + (lane & 15);
      int kk = ks * 32 + ((lane >> 4) << 3) + r;
      float v = opw[R * 64 + kk];
      unsigned short hi = bf16bits(v);
      POh[i2] = hi;
      POl[i2] = bf16bits(v - bf16val(hi));
    }
  }
}

// ============ edge bucketing by src (once per call; counting sort) ============
__global__ void k_count(const int* __restrict__ pairs, int* __restrict__ count) {
  int e = blockIdx.x * 256 + threadIdx.x;
  if (e >= NE) return;
  atomicAdd(&count[pairs[2 * e]], 1);
}
__global__ void k_scan1(const int* __restrict__ count, int* __restrict__ bsum) {
  __shared__ int red[256];
  int b = blockIdx.x, t = threadIdx.x;
  red[t] = count[b * 256 + t];
  __syncthreads();
  for (int s = 128; s > 0; s >>= 1) { if (t < s) red[t] += red[t + s]; __syncthreads(); }
  if (t == 0) bsum[b] = red[0];
}
__global__ void k_scan2(const int* __restrict__ count, const int* __restrict__ bsum,
                        int* __restrict__ start, int* __restrict__ cursor) {
  __shared__ int sc[256];
  __shared__ int basev;
  int b = blockIdx.x, t = threadIdx.x;
  if (t == 0) { int s = 0; for (int i = 0; i < b; ++i) s += bsum[i]; basev = s; }
  int v = count[b * 256 + t];
  sc[t] = v;
  __syncthreads();
  for (int off = 1; off < 256; off <<= 1) {
    int add = (t >= off) ? sc[t - off] : 0;
    __syncthreads();
    sc[t] += add;
    __syncthreads();
  }
  int excl = sc[t] - v + basev;
  start[b * 256 + t] = excl;
  cursor[b * 256 + t] = excl;
  if (b * 256 + t == NA - 1) start[NA] = excl + v;   // sentinel = NE
}
// place + payload reorder fused: write sorted dst + bond features directly.
__global__ void k_place(const int* __restrict__ pairs, int* __restrict__ cursor,
                        const float* __restrict__ bf, int* __restrict__ sdst,
                        float* __restrict__ sbf) {
  int e = blockIdx.x * 256 + threadIdx.x;
  if (e >= NE) return;
  int src = pairs[2 * e], dst = pairs[2 * e + 1];
  int pos = atomicAdd(&cursor[src], 1);
  sdst[pos] = dst;
  const float4* b4 = reinterpret_cast<const float4*>(&bf[e * 8]);
  float4* s4 = reinterpret_cast<float4*>(&sbf[(size_t)pos * 8]);
  s4[0] = b4[0];
  s4[1] = b4[1];
}

// ============ fused message + GRU step, fully MFMA'd dense parts ============
// Phase A: all 4 atoms' first 8-edge batches issued together (32 h-gathers in
// flight — round-14's per-atom serial loop exposed 4 L2 latencies; avg edges
// per atom is only 4, so one batch nearly always suffices; rare leftovers
// handled in a fallback loop).
#define MW 4
#define MAW 4
__global__ __launch_bounds__(256, 4) void k_msg(
    const float* __restrict__ h_in, const int* __restrict__ start,
    const int* __restrict__ sdst, const float* __restrict__ sbf,
    const unsigned short* __restrict__ KrA,
    const unsigned short* __restrict__ Wh, const unsigned short* __restrict__ Wl,
    const float* __restrict__ bih, const float* __restrict__ bhh,
    float* __restrict__ h_out) {
  __shared__ __align__(16) unsigned short Tb[16 * 584];   // 18,688 B
  __shared__ __align__(16) unsigned short Xh[16 * 136];   // 4,352 B
  __shared__ __align__(16) unsigned short Xl[16 * 136];   // 4,352 B
  __shared__ __align__(16) float Hf[16 * 68];             // 4,352 B
  __shared__ __align__(16) float AHa[16 * 68];            // 4,352 B
  __shared__ float bias_s[384];                           // 1,536 B
  const int tid = threadIdx.x, lane = tid & 63, wv = tid >> 6;
  const int ablk = blockIdx.x * 16;
  const int awave = ablk + wv * MAW;

  // ---- stage h (fp32 + bf16 hi/lo) and biases ----
#pragma unroll
  for (int aa = 0; aa < MAW; ++aa) {
    const int a = wv * MAW + aa;
    const float v = h_in[(ablk + a) * 64 + lane];
    Hf[a * 68 + lane] = v;
    const unsigned short hi = bf16bits(v);
    Xh[a * 136 + 64 + lane] = hi;
    Xl[a * 136 + 64 + lane] = bf16bits(v - bf16val(hi));
  }
  if (tid < 192) { bias_s[tid] = bih[tid]; bias_s[192 + tid] = bhh[tid]; }

  // ---- Phase A: interleaved gather across the wave's 4 atoms ----
  int s0[MAW], s1[MAW];
#pragma unroll
  for (int a = 0; a < MAW; ++a) {
    s0[a] = __builtin_amdgcn_readfirstlane(start[awave + a]);
    s1[a] = __builtin_amdgcn_readfirstlane(start[awave + a + 1]);
  }
  float t[MAW][9];
#pragma unroll
  for (int a = 0; a < MAW; ++a)
#pragma unroll
    for (int k = 0; k < 9; ++k) t[a][k] = 0.f;

  float hv[MAW][8];
#pragma unroll
  for (int a = 0; a < MAW; ++a) {
    const int cnt = s1[a] - s0[a];
#pragma unroll
    for (int i = 0; i < 8; ++i) {
      hv[a][i] = 0.f;
      if (i < cnt) {                       // wave-uniform
        int d = sdst[s0[a] + i];
        hv[a][i] = h_in[d * 64 + lane];
      }
    }
  }
#pragma unroll
  for (int a = 0; a < MAW; ++a) {
    const int cnt = s1[a] - s0[a];
#pragma unroll
    for (int i = 0; i < 8; ++i) {
      if (i < cnt) {
#pragma unroll
        for (int k = 0; k < 8; ++k)
          t[a][k] = fmaf(sbf[(size_t)(s0[a] + i) * 8 + k], hv[a][i], t[a][k]);
        t[a][8] += hv[a][i];
      }
    }
  }
  // leftovers (>8 edges on an atom; ~2% of atoms)
#pragma unroll
  for (int a = 0; a < MAW; ++a) {
    for (int base = s0[a] + 8; base < s1[a]; base += 8) {
      const int nb = s1[a] - base;
      float hv2[8];
#pragma unroll
      for (int i = 0; i < 8; ++i) {
        hv2[i] = 0.f;
        if (i < nb) {
          int d = sdst[base + i];
          hv2[i] = h_in[d * 64 + lane];
        }
      }
#pragma unroll
      for (int i = 0; i < 8; ++i) {
        if (i < nb) {
#pragma unroll
          for (int k = 0; k < 8; ++k)
            t[a][k] = fmaf(sbf[(size_t)(base + i) * 8 + k], hv2[i], t[a][k]);
          t[a][8] += hv2[i];
        }
      }
    }
  }
#pragma unroll
  for (int a = 0; a < MAW; ++a) {
    const int row = wv * MAW + a;
#pragma unroll
    for (int k = 0; k < 9; ++k) Tb[row * 584 + k * 64 + lane] = bf16bits(t[a][k]);
  }
  __syncthreads();

  // ---- Phase B: MFMA  agg[i][atom] = sum_kj K[i][kj] * T[atom][kj] ----
  f32x4 acc = {0.f, 0.f, 0.f, 0.f};
  const bfrag8* KrA8 = reinterpret_cast<const bfrag8*>(KrA);
  const int tb_base = (lane & 15) * 584 + ((lane >> 4) << 3);
#pragma unroll 3
  for (int ks = 0; ks < 18; ++ks) {
    bfrag8 af = KrA8[(wv * 18 + ks) * 64 + lane];
    bfrag8 bfr = *reinterpret_cast<const bfrag8*>(&Tb[tb_base + ks * 32]);
    acc = __builtin_amdgcn_mfma_f32_16x16x32_bf16(af, bfr, acc, 0, 0, 0);
  }
#pragma unroll
  for (int reg = 0; reg < 4; ++reg) {
    const int ii = wv * 16 + ((lane >> 4) << 2) + reg;
    const unsigned short hi = bf16bits(acc[reg]);
    Xh[(lane & 15) * 136 + ii] = hi;
    Xl[(lane & 15) * 136 + ii] = bf16bits(acc[reg] - bf16val(hi));
  }
  __syncthreads();

  // ---- Phase C: GRU matvec via MFMA (3-product split-bf16) ----
  const bfrag8* Wh8 = reinterpret_cast<const bfrag8*>(Wh);
  const bfrag8* Wl8 = reinterpret_cast<const bfrag8*>(Wl);
  f32x4 g0 = {0,0,0,0}, g1 = {0,0,0,0}, g2 = {0,0,0,0};
  f32x4 g3 = {0,0,0,0}, g4 = {0,0,0,0}, g5 = {0,0,0,0};
  f32x4* gptr[6] = {&g0, &g1, &g2, &g3, &g4, &g5};
#pragma unroll
  for (int q = 0; q < 6; ++q) {
    const int s = q / 3;
    f32x4 g = *gptr[q];
#pragma unroll
    for (int ks = 0; ks < 2; ++ks) {
      const int fidx = ((wv * 6 + q) * 2 + ks) * 64 + lane;
      bfrag8 Ah = Wh8[fidx];
      bfrag8 Al = Wl8[fidx];
      const int xoff = (lane & 15) * 136 + (s * 2 + ks) * 32 + ((lane >> 4) << 3);
      bfrag8 Bh = *reinterpret_cast<const bfrag8*>(&Xh[xoff]);
      bfrag8 Bl = *reinterpret_cast<const bfrag8*>(&Xl[xoff]);
      g = __builtin_amdgcn_mfma_f32_16x16x32_bf16(Ah, Bh, g, 0, 0, 0);
      g = __builtin_amdgcn_mfma_f32_16x16x32_bf16(Ah, Bl, g, 0, 0, 0);
      g = __builtin_amdgcn_mfma_f32_16x16x32_bf16(Al, Bh, g, 0, 0, 0);
    }
    *gptr[q] = g;
  }
#pragma unroll
  for (int reg = 0; reg < 4; ++reg) {
    const int i = wv * 16 + ((lane >> 4) << 2) + reg;
    const int atom = lane & 15;
    const float r = sigmoidf_(g0[reg] + bias_s[i] + g3[reg] + bias_s[192 + i]);
    const float z = sigmoidf_(g1[reg] + bias_s[64 + i] + g4[reg] + bias_s[256 + i]);
    const float nn = tanhf(g2[reg] + bias_s[128 + i] + r * (g5[reg] + bias_s[320 + i]));
    const float hold = Hf[atom * 68 + i];
    AHa[atom * 68 + i] = (1.0f - z) * nn + z * hold;
  }
  __syncthreads();
#pragma unroll
  for (int aa = 0; aa < MAW; ++aa) {
    const int a = wv * MAW + aa;
    h_out[(ablk + a) * 64 + lane] = AHa[a * 68 + lane];
  }
}

// ============ fused per-molecule: QKV (MFMA) + attention + out_proj (MFMA)
//              + residual + LN1.  1 block = 1 molecule = 64 atoms. ============
__global__ __launch_bounds__(256, 1) void k_mol(
    const float* __restrict__ h,
    const unsigned short* __restrict__ PQh, const unsigned short* __restrict__ PQl,
    const unsigned short* __restrict__ POh, const unsigned short* __restrict__ POl,
    const float* __restrict__ ipb, const float* __restrict__ opb,
    const float* __restrict__ l1g, const float* __restrict__ l1b,
    float* __restrict__ y1) {
  __shared__ __align__(16) float Hf[64 * 65];             // 16,640 B
  __shared__ __align__(16) unsigned short Xh[64 * 72];    //  9,216 B
  __shared__ __align__(16) unsigned short Xl[64 * 72];    //  9,216 B
  __shared__ __align__(16) float QKVs[192 * 65];          // 49,920 B
  __shared__ __align__(16) unsigned short AOh[64 * 72];   //  9,216 B
  __shared__ __align__(16) unsigned short AOl[64 * 72];   //  9,216 B
  __shared__ __align__(16) float Of[64 * 65];             // 16,640 B
  __shared__ int vd[64];
  const int tid = threadIdx.x, lane = tid & 63, wv = tid >> 6;
  const int mol = blockIdx.x;

  for (int aa = 0; aa < 16; ++aa) {
    const int a = wv * 16 + aa;
    const float v = h[(mol * 64 + a) * 64 + lane];
    Hf[a * 65 + lane] = v;
    const unsigned short hi = bf16bits(v);
    Xh[a * 72 + lane] = hi;
    Xl[a * 72 + lane] = bf16bits(v - bf16val(hi));
    int nz = __any(v != 0.0f);
    if (lane == 0) vd[a] = nz;
  }
  __syncthreads();

  const bfrag8* PQh8 = reinterpret_cast<const bfrag8*>(PQh);
  const bfrag8* PQl8 = reinterpret_cast<const bfrag8*>(PQl);
  const int xoff_b = (wv * 16 + (lane & 15)) * 72 + ((lane >> 4) << 3);
#pragma unroll 3
  for (int tile = 0; tile < 12; ++tile) {
    f32x4 acc = {0.f, 0.f, 0.f, 0.f};
#pragma unroll
    for (int ks = 0; ks < 2; ++ks) {
      const int fidx = (tile * 2 + ks) * 64 + lane;
      bfrag8 Ah = PQh8[fidx];
      bfrag8 Al = PQl8[fidx];
      bfrag8 Bh = *reinterpret_cast<const bfrag8*>(&Xh[xoff_b + ks * 32]);
      bfrag8 Bl = *reinterpret_cast<const bfrag8*>(&Xl[xoff_b + ks * 32]);
      acc = __builtin_amdgcn_mfma_f32_16x16x32_bf16(Ah, Bh, acc, 0, 0, 0);
      acc = __builtin_amdgcn_mfma_f32_16x16x32_bf16(Ah, Bl, acc, 0, 0, 0);
      acc = __builtin_amdgcn_mfma_f32_16x16x32_bf16(Al, Bh, acc, 0, 0, 0);
    }
#pragma unroll
    for (int reg = 0; reg < 4; ++reg) {
      const int row = tile * 16 + ((lane >> 4) << 2) + reg;
      QKVs[row * 65 + wv * 16 + (lane & 15)] = acc[reg] + ipb[row];
    }
  }
  __syncthreads();

#pragma unroll
  for (int hp = 0; hp < 2; ++hp) {
    const int hh = wv * 2 + hp;
    float q[8];
#pragma unroll
    for (int j = 0; j < 8; ++j) q[j] = QKVs[(hh * 8 + j) * 65 + lane];
    float m = -3.0e38f, l = 0.f, o[8] = {0,0,0,0,0,0,0,0};
    for (int t = 0; t < 64; ++t) {
      float s = 0.f;
#pragma unroll
      for (int j = 0; j < 8; ++j) s += q[j] * QKVs[(64 + hh * 8 + j) * 65 + t];
      s *= 0.35355339059327373f;
      s = vd[t] ? s : -1.0e9f;
      float mn = fmaxf(m, s);
      float c = expf(m - mn);
      float p = expf(s - mn);
      l = l * c + p;
#pragma unroll
      for (int j = 0; j < 8; ++j) o[j] = o[j] * c + p * QKVs[(128 + hh * 8 + j) * 65 + t];
      m = mn;
    }
    const float inv = 1.0f / l;
#pragma unroll
    for (int j = 0; j < 8; ++j) {
      const float v = o[j] * inv;
      const unsigned short hi = bf16bits(v);
      AOh[lane * 72 + hh * 8 + j] = hi;
      AOl[lane * 72 + hh * 8 + j] = bf16bits(v - bf16val(hi));
    }
  }
  __syncthreads();

  const bfrag8* POh8 = reinterpret_cast<const bfrag8*>(POh);
  const bfrag8* POl8 = reinterpret_cast<const bfrag8*>(POl);
  const int aoff_b = (wv * 16 + (lane & 15)) * 72 + ((lane >> 4) << 3);
#pragma unroll
  for (int tile = 0; tile < 4; ++tile) {
    f32x4 acc = {0.f, 0.f, 0.f, 0.f};
#pragma unroll
    for (int ks = 0; ks < 2; ++ks) {
      const int fidx = (tile * 2 + ks) * 64 + lane;
      bfrag8 Ah = POh8[fidx];
      bfrag8 Al = POl8[fidx];
      bfrag8 Bh = *reinterpret_cast<const bfrag8*>(&AOh[aoff_b + ks * 32]);
      bfrag8 Bl = *reinterpret_cast<const bfrag8*>(&AOl[aoff_b + ks * 32]);
      acc = __builtin_amdgcn_mfma_f32_16x16x32_bf16(Ah, Bh, acc, 0, 0, 0);
      acc = __builtin_amdgcn_mfma_f32_16x16x32_bf16(Ah, Bl, acc, 0, 0, 0);
      acc = __builtin_amdgcn_mfma_f32_16x16x32_bf16(Al, Bh, acc, 0, 0, 0);
    }
#pragma unroll
    for (int reg = 0; reg < 4; ++reg) {
      const int dim = tile * 16 + ((lane >> 4) << 2) + reg;
      Of[(wv * 16 + (lane & 15)) * 65 + dim] = acc[reg] + opb[dim];
    }
  }
  __syncthreads();

  const float gg = l1g[lane], bbb = l1b[lane];
  for (int aa = 0; aa < 16; ++aa) {
    const int a = wv * 16 + aa;
    float val = Hf[a * 65 + lane] + Of[a * 65 + lane];
    float s1 = val, s2 = val * val;
#pragma unroll
    for (int mm = 1; mm < 64; mm <<= 1) {
      s1 += __shfl_xor(s1, mm, 64);
      s2 += __shfl_xor(s2, mm, 64);
    }
    float mu = s1 * 0.015625f;
    float var = s2 * 0.015625f - mu * mu;
    y1[(mol * 64 + a) * 64 + lane] = (val - mu) * rsqrtf(var + 1e-5f) * gg + bbb;
  }
}

// ============ FFN via MFMA (split-bf16 3-product) + residual + LN2 ============
__global__ __launch_bounds__(256, 3) void k_ffn(
    const float* __restrict__ y1,
    const unsigned short* __restrict__ W1h, const unsigned short* __restrict__ W1l,
    const unsigned short* __restrict__ W2h, const unsigned short* __restrict__ W2l,
    const float* __restrict__ b1, const float* __restrict__ b2,
    const float* __restrict__ g, const float* __restrict__ bb,
    float* __restrict__ y2) {
  __shared__ __align__(16) unsigned short Xh[16 * 72];
  __shared__ __align__(16) unsigned short Xl[16 * 72];
  __shared__ __align__(16) unsigned short Hh[16 * 520];
  __shared__ __align__(16) unsigned short Hl[16 * 520];
  __shared__ __align__(16) float Y1f[16 * 68];
  __shared__ __align__(16) float Of[16 * 68];
  const int tid = threadIdx.x, lane = tid & 63, wv = tid >> 6;
  const int ablk = blockIdx.x * 16;

#pragma unroll
  for (int aa = 0; aa < 4; ++aa) {
    const int a = wv * 4 + aa;
    const float v = y1[(ablk + a) * 64 + lane];
    Y1f[a * 68 + lane] = v;
    const unsigned short hi = bf16bits(v);
    Xh[a * 72 + lane] = hi;
    Xl[a * 72 + lane] = bf16bits(v - bf16val(hi));
  }
  __syncthreads();

  const bfrag8* W1h8 = reinterpret_cast<const bfrag8*>(W1h);
  const bfrag8* W1l8 = reinterpret_cast<const bfrag8*>(W1l);
  const int xoff_base = (lane & 15) * 72 + ((lane >> 4) << 3);
#pragma unroll 2
  for (int t = 0; t < 8; ++t) {
    f32x4 acc = {0.f, 0.f, 0.f, 0.f};
    const int tile = wv * 8 + t;
#pragma unroll
    for (int ks = 0; ks < 2; ++ks) {
      const int fidx = (tile * 2 + ks) * 64 + lane;
      bfrag8 Ah = W1h8[fidx];
      bfrag8 Al = W1l8[fidx];
      bfrag8 Bh = *reinterpret_cast<const bfrag8*>(&Xh[xoff_base + ks * 32]);
      bfrag8 Bl = *reinterpret_cast<const bfrag8*>(&Xl[xoff_base + ks * 32]);
      acc = __builtin_amdgcn_mfma_f32_16x16x32_bf16(Ah, Bh, acc, 0, 0, 0);
      acc = __builtin_amdgcn_mfma_f32_16x16x32_bf16(Ah, Bl, acc, 0, 0, 0);
      acc = __builtin_amdgcn_mfma_f32_16x16x32_bf16(Al, Bh, acc, 0, 0, 0);
    }
#pragma unroll
    for (int reg = 0; reg < 4; ++reg) {
      const int hid = tile * 16 + ((lane >> 4) << 2) + reg;
      float val = fmaxf(acc[reg] + b1[hid], 0.f);
      const unsigned short hi = bf16bits(val);
      Hh[(lane & 15) * 520 + hid] = hi;
      Hl[(lane & 15) * 520 + hid] = bf16bits(val - bf16val(hi));
    }
  }
  __syncthreads();

  const bfrag8* W2h8 = reinterpret_cast<const bfrag8*>(W2h);
  const bfrag8* W2l8 = reinterpret_cast<const bfrag8*>(W2l);
  f32x4 acc2 = {0.f, 0.f, 0.f, 0.f};
  const int hoff_base = (lane & 15) * 520 + ((lane >> 4) << 3);
#pragma unroll 4
  for (int ks = 0; ks < 16; ++ks) {
    const int fidx = (wv * 16 + ks) * 64 + lane;
    bfrag8 Ah = W2h8[fidx];
    bfrag8 Al = W2l8[fidx];
    bfrag8 Bh = *reinterpret_cast<const bfrag8*>(&Hh[hoff_base + ks * 32]);
    bfrag8 Bl = *reinterpret_cast<const bfrag8*>(&Hl[hoff_base + ks * 32]);
    acc2 = __builtin_amdgcn_mfma_f32_16x16x32_bf16(Ah, Bh, acc2, 0, 0, 0);
    acc2 = __builtin_amdgcn_mfma_f32_16x16x32_bf16(Ah, Bl, acc2, 0, 0, 0);
    acc2 = __builtin_amdgcn_mfma_f32_16x16x32_bf16(Al, Bh, acc2, 0, 0, 0);
  }
#pragma unroll
  for (int reg = 0; reg < 4; ++reg) {
    const int outr = wv * 16 + ((lane >> 4) << 2) + reg;
    Of[(lane & 15) * 68 + outr] = acc2[reg] + b2[outr];
  }
  __syncthreads();

  const float gg = g[lane], bbb = bb[lane];
#pragma unroll
  for (int aa = 0; aa < 4; ++aa) {
    const int a = wv * 4 + aa;
    float val = Y1f[a * 68 + lane] + Of[a * 68 + lane];
    float s1 = val, s2 = val * val;
#pragma unroll
    for (int mm = 1; mm < 64; mm <<= 1) {
      s1 += __shfl_xor(s1, mm, 64);
      s2 += __shfl_xor(s2, mm, 64);
    }
    float mu = s1 * 0.015625f;
    float var = s2 * 0.015625f - mu * mu;
    y2[(ablk + a) * 64 + lane] = (val - mu) * rsqrtf(var + 1e-5f) * gg + bbb;
  }
}

// ============ mean-pool + readout head fused (1 block per molecule) ============
__global__ __launch_bounds__(256) void k_head(
    const float* __restrict__ y2, const float* __restrict__ d1w,
    const float* __restrict__ d1b, const float* __restrict__ d2w,
    const float* __restrict__ d2b, float* __restrict__ out) {
  const int b = blockIdx.x;
  const int tid = threadIdx.x, lane = tid & 63, wv = tid >> 6;
  __shared__ float part[4][64];
  __shared__ float p_s[64];
  __shared__ float red_s[4];
  float s = 0.f;
#pragma unroll 4
  for (int t = wv * 16; t < wv * 16 + 16; ++t) s += y2[(b * 64 + t) * 64 + lane];
  part[wv][lane] = s;
  __syncthreads();
  if (tid < 64)
    p_s[tid] = (part[0][tid] + part[1][tid] + part[2][tid] + part[3][tid]) * 0.015625f;
  __syncthreads();
  float acc = 0.f;
#pragma unroll
  for (int rep = 0; rep < 2; ++rep) {
    int c = rep * 256 + tid;
    float hvv = d1b[c];
    for (int d = 0; d < 64; ++d) hvv += p_s[d] * d1w[d * 512 + c];
    acc += fmaxf(hvv, 0.f) * d2w[c];
  }
#pragma unroll
  for (int mm = 1; mm < 64; mm <<= 1) acc += __shfl_xor(acc, mm, 64);
  if ((tid & 63) == 0) red_s[tid >> 6] = acc;
  __syncthreads();
  if (tid == 0) {
    float t = red_s[0] + red_s[1] + red_s[2] + red_s[3] + d2b[0];
    out[b] = 1.0f / (1.0f + expf(-t));
  }
}

extern "C" void kernel_launch(void* const* d_in, const int* in_sizes, int n_in,
                              void* d_out, int out_size, void* d_ws, size_t ws_size,
                              hipStream_t stream) {
  (void)in_sizes; (void)n_in; (void)out_size; (void)ws_size;
  const float* af   = (const float*)d_in[0];
  const float* bfeat= (const float*)d_in[1];
  const int*   pairs= (const int*)d_in[2];
  // d_in[3] = molecule_indicator (identity layout; unused)
  const float* kern = (const float*)d_in[4];
  const float* kbias= (const float*)d_in[5];
  const float* wih  = (const float*)d_in[6];
  const float* whh  = (const float*)d_in[7];
  const float* bih  = (const float*)d_in[8];
  const float* bhh  = (const float*)d_in[9];
  const float* ipw  = (const float*)d_in[10];
  const float* ipb  = (const float*)d_in[11];
  const float* opw  = (const float*)d_in[12];
  const float* opb  = (const float*)d_in[13];
  const float* fw1  = (const float*)d_in[14];
  const float* fb1  = (const float*)d_in[15];
  const float* fw2  = (const float*)d_in[16];
  const float* fb2  = (const float*)d_in[17];
  const float* l1g  = (const float*)d_in[18];
  const float* l1b  = (const float*)d_in[19];
  const float* l2g  = (const float*)d_in[20];
  const float* l2b  = (const float*)d_in[21];
  const float* d1w  = (const float*)d_in[22];
  const float* d1b  = (const float*)d_in[23];
  const float* d2w  = (const float*)d_in[24];
  const float* d2b  = (const float*)d_in[25];
  float* out = (float*)d_out;

  // workspace layout (floats)
  float* ws = (float*)d_ws;
  float* h      = ws;                    // ping buffer (final h after 4 steps)
  float* h2     = h + (size_t)NA * 64;   // pong buffer
  float* qkv    = h2 + (size_t)NA * 64;  // region reused as MP scratch
  float* ao     = qkv + (size_t)NA * 192;
  float* y1     = ao + (size_t)NA * 64;
  float* y2     = y1 + (size_t)NA * 64;
  float* pooled = y2 + (size_t)NA * 64;
  int*   valid  = (int*)(pooled + 256 * 64);
  (void)ao; (void)pooled;

  // weight fragments AFTER base layout (ws headroom proven in round 3).
  unsigned short* W1h = (unsigned short*)(valid + NA);
  unsigned short* W1l = W1h + 32768;
  unsigned short* W2h = W1l + 32768;
  unsigned short* W2l = W2h + 32768;
  unsigned short* PQh = W2l + 32768;     // 12288
  unsigned short* PQl = PQh + 12288;
  unsigned short* POh = PQl + 12288;     // 4096
  unsigned short* POl = POh + 4096;

  // MP-loop scratch aliased into the qkv region (dead until after the loop):
  unsigned short* KrA = (unsigned short*)qkv;  // 36864 ushort
  int*   count  = (int*)(qkv + 36864);         // NA
  int*   start  = count + NA;                  // NA+1
  int*   cursor = start + NA + 1;              // NA
  int*   bsum   = cursor + NA;                 // 256
  int*   sdst   = bsum + 256;                  // NE + 8 pad
  float* sbf    = (float*)(sdst + NE + 8);     // NE*8 + 64 pad
  unsigned short* Wh = (unsigned short*)(sbf + (size_t)NE * 8 + 64);   // 24576 ushort
  unsigned short* Wl = Wh + 24576;                                     // 24576 ushort

  k_init_prep<<<NA * 64 / 256, 256, 0, stream>>>(
      af, h, count, kern, kbias, wih, whh, fw1, fw2, ipw, opw,
      KrA, Wh, Wl, W1h, W1l, W2h, W2l, PQh, PQl, POh, POl);
  k_count<<<NE / 256, 256, 0, stream>>>(pairs, count);
  k_scan1<<<64, 256, 0, stream>>>(count, bsum);
  k_scan2<<<64, 256, 0, stream>>>(count, bsum, start, cursor);
  k_place<<<NE / 256, 256, 0, stream>>>(pairs, cursor, bfeat, sdst, sbf);

  float* hin = h;
  float* hout = h2;
  for (int s = 0; s < 4; ++s) {
    k_msg<<<NA / 16, 256, 0, stream>>>(hin, start, sdst, sbf, KrA,
                                       Wh, Wl, bih, bhh, hout);
    float* tmp = hin; hin = hout; hout = tmp;
  }
  // 4 swaps -> final h is back in 'h'

  k_mol<<<256, 256, 0, stream>>>(h, PQh, PQl, POh, POl, ipb, opb, l1g, l1b, y1);
  k_ffn<<<NA / 16, 256, 0, stream>>>(y1, W1h, W1l, W2h, W2l, fb1, fb2, l2g, l2b, y2);
  k_head<<<256, 256, 0, stream>>>(y2, d1w, d1b, d2w, d2b, out);
}

// Round 16
// 153.423 us; speedup vs baseline: 2.8927x; 1.0077x over previous
//
#include <hip/hip_runtime.h>
#include <hip/hip_bf16.h>
#include <math.h>

#define NA 16384
#define NE 65536
#define AD 29

typedef __attribute__((ext_vector_type(8))) short bfrag8;
typedef __attribute__((ext_vector_type(4))) float f32x4;

__device__ __forceinline__ float sigmoidf_(float x) { return 1.0f / (1.0f + expf(-x)); }
__device__ __forceinline__ unsigned short bf16bits(float x) {
  __hip_bfloat16 hb = __float2bfloat16(x);
  return *reinterpret_cast<unsigned short*>(&hb);
}
__device__ __forceinline__ float bf16val(unsigned short u) {
  unsigned int b = ((unsigned int)u) << 16;
  return __uint_as_float(b);
}

// ============ init h + zero count + ALL weight-fragment preps (one kernel) ====
__global__ void k_init_prep(
    const float* __restrict__ af, float* __restrict__ h, int* __restrict__ count,
    const float* __restrict__ kern, const float* __restrict__ kbias,
    const float* __restrict__ wih, const float* __restrict__ whh,
    const float* __restrict__ w1, const float* __restrict__ w2,
    const float* __restrict__ ipw, const float* __restrict__ opw,
    unsigned short* __restrict__ KrA,
    unsigned short* __restrict__ Wh, unsigned short* __restrict__ Wl,
    unsigned short* __restrict__ W1h, unsigned short* __restrict__ W1l,
    unsigned short* __restrict__ W2h, unsigned short* __restrict__ W2l,
    unsigned short* __restrict__ PQh, unsigned short* __restrict__ PQl,
    unsigned short* __restrict__ POh, unsigned short* __restrict__ POl) {
  int idx0 = blockIdx.x * 256 + threadIdx.x;
  if (idx0 >= NA * 64) return;
  if (idx0 < NA) count[idx0] = 0;
  {
    int a = idx0 >> 6, d = idx0 & 63;
    h[idx0] = (d < AD) ? af[a * AD + d] : 0.0f;
  }
  if (idx0 < 36864) {                     // KrA (message kernel, bf16 single)
    int idx = idx0;
    int r = idx & 7;
    int lane = (idx >> 3) & 63;
    int tmp2 = idx >> 9;                  // w*18 + ks
    int ks = tmp2 % 18, w = tmp2 / 18;
    int i = w * 16 + (lane & 15);
    int kj = ks * 32 + ((lane >> 4) << 3) + r;
    int k9 = kj >> 6, j = kj & 63;
    float v = (k9 < 8) ? kern[k9 * 4096 + i * 64 + j] : kbias[i * 64 + j];
    KrA[idx] = bf16bits(v);
  } else if (idx0 < 61440) {              // GRU weights hi/lo
    int idx = idx0 - 36864;
    int r = idx & 7;
    int lane = (idx >> 3) & 63;
    int t2 = idx >> 9;
    int ks = t2 & 1;
    int t3 = t2 >> 1;
    int q = t3 % 6, w = t3 / 6;
    int s = q / 3, g = q % 3;
    int R = g * 64 + w * 16 + (lane & 15);
    int kk = ks * 32 + ((lane >> 4) << 3) + r;
    float v = (s == 0) ? wih[R * 64 + kk] : whh[R * 64 + kk];
    unsigned short hi = bf16bits(v);
    Wh[idx] = hi;
    Wl[idx] = bf16bits(v - bf16val(hi));
  } else if (idx0 < 126976) {             // FFN weights hi/lo
    int idx = idx0 - 61440;
    int r = idx & 7;
    int lane = (idx >> 3) & 63;
    int rest = (idx >> 9) & 63;
    if (idx < 32768) {                    // W1
      int tile = rest >> 1, ks = rest & 1;
      int hid = tile * 16 + (lane & 15);
      int kk = ks * 32 + ((lane >> 4) << 3) + r;
      float v = w1[kk * 512 + hid];
      unsigned short hi = bf16bits(v);
      W1h[idx] = hi;
      W1l[idx] = bf16bits(v - bf16val(hi));
    } else {                              // W2
      int i2 = idx - 32768;
      int tile = rest >> 4, ks = rest & 15;
      int outr = tile * 16 + (lane & 15);
      int kk = ks * 32 + ((lane >> 4) << 3) + r;
      float v = w2[kk * 64 + outr];
      unsigned short hi = bf16bits(v);
      W2h[i2] = hi;
      W2l[i2] = bf16bits(v - bf16val(hi));
    }
  } else if (idx0 < 143360) {             // attn in_proj / out_proj hi/lo
    int i = idx0 - 126976;
    if (i < 12288) {                      // ipw: 12 tiles x 2 ksteps
      int r = i & 7;
      int lane = (i >> 3) & 63;
      int rest = i >> 9;                  // 0..23
      int t = rest >> 1, ks = rest & 1;
      int R = t * 16 + (lane & 15);
      int kk = ks * 32 + ((lane >> 4) << 3) + r;
      float v = ipw[R * 64 + kk];
      unsigned short hi = bf16bits(v);
      PQh[i] = hi;
      PQl[i] = bf16bits(v - bf16val(hi));
    } else {                              // opw: 4 tiles x 2 ksteps
      int i2 = i - 12288;
      int r = i2 & 7;
      int lane = (i2 >> 3) & 63;
      int rest = i2 >> 9;                 // 0..7
      int t = rest >> 1, ks = rest & 1;
      int R = t * 16 + (lane & 15);
      int kk = ks * 32 + ((lane >> 4) << 3) + r;
      float v = opw[R * 64 + kk];
      unsigned short hi = bf16bits(v);
      POh[i2] = hi;
      POl[i2] = bf16bits(v - bf16val(hi));
    }
  }
}

// ============ edge bucketing by src (once per call; counting sort) ============
__global__ void k_count(const int* __restrict__ pairs, int* __restrict__ count) {
  int e = blockIdx.x * 256 + threadIdx.x;
  if (e >= NE) return;
  atomicAdd(&count[pairs[2 * e]], 1);
}
__global__ void k_scan1(const int* __restrict__ count, int* __restrict__ bsum) {
  __shared__ int red[256];
  int b = blockIdx.x, t = threadIdx.x;
  red[t] = count[b * 256 + t];
  __syncthreads();
  for (int s = 128; s > 0; s >>= 1) { if (t < s) red[t] += red[t + s]; __syncthreads(); }
  if (t == 0) bsum[b] = red[0];
}
// base via 64-lane parallel reduction (round-15: thread-0 serial loop over
// up to 63 L2 loads was a dependent-latency chain).
__global__ void k_scan2(const int* __restrict__ count, const int* __restrict__ bsum,
                        int* __restrict__ start, int* __restrict__ cursor) {
  __shared__ int sc[256];
  __shared__ int basev;
  int b = blockIdx.x, t = threadIdx.x;
  if (t < 64) {
    int v = (t < b) ? bsum[t] : 0;
#pragma unroll
    for (int off = 1; off < 64; off <<= 1) v += __shfl_xor(v, off, 64);
    if (t == 0) basev = v;
  }
  int v = count[b * 256 + t];
  sc[t] = v;
  __syncthreads();
  for (int off = 1; off < 256; off <<= 1) {
    int add = (t >= off) ? sc[t - off] : 0;
    __syncthreads();
    sc[t] += add;
    __syncthreads();
  }
  int excl = sc[t] - v + basev;
  start[b * 256 + t] = excl;
  cursor[b * 256 + t] = excl;
  if (b * 256 + t == NA - 1) start[NA] = excl + v;   // sentinel = NE
}
// place + payload reorder fused: write sorted dst + bond features directly.
__global__ void k_place(const int* __restrict__ pairs, int* __restrict__ cursor,
                        const float* __restrict__ bf, int* __restrict__ sdst,
                        float* __restrict__ sbf) {
  int e = blockIdx.x * 256 + threadIdx.x;
  if (e >= NE) return;
  int src = pairs[2 * e], dst = pairs[2 * e + 1];
  int pos = atomicAdd(&cursor[src], 1);
  sdst[pos] = dst;
  const float4* b4 = reinterpret_cast<const float4*>(&bf[e * 8]);
  float4* s4 = reinterpret_cast<float4*>(&sbf[(size_t)pos * 8]);
  s4[0] = b4[0];
  s4[1] = b4[1];
}

// ============ fused message + GRU step, fully MFMA'd dense parts ============
// LDS diet (round-16): AHa aliased over Tb (dead after phase B; syncthreads
// separates), GRU biases moved to per-thread float4 loads -> 31,744 B LDS ->
// 5 blocks/CU (was 4).
#define MW 4
#define MAW 4
__global__ __launch_bounds__(256, 5) void k_msg(
    const float* __restrict__ h_in, const int* __restrict__ start,
    const int* __restrict__ sdst, const float* __restrict__ sbf,
    const unsigned short* __restrict__ KrA,
    const unsigned short* __restrict__ Wh, const unsigned short* __restrict__ Wl,
    const float* __restrict__ bih, const float* __restrict__ bhh,
    float* __restrict__ h_out) {
  __shared__ __align__(16) unsigned short Tb[16 * 584];   // 18,688 B (AHa aliased)
  __shared__ __align__(16) unsigned short Xh[16 * 136];   // 4,352 B
  __shared__ __align__(16) unsigned short Xl[16 * 136];   // 4,352 B
  __shared__ __align__(16) float Hf[16 * 68];             // 4,352 B
  float* AHa = reinterpret_cast<float*>(Tb);              // alias (phase C only)
  const int tid = threadIdx.x, lane = tid & 63, wv = tid >> 6;
  const int ablk = blockIdx.x * 16;
  const int awave = ablk + wv * MAW;

  // ---- stage h (fp32 + bf16 hi/lo) ----
#pragma unroll
  for (int aa = 0; aa < MAW; ++aa) {
    const int a = wv * MAW + aa;
    const float v = h_in[(ablk + a) * 64 + lane];
    Hf[a * 68 + lane] = v;
    const unsigned short hi = bf16bits(v);
    Xh[a * 136 + 64 + lane] = hi;
    Xl[a * 136 + 64 + lane] = bf16bits(v - bf16val(hi));
  }

  // ---- Phase A: interleaved gather across the wave's 4 atoms ----
  int s0[MAW], s1[MAW];
#pragma unroll
  for (int a = 0; a < MAW; ++a) {
    s0[a] = __builtin_amdgcn_readfirstlane(start[awave + a]);
    s1[a] = __builtin_amdgcn_readfirstlane(start[awave + a + 1]);
  }
  float t[MAW][9];
#pragma unroll
  for (int a = 0; a < MAW; ++a)
#pragma unroll
    for (int k = 0; k < 9; ++k) t[a][k] = 0.f;

  float hv[MAW][8];
#pragma unroll
  for (int a = 0; a < MAW; ++a) {
    const int cnt = s1[a] - s0[a];
#pragma unroll
    for (int i = 0; i < 8; ++i) {
      hv[a][i] = 0.f;
      if (i < cnt) {                       // wave-uniform
        int d = sdst[s0[a] + i];
        hv[a][i] = h_in[d * 64 + lane];
      }
    }
  }
#pragma unroll
  for (int a = 0; a < MAW; ++a) {
    const int cnt = s1[a] - s0[a];
#pragma unroll
    for (int i = 0; i < 8; ++i) {
      if (i < cnt) {
#pragma unroll
        for (int k = 0; k < 8; ++k)
          t[a][k] = fmaf(sbf[(size_t)(s0[a] + i) * 8 + k], hv[a][i], t[a][k]);
        t[a][8] += hv[a][i];
      }
    }
  }
  // leftovers (>8 edges on an atom; ~2% of atoms)
#pragma unroll
  for (int a = 0; a < MAW; ++a) {
    for (int base = s0[a] + 8; base < s1[a]; base += 8) {
      const int nb = s1[a] - base;
      float hv2[8];
#pragma unroll
      for (int i = 0; i < 8; ++i) {
        hv2[i] = 0.f;
        if (i < nb) {
          int d = sdst[base + i];
          hv2[i] = h_in[d * 64 + lane];
        }
      }
#pragma unroll
      for (int i = 0; i < 8; ++i) {
        if (i < nb) {
#pragma unroll
          for (int k = 0; k < 8; ++k)
            t[a][k] = fmaf(sbf[(size_t)(base + i) * 8 + k], hv2[i], t[a][k]);
          t[a][8] += hv2[i];
        }
      }
    }
  }
#pragma unroll
  for (int a = 0; a < MAW; ++a) {
    const int row = wv * MAW + a;
#pragma unroll
    for (int k = 0; k < 9; ++k) Tb[row * 584 + k * 64 + lane] = bf16bits(t[a][k]);
  }
  __syncthreads();

  // ---- Phase B: MFMA  agg[i][atom] = sum_kj K[i][kj] * T[atom][kj] ----
  f32x4 acc = {0.f, 0.f, 0.f, 0.f};
  const bfrag8* KrA8 = reinterpret_cast<const bfrag8*>(KrA);
  const int tb_base = (lane & 15) * 584 + ((lane >> 4) << 3);
#pragma unroll 3
  for (int ks = 0; ks < 18; ++ks) {
    bfrag8 af = KrA8[(wv * 18 + ks) * 64 + lane];
    bfrag8 bfr = *reinterpret_cast<const bfrag8*>(&Tb[tb_base + ks * 32]);
    acc = __builtin_amdgcn_mfma_f32_16x16x32_bf16(af, bfr, acc, 0, 0, 0);
  }
#pragma unroll
  for (int reg = 0; reg < 4; ++reg) {
    const int ii = wv * 16 + ((lane >> 4) << 2) + reg;
    const unsigned short hi = bf16bits(acc[reg]);
    Xh[(lane & 15) * 136 + ii] = hi;
    Xl[(lane & 15) * 136 + ii] = bf16bits(acc[reg] - bf16val(hi));
  }
  __syncthreads();      // also separates last Tb read from AHa (alias) writes

  // ---- Phase C: GRU matvec via MFMA (3-product split-bf16) ----
  const bfrag8* Wh8 = reinterpret_cast<const bfrag8*>(Wh);
  const bfrag8* Wl8 = reinterpret_cast<const bfrag8*>(Wl);
  f32x4 g0 = {0,0,0,0}, g1 = {0,0,0,0}, g2 = {0,0,0,0};
  f32x4 g3 = {0,0,0,0}, g4 = {0,0,0,0}, g5 = {0,0,0,0};
  f32x4* gptr[6] = {&g0, &g1, &g2, &g3, &g4, &g5};
#pragma unroll
  for (int q = 0; q < 6; ++q) {
    const int s = q / 3;
    f32x4 g = *gptr[q];
#pragma unroll
    for (int ks = 0; ks < 2; ++ks) {
      const int fidx = ((wv * 6 + q) * 2 + ks) * 64 + lane;
      bfrag8 Ah = Wh8[fidx];
      bfrag8 Al = Wl8[fidx];
      const int xoff = (lane & 15) * 136 + (s * 2 + ks) * 32 + ((lane >> 4) << 3);
      bfrag8 Bh = *reinterpret_cast<const bfrag8*>(&Xh[xoff]);
      bfrag8 Bl = *reinterpret_cast<const bfrag8*>(&Xl[xoff]);
      g = __builtin_amdgcn_mfma_f32_16x16x32_bf16(Ah, Bh, g, 0, 0, 0);
      g = __builtin_amdgcn_mfma_f32_16x16x32_bf16(Ah, Bl, g, 0, 0, 0);
      g = __builtin_amdgcn_mfma_f32_16x16x32_bf16(Al, Bh, g, 0, 0, 0);
    }
    *gptr[q] = g;
  }
  // biases: per-thread reg-contiguous float4 loads (replaces LDS staging)
  const int ib = wv * 16 + ((lane >> 4) << 2);
  const float4 bir4 = *reinterpret_cast<const float4*>(&bih[ib]);
  const float4 biz4 = *reinterpret_cast<const float4*>(&bih[64 + ib]);
  const float4 bin4 = *reinterpret_cast<const float4*>(&bih[128 + ib]);
  const float4 bhr4 = *reinterpret_cast<const float4*>(&bhh[ib]);
  const float4 bhz4 = *reinterpret_cast<const float4*>(&bhh[64 + ib]);
  const float4 bhn4 = *reinterpret_cast<const float4*>(&bhh[128 + ib]);
  const float birA[4] = {bir4.x, bir4.y, bir4.z, bir4.w};
  const float bizA[4] = {biz4.x, biz4.y, biz4.z, biz4.w};
  const float binA[4] = {bin4.x, bin4.y, bin4.z, bin4.w};
  const float bhrA[4] = {bhr4.x, bhr4.y, bhr4.z, bhr4.w};
  const float bhzA[4] = {bhz4.x, bhz4.y, bhz4.z, bhz4.w};
  const float bhnA[4] = {bhn4.x, bhn4.y, bhn4.z, bhn4.w};
#pragma unroll
  for (int reg = 0; reg < 4; ++reg) {
    const int i = ib + reg;
    const int atom = lane & 15;
    const float r = sigmoidf_(g0[reg] + birA[reg] + g3[reg] + bhrA[reg]);
    const float z = sigmoidf_(g1[reg] + bizA[reg] + g4[reg] + bhzA[reg]);
    const float nn = tanhf(g2[reg] + binA[reg] + r * (g5[reg] + bhnA[reg]));
    const float hold = Hf[atom * 68 + i];
    AHa[atom * 68 + i] = (1.0f - z) * nn + z * hold;
  }
  __syncthreads();
#pragma unroll
  for (int aa = 0; aa < MAW; ++aa) {
    const int a = wv * MAW + aa;
    h_out[(ablk + a) * 64 + lane] = AHa[a * 68 + lane];
  }
}

// ============ fused per-molecule: QKV (MFMA) + attention + out_proj (MFMA)
//              + residual + LN1.  1 block = 1 molecule = 64 atoms. ============
__global__ __launch_bounds__(256, 1) void k_mol(
    const float* __restrict__ h,
    const unsigned short* __restrict__ PQh, const unsigned short* __restrict__ PQl,
    const unsigned short* __restrict__ POh, const unsigned short* __restrict__ POl,
    const float* __restrict__ ipb, const float* __restrict__ opb,
    const float* __restrict__ l1g, const float* __restrict__ l1b,
    float* __restrict__ y1) {
  __shared__ __align__(16) float Hf[64 * 65];             // 16,640 B
  __shared__ __align__(16) unsigned short Xh[64 * 72];    //  9,216 B
  __shared__ __align__(16) unsigned short Xl[64 * 72];    //  9,216 B
  __shared__ __align__(16) float QKVs[192 * 65];          // 49,920 B
  __shared__ __align__(16) unsigned short AOh[64 * 72];   //  9,216 B
  __shared__ __align__(16) unsigned short AOl[64 * 72];   //  9,216 B
  __shared__ __align__(16) float Of[64 * 65];             // 16,640 B
  __shared__ int vd[64];
  const int tid = threadIdx.x, lane = tid & 63, wv = tid >> 6;
  const int mol = blockIdx.x;

  for (int aa = 0; aa < 16; ++aa) {
    const int a = wv * 16 + aa;
    const float v = h[(mol * 64 + a) * 64 + lane];
    Hf[a * 65 + lane] = v;
    const unsigned short hi = bf16bits(v);
    Xh[a * 72 + lane] = hi;
    Xl[a * 72 + lane] = bf16bits(v - bf16val(hi));
    int nz = __any(v != 0.0f);
    if (lane == 0) vd[a] = nz;
  }
  __syncthreads();

  const bfrag8* PQh8 = reinterpret_cast<const bfrag8*>(PQh);
  const bfrag8* PQl8 = reinterpret_cast<const bfrag8*>(PQl);
  const int xoff_b = (wv * 16 + (lane & 15)) * 72 + ((lane >> 4) << 3);
#pragma unroll 3
  for (int tile = 0; tile < 12; ++tile) {
    f32x4 acc = {0.f, 0.f, 0.f, 0.f};
#pragma unroll
    for (int ks = 0; ks < 2; ++ks) {
      const int fidx = (tile * 2 + ks) * 64 + lane;
      bfrag8 Ah = PQh8[fidx];
      bfrag8 Al = PQl8[fidx];
      bfrag8 Bh = *reinterpret_cast<const bfrag8*>(&Xh[xoff_b + ks * 32]);
      bfrag8 Bl = *reinterpret_cast<const bfrag8*>(&Xl[xoff_b + ks * 32]);
      acc = __builtin_amdgcn_mfma_f32_16x16x32_bf16(Ah, Bh, acc, 0, 0, 0);
      acc = __builtin_amdgcn_mfma_f32_16x16x32_bf16(Ah, Bl, acc, 0, 0, 0);
      acc = __builtin_amdgcn_mfma_f32_16x16x32_bf16(Al, Bh, acc, 0, 0, 0);
    }
#pragma unroll
    for (int reg = 0; reg < 4; ++reg) {
      const int row = tile * 16 + ((lane >> 4) << 2) + reg;
      QKVs[row * 65 + wv * 16 + (lane & 15)] = acc[reg] + ipb[row];
    }
  }
  __syncthreads();

#pragma unroll
  for (int hp = 0; hp < 2; ++hp) {
    const int hh = wv * 2 + hp;
    float q[8];
#pragma unroll
    for (int j = 0; j < 8; ++j) q[j] = QKVs[(hh * 8 + j) * 65 + lane];
    float m = -3.0e38f, l = 0.f, o[8] = {0,0,0,0,0,0,0,0};
    for (int t = 0; t < 64; ++t) {
      float s = 0.f;
#pragma unroll
      for (int j = 0; j < 8; ++j) s += q[j] * QKVs[(64 + hh * 8 + j) * 65 + t];
      s *= 0.35355339059327373f;
      s = vd[t] ? s : -1.0e9f;
      float mn = fmaxf(m, s);
      float c = expf(m - mn);
      float p = expf(s - mn);
      l = l * c + p;
#pragma unroll
      for (int j = 0; j < 8; ++j) o[j] = o[j] * c + p * QKVs[(128 + hh * 8 + j) * 65 + t];
      m = mn;
    }
    const float inv = 1.0f / l;
#pragma unroll
    for (int j = 0; j < 8; ++j) {
      const float v = o[j] * inv;
      const unsigned short hi = bf16bits(v);
      AOh[lane * 72 + hh * 8 + j] = hi;
      AOl[lane * 72 + hh * 8 + j] = bf16bits(v - bf16val(hi));
    }
  }
  __syncthreads();

  const bfrag8* POh8 = reinterpret_cast<const bfrag8*>(POh);
  const bfrag8* POl8 = reinterpret_cast<const bfrag8*>(POl);
  const int aoff_b = (wv * 16 + (lane & 15)) * 72 + ((lane >> 4) << 3);
#pragma unroll
  for (int tile = 0; tile < 4; ++tile) {
    f32x4 acc = {0.f, 0.f, 0.f, 0.f};
#pragma unroll
    for (int ks = 0; ks < 2; ++ks) {
      const int fidx = (tile * 2 + ks) * 64 + lane;
      bfrag8 Ah = POh8[fidx];
      bfrag8 Al = POl8[fidx];
      bfrag8 Bh = *reinterpret_cast<const bfrag8*>(&AOh[aoff_b + ks * 32]);
      bfrag8 Bl = *reinterpret_cast<const bfrag8*>(&AOl[aoff_b + ks * 32]);
      acc = __builtin_amdgcn_mfma_f32_16x16x32_bf16(Ah, Bh, acc, 0, 0, 0);
      acc = __builtin_amdgcn_mfma_f32_16x16x32_bf16(Ah, Bl, acc, 0, 0, 0);
      acc = __builtin_amdgcn_mfma_f32_16x16x32_bf16(Al, Bh, acc, 0, 0, 0);
    }
#pragma unroll
    for (int reg = 0; reg < 4; ++reg) {
      const int dim = tile * 16 + ((lane >> 4) << 2) + reg;
      Of[(wv * 16 + (lane & 15)) * 65 + dim] = acc[reg] + opb[dim];
    }
  }
  __syncthreads();

  const float gg = l1g[lane], bbb = l1b[lane];
  for (int aa = 0; aa < 16; ++aa) {
    const int a = wv * 16 + aa;
    float val = Hf[a * 65 + lane] + Of[a * 65 + lane];
    float s1 = val, s2 = val * val;
#pragma unroll
    for (int mm = 1; mm < 64; mm <<= 1) {
      s1 += __shfl_xor(s1, mm, 64);
      s2 += __shfl_xor(s2, mm, 64);
    }
    float mu = s1 * 0.015625f;
    float var = s2 * 0.015625f - mu * mu;
    y1[(mol * 64 + a) * 64 + lane] = (val - mu) * rsqrtf(var + 1e-5f) * gg + bbb;
  }
}

// ============ FFN via MFMA (split-bf16 3-product) + residual + LN2 ============
__global__ __launch_bounds__(256, 3) void k_ffn(
    const float* __restrict__ y1,
    const unsigned short* __restrict__ W1h, const unsigned short* __restrict__ W1l,
    const unsigned short* __restrict__ W2h, const unsigned short* __restrict__ W2l,
    const float* __restrict__ b1, const float* __restrict__ b2,
    const float* __restrict__ g, const float* __restrict__ bb,
    float* __restrict__ y2) {
  __shared__ __align__(16) unsigned short Xh[16 * 72];
  __shared__ __align__(16) unsigned short Xl[16 * 72];
  __shared__ __align__(16) unsigned short Hh[16 * 520];
  __shared__ __align__(16) unsigned short Hl[16 * 520];
  __shared__ __align__(16) float Y1f[16 * 68];
  __shared__ __align__(16) float Of[16 * 68];
  const int tid = threadIdx.x, lane = tid & 63, wv = tid >> 6;
  const int ablk = blockIdx.x * 16;

#pragma unroll
  for (int aa = 0; aa < 4; ++aa) {
    const int a = wv * 4 + aa;
    const float v = y1[(ablk + a) * 64 + lane];
    Y1f[a * 68 + lane] = v;
    const unsigned short hi = bf16bits(v);
    Xh[a * 72 + lane] = hi;
    Xl[a * 72 + lane] = bf16bits(v - bf16val(hi));
  }
  __syncthreads();

  const bfrag8* W1h8 = reinterpret_cast<const bfrag8*>(W1h);
  const bfrag8* W1l8 = reinterpret_cast<const bfrag8*>(W1l);
  const int xoff_base = (lane & 15) * 72 + ((lane >> 4) << 3);
#pragma unroll 2
  for (int t = 0; t < 8; ++t) {
    f32x4 acc = {0.f, 0.f, 0.f, 0.f};
    const int tile = wv * 8 + t;
#pragma unroll
    for (int ks = 0; ks < 2; ++ks) {
      const int fidx = (tile * 2 + ks) * 64 + lane;
      bfrag8 Ah = W1h8[fidx];
      bfrag8 Al = W1l8[fidx];
      bfrag8 Bh = *reinterpret_cast<const bfrag8*>(&Xh[xoff_base + ks * 32]);
      bfrag8 Bl = *reinterpret_cast<const bfrag8*>(&Xl[xoff_base + ks * 32]);
      acc = __builtin_amdgcn_mfma_f32_16x16x32_bf16(Ah, Bh, acc, 0, 0, 0);
      acc = __builtin_amdgcn_mfma_f32_16x16x32_bf16(Ah, Bl, acc, 0, 0, 0);
      acc = __builtin_amdgcn_mfma_f32_16x16x32_bf16(Al, Bh, acc, 0, 0, 0);
    }
#pragma unroll
    for (int reg = 0; reg < 4; ++reg) {
      const int hid = tile * 16 + ((lane >> 4) << 2) + reg;
      float val = fmaxf(acc[reg] + b1[hid], 0.f);
      const unsigned short hi = bf16bits(val);
      Hh[(lane & 15) * 520 + hid] = hi;
      Hl[(lane & 15) * 520 + hid] = bf16bits(val - bf16val(hi));
    }
  }
  __syncthreads();

  const bfrag8* W2h8 = reinterpret_cast<const bfrag8*>(W2h);
  const bfrag8* W2l8 = reinterpret_cast<const bfrag8*>(W2l);
  f32x4 acc2 = {0.f, 0.f, 0.f, 0.f};
  const int hoff_base = (lane & 15) * 520 + ((lane >> 4) << 3);
#pragma unroll 4
  for (int ks = 0; ks < 16; ++ks) {
    const int fidx = (wv * 16 + ks) * 64 + lane;
    bfrag8 Ah = W2h8[fidx];
    bfrag8 Al = W2l8[fidx];
    bfrag8 Bh = *reinterpret_cast<const bfrag8*>(&Hh[hoff_base + ks * 32]);
    bfrag8 Bl = *reinterpret_cast<const bfrag8*>(&Hl[hoff_base + ks * 32]);
    acc2 = __builtin_amdgcn_mfma_f32_16x16x32_bf16(Ah, Bh, acc2, 0, 0, 0);
    acc2 = __builtin_amdgcn_mfma_f32_16x16x32_bf16(Ah, Bl, acc2, 0, 0, 0);
    acc2 = __builtin_amdgcn_mfma_f32_16x16x32_bf16(Al, Bh, acc2, 0, 0, 0);
  }
#pragma unroll
  for (int reg = 0; reg < 4; ++reg) {
    const int outr = wv * 16 + ((lane >> 4) << 2) + reg;
    Of[(lane & 15) * 68 + outr] = acc2[reg] + b2[outr];
  }
  __syncthreads();

  const float gg = g[lane], bbb = bb[lane];
#pragma unroll
  for (int aa = 0; aa < 4; ++aa) {
    const int a = wv * 4 + aa;
    float val = Y1f[a * 68 + lane] + Of[a * 68 + lane];
    float s1 = val, s2 = val * val;
#pragma unroll
    for (int mm = 1; mm < 64; mm <<= 1) {
      s1 += __shfl_xor(s1, mm, 64);
      s2 += __shfl_xor(s2, mm, 64);
    }
    float mu = s1 * 0.015625f;
    float var = s2 * 0.015625f - mu * mu;
    y2[(ablk + a) * 64 + lane] = (val - mu) * rsqrtf(var + 1e-5f) * gg + bbb;
  }
}

// ============ mean-pool + readout head fused (1 block per molecule) ============
__global__ __launch_bounds__(256) void k_head(
    const float* __restrict__ y2, const float* __restrict__ d1w,
    const float* __restrict__ d1b, const float* __restrict__ d2w,
    const float* __restrict__ d2b, float* __restrict__ out) {
  const int b = blockIdx.x;
  const int tid = threadIdx.x, lane = tid & 63, wv = tid >> 6;
  __shared__ float part[4][64];
  __shared__ float p_s[64];
  __shared__ float red_s[4];
  float s = 0.f;
#pragma unroll 4
  for (int t = wv * 16; t < wv * 16 + 16; ++t) s += y2[(b * 64 + t) * 64 + lane];
  part[wv][lane] = s;
  __syncthreads();
  if (tid < 64)
    p_s[tid] = (part[0][tid] + part[1][tid] + part[2][tid] + part[3][tid]) * 0.015625f;
  __syncthreads();
  float acc = 0.f;
#pragma unroll
  for (int rep = 0; rep < 2; ++rep) {
    int c = rep * 256 + tid;
    float hvv = d1b[c];
    for (int d = 0; d < 64; ++d) hvv += p_s[d] * d1w[d * 512 + c];
    acc += fmaxf(hvv, 0.f) * d2w[c];
  }
#pragma unroll
  for (int mm = 1; mm < 64; mm <<= 1) acc += __shfl_xor(acc, mm, 64);
  if ((tid & 63) == 0) red_s[tid >> 6] = acc;
  __syncthreads();
  if (tid == 0) {
    float t = red_s[0] + red_s[1] + red_s[2] + red_s[3] + d2b[0];
    out[b] = 1.0f / (1.0f + expf(-t));
  }
}

extern "C" void kernel_launch(void* const* d_in, const int* in_sizes, int n_in,
                              void* d_out, int out_size, void* d_ws, size_t ws_size,
                              hipStream_t stream) {
  (void)in_sizes; (void)n_in; (void)out_size; (void)ws_size;
  const float* af   = (const float*)d_in[0];
  const float* bfeat= (const float*)d_in[1];
  const int*   pairs= (const int*)d_in[2];
  // d_in[3] = molecule_indicator (identity layout; unused)
  const float* kern = (const float*)d_in[4];
  const float* kbias= (const float*)d_in[5];
  const float* wih  = (const float*)d_in[6];
  const float* whh  = (const float*)d_in[7];
  const float* bih  = (const float*)d_in[8];
  const float* bhh  = (const float*)d_in[9];
  const float* ipw  = (const float*)d_in[10];
  const float* ipb  = (const float*)d_in[11];
  const float* opw  = (const float*)d_in[12];
  const float* opb  = (const float*)d_in[13];
  const float* fw1  = (const float*)d_in[14];
  const float* fb1  = (const float*)d_in[15];
  const float* fw2  = (const float*)d_in[16];
  const float* fb2  = (const float*)d_in[17];
  const float* l1g  = (const float*)d_in[18];
  const float* l1b  = (const float*)d_in[19];
  const float* l2g  = (const float*)d_in[20];
  const float* l2b  = (const float*)d_in[21];
  const float* d1w  = (const float*)d_in[22];
  const float* d1b  = (const float*)d_in[23];
  const float* d2w  = (const float*)d_in[24];
  const float* d2b  = (const float*)d_in[25];
  float* out = (float*)d_out;

  // workspace layout (floats)
  float* ws = (float*)d_ws;
  float* h      = ws;                    // ping buffer (final h after 4 steps)
  float* h2     = h + (size_t)NA * 64;   // pong buffer
  float* qkv    = h2 + (size_t)NA * 64;  // region reused as MP scratch
  float* ao     = qkv + (size_t)NA * 192;
  float* y1     = ao + (size_t)NA * 64;
  float* y2     = y1 + (size_t)NA * 64;
  float* pooled = y2 + (size_t)NA * 64;
  int*   valid  = (int*)(pooled + 256 * 64);
  (void)ao; (void)pooled;

  // weight fragments AFTER base layout (ws headroom proven in round 3).
  unsigned short* W1h = (unsigned short*)(valid + NA);
  unsigned short* W1l = W1h + 32768;
  unsigned short* W2h = W1l + 32768;
  unsigned short* W2l = W2h + 32768;
  unsigned short* PQh = W2l + 32768;     // 12288
  unsigned short* PQl = PQh + 12288;
  unsigned short* POh = PQl + 12288;     // 4096
  unsigned short* POl = POh + 4096;

  // MP-loop scratch aliased into the qkv region (dead until after the loop):
  unsigned short* KrA = (unsigned short*)qkv;  // 36864 ushort
  int*   count  = (int*)(qkv + 36864);         // NA
  int*   start  = count + NA;                  // NA+1
  int*   cursor = start + NA + 1;              // NA
  int*   bsum   = cursor + NA;                 // 256
  int*   sdst   = bsum + 256;                  // NE + 8 pad
  float* sbf    = (float*)(sdst + NE + 8);     // NE*8 + 64 pad
  unsigned short* Wh = (unsigned short*)(sbf + (size_t)NE * 8 + 64);   // 24576 ushort
  unsigned short* Wl = Wh + 24576;                                     // 24576 ushort

  k_init_prep<<<NA * 64 / 256, 256, 0, stream>>>(
      af, h, count, kern, kbias, wih, whh, fw1, fw2, ipw, opw,
      KrA, Wh, Wl, W1h, W1l, W2h, W2l, PQh, PQl, POh, POl);
  k_count<<<NE / 256, 256, 0, stream>>>(pairs, count);
  k_scan1<<<64, 256, 0, stream>>>(count, bsum);
  k_scan2<<<64, 256, 0, stream>>>(count, bsum, start, cursor);
  k_place<<<NE / 256, 256, 0, stream>>>(pairs, cursor, bfeat, sdst, sbf);

  float* hin = h;
  float* hout = h2;
  for (int s = 0; s < 4; ++s) {
    k_msg<<<NA / 16, 256, 0, stream>>>(hin, start, sdst, sbf, KrA,
                                       Wh, Wl, bih, bhh, hout);
    float* tmp = hin; hin = hout; hout = tmp;
  }
  // 4 swaps -> final h is back in 'h'

  k_mol<<<256, 256, 0, stream>>>(h, PQh, PQl, POh, POl, ipb, opb, l1g, l1b, y1);
  k_ffn<<<NA / 16, 256, 0, stream>>>(y1, W1h, W1l, W2h, W2l, fb1, fb2, l2g, l2b, y2);
  k_head<<<256, 256, 0, stream>>>(y2, d1w, d1b, d2w, d2b, out);
}